// Round 13
// baseline (1845.888 us; speedup 1.0000x reference)
//
#include <hip/hip_runtime.h>
#include <hip/hip_bf16.h>
#include <math.h>

#define NN 50000
#define NNP 50048          // padded to multiple of 128
#define NE 800000
#define NG 512
#define DIN 128
#define HD 256
#define DOUT 128
#define NL 5
#define H4 1024

typedef _Float16 f16x8 __attribute__((ext_vector_type(8)));
typedef _Float16 f16x4 __attribute__((ext_vector_type(4)));
typedef float f32x4 __attribute__((ext_vector_type(4)));

__device__ __forceinline__ float gelu_exact(float x) {
    return 0.5f * x * (1.0f + erff(x * 0.70710678118654752f));
}

__device__ __forceinline__ void gl_lds16(const _Float16* g, _Float16* l) {
    __builtin_amdgcn_global_load_lds(
        (const __attribute__((address_space(1))) unsigned int*)g,
        (__attribute__((address_space(3))) unsigned int*)l, 16, 0, 0);
}

// ---------------- graph meta ----------------
__global__ void k_hist(const int* __restrict__ idx, int* __restrict__ cnt, int n) {
    int i = blockIdx.x * blockDim.x + threadIdx.x;
    if (i < n) atomicAdd(&cnt[idx[i]], 1);
}

__global__ void k_scan_small(const int* __restrict__ in, int* __restrict__ out, int n) {
    __shared__ int buf[1024];
    int t = threadIdx.x;
    int v = (t < n) ? in[t] : 0;
    buf[t] = v;
    __syncthreads();
    for (int off = 1; off < 1024; off <<= 1) {
        int x = (t >= off) ? buf[t - off] : 0;
        __syncthreads();
        buf[t] += x;
        __syncthreads();
    }
    if (t < n) out[t] = buf[t] - v;
    if (t == 1023) out[n] = buf[1023];
}

__global__ void k_scan_part(const int* __restrict__ in, int* __restrict__ bsum, int n) {
    __shared__ int buf[256];
    int i = blockIdx.x * 256 + threadIdx.x;
    buf[threadIdx.x] = (i < n) ? in[i] : 0;
    __syncthreads();
    for (int off = 128; off > 0; off >>= 1) {
        if (threadIdx.x < off) buf[threadIdx.x] += buf[threadIdx.x + off];
        __syncthreads();
    }
    if (threadIdx.x == 0) bsum[blockIdx.x] = buf[0];
}

__global__ void k_scan_mid(const int* __restrict__ bsum, int* __restrict__ bexcl, int nb,
                           int* __restrict__ out, int n) {
    __shared__ int buf[1024];
    int t = threadIdx.x;
    int v = (t < nb) ? bsum[t] : 0;
    buf[t] = v;
    __syncthreads();
    for (int off = 1; off < 1024; off <<= 1) {
        int x = (t >= off) ? buf[t - off] : 0;
        __syncthreads();
        buf[t] += x;
        __syncthreads();
    }
    if (t < nb) bexcl[t] = buf[t] - v;
    if (t == 1023) out[n] = buf[1023];
}

__global__ void k_scan_out(const int* __restrict__ in, const int* __restrict__ bexcl,
                           int* __restrict__ out, int n) {
    __shared__ int buf[256];
    int i = blockIdx.x * 256 + threadIdx.x;
    int t = threadIdx.x;
    int v = (i < n) ? in[i] : 0;
    buf[t] = v;
    __syncthreads();
    for (int off = 1; off < 256; off <<= 1) {
        int x = (t >= off) ? buf[t - off] : 0;
        __syncthreads();
        buf[t] += x;
        __syncthreads();
    }
    if (i < n) out[i] = bexcl[blockIdx.x] + buf[t] - v;
}

__global__ void k_fill_csr(const int* __restrict__ src, const int* __restrict__ dst,
                           const int* __restrict__ eoff, int* __restrict__ cursor,
                           int* __restrict__ csr, int n) {
    int e = blockIdx.x * blockDim.x + threadIdx.x;
    if (e < n) {
        int d = dst[e];
        int p = atomicAdd(&cursor[d], 1);
        csr[eoff[d] + p] = src[e];
    }
}

// ---------------- converts ----------------
__global__ void k_cvt16(const float* __restrict__ in, _Float16* __restrict__ out, int n4) {
    int i = blockIdx.x * blockDim.x + threadIdx.x;
    if (i < n4) {
        float4 v = *(const float4*)&in[i * 4];
        f16x4 o = { (_Float16)v.x, (_Float16)v.y, (_Float16)v.z, (_Float16)v.w };
        *(f16x4*)&out[i * 4] = o;
    }
}

// batched transpose + convert: one launch for all weight matrices
#define NWTJOBS 44
struct WtJobs {
    const float* src[NWTJOBS];
    _Float16* dst[NWTJOBS];
    short K32[NWTJOBS];
    short N32[NWTJOBS];
    short pre[NWTJOBS + 1];
};
__global__ void k_wtb(WtJobs j) {
    int bid = blockIdx.x;
    int lo = 0;
    while (j.pre[lo + 1] <= bid) ++lo;
    int tl = bid - j.pre[lo];
    int nx = j.N32[lo];
    int n0 = (tl % nx) * 32, k0 = (tl / nx) * 32;
    int K = j.K32[lo] * 32, N = nx * 32;
    const float* W = j.src[lo];
    _Float16* Wt = j.dst[lo];
    __shared__ float tile[32][33];
    for (int i = threadIdx.y; i < 32; i += 8)
        tile[i][threadIdx.x] = W[(size_t)(k0 + i) * N + n0 + threadIdx.x];
    __syncthreads();
    for (int i = threadIdx.y; i < 32; i += 8)
        Wt[(size_t)(n0 + i) * K + k0 + threadIdx.x] = (_Float16)tile[threadIdx.x][i];
}

// ---------------- pooling / aggregation ----------------
__global__ void k_pool16(const _Float16* __restrict__ h16, const int* __restrict__ goff,
                         _Float16* __restrict__ pool) {
    int g = blockIdx.x;
    int c = threadIdx.x;
    int s = goff[g], e = goff[g + 1];
    float acc = 0.f;
    for (int r = s; r < e; ++r) acc += (float)h16[(size_t)r * HD + c];
    int cnt = e - s;
    pool[g * HD + c] = (_Float16)(acc / (float)(cnt > 0 ? cnt : 1));
}

// one wave per node; WAVE-UNIFORM loop bounds; 8 edges/iter
__global__ __launch_bounds__(256) void k_agg16(const _Float16* __restrict__ h16,
                                               const int* __restrict__ eoff,
                                               const int* __restrict__ csr,
                                               _Float16* __restrict__ out) {
    int node = blockIdx.x * 4 + (threadIdx.x >> 6);
    int lane = threadIdx.x & 63;
    int half = lane >> 5, l = lane & 31;
    f16x8 mine = *(const f16x8*)&h16[(size_t)node * HD + l * 8];
    float acc[8];
#pragma unroll
    for (int q = 0; q < 8; ++q) acc[q] = half ? 0.f : (float)mine[q];
    int s = eoff[node], e = eoff[node + 1];
    for (int base = s; base < e; base += 64) {
        int myi = base + lane;
        int vidx = (myi < e) ? csr[myi] : 0;
        int cnt = min(64, e - base);
        int jj = 0;
        for (; jj + 7 < cnt; jj += 8) {
            int s0 = __shfl(vidx, jj + half);
            int s1 = __shfl(vidx, jj + 2 + half);
            int s2 = __shfl(vidx, jj + 4 + half);
            int s3 = __shfl(vidx, jj + 6 + half);
            f16x8 v0 = *(const f16x8*)&h16[(size_t)s0 * HD + l * 8];
            f16x8 v1 = *(const f16x8*)&h16[(size_t)s1 * HD + l * 8];
            f16x8 v2 = *(const f16x8*)&h16[(size_t)s2 * HD + l * 8];
            f16x8 v3 = *(const f16x8*)&h16[(size_t)s3 * HD + l * 8];
#pragma unroll
            for (int q = 0; q < 8; ++q)
                acc[q] += ((float)v0[q] + (float)v1[q]) + ((float)v2[q] + (float)v3[q]);
        }
        for (; jj + 3 < cnt; jj += 4) {
            int s0 = __shfl(vidx, jj + half);
            int s1 = __shfl(vidx, jj + 2 + half);
            f16x8 v0 = *(const f16x8*)&h16[(size_t)s0 * HD + l * 8];
            f16x8 v1 = *(const f16x8*)&h16[(size_t)s1 * HD + l * 8];
#pragma unroll
            for (int q = 0; q < 8; ++q) acc[q] += (float)v0[q] + (float)v1[q];
        }
        for (; jj < cnt; jj += 2) {
            int i0 = jj + half;
            int s0 = __shfl(vidx, i0);
            if (i0 < cnt) {
                f16x8 v0 = *(const f16x8*)&h16[(size_t)s0 * HD + l * 8];
#pragma unroll
                for (int q = 0; q < 8; ++q) acc[q] += (float)v0[q];
            }
        }
    }
#pragma unroll
    for (int q = 0; q < 8; ++q) acc[q] += __shfl_xor(acc[q], 32);
    if (!half) {
        f16x8 o;
#pragma unroll
        for (int q = 0; q < 8; ++q) o[q] = (_Float16)acc[q];
        *(f16x8*)&out[(size_t)node * HD + l * 8] = o;
    }
}

// ---------------- batch norm finalize (also re-zeroes stat for next layer) ----
__global__ void k_bn_final(float* __restrict__ stat,
                           const float* __restrict__ gamma, const float* __restrict__ beta,
                           float* __restrict__ scale, float* __restrict__ shift) {
    int c = threadIdx.x;
    float mu = stat[c] * (1.0f / NN);
    float var = stat[HD + c] * (1.0f / NN) - mu * mu;
    float rs = rsqrtf(var + 1e-5f);
    float sc = rs * gamma[c];
    scale[c] = sc;
    shift[c] = beta[c] - mu * sc;
    stat[c] = 0.f;
    stat[HD + c] = 0.f;
}

__device__ __forceinline__ void bnpack(float4 g0, float4 g1, float4 s0, float4 s1,
                                       float4 h0, float4 h1, float4 o0, float4 o1, f16x8& r) {
    r[0] = (_Float16)(g0.x * s0.x + h0.x + o0.x);
    r[1] = (_Float16)(g0.y * s0.y + h0.y + o0.y);
    r[2] = (_Float16)(g0.z * s0.z + h0.z + o0.z);
    r[3] = (_Float16)(g0.w * s0.w + h0.w + o0.w);
    r[4] = (_Float16)(g1.x * s1.x + h1.x + o1.x);
    r[5] = (_Float16)(g1.y * s1.y + h1.y + o1.y);
    r[6] = (_Float16)(g1.z * s1.z + h1.z + o1.z);
    r[7] = (_Float16)(g1.w * s1.w + h1.w + o1.w);
}

// ======== fused back-to-back FFNN (round-10 proven version, all-LDS) ========
template <bool ABN1, bool RES2, bool RESBN2, bool STATS2, bool O32, bool O16>
__global__ __launch_bounds__(512) void k_b2b(const _Float16* __restrict__ A16,
                                             const float* __restrict__ A32,
                                             const _Float16* __restrict__ W1t,
                                             const float* __restrict__ b1,
                                             const _Float16* __restrict__ W2t,
                                             const float* __restrict__ b2,
                                             const float* __restrict__ R32,
                                             const float* __restrict__ bnsc,
                                             const float* __restrict__ bnsh,
                                             const float* __restrict__ ovn,
                                             const int* __restrict__ batchv,
                                             float* __restrict__ stat,
                                             float* __restrict__ C32,
                                             _Float16* __restrict__ C16,
                                             int M, int K1) {
    __shared__ _Float16 As[2][4][64][8];    // 8 KB
    __shared__ _Float16 Bs[2][4][256][8];   // 32 KB
    __shared__ _Float16 C1L[32][64][8];     // 32 KB
    const int t = threadIdx.x;
    const int w = t >> 6, lane = t & 63;
    const int m0 = blockIdx.x * 64;
    const int kb = lane >> 4, fr = lane & 15, rr = lane >> 4;

    auto stageB = [&](int buf, int k0, const _Float16* Wt, int KB) {
        int s0 = t, s1 = t + 512;
        gl_lds16(Wt + (size_t)(s0 & 255) * KB + k0 + (s0 >> 8) * 8, &Bs[buf][s0 >> 8][s0 & 255][0]);
        gl_lds16(Wt + (size_t)(s1 & 255) * KB + k0 + (s1 >> 8) * 8, &Bs[buf][s1 >> 8][s1 & 255][0]);
    };
    int b0 = 0;
    if constexpr (ABN1) {
        if (t < 256) b0 = batchv[min(m0 + (t & 63), M - 1)];
    }
    auto stageA = [&](int buf, int k0) {
        if constexpr (ABN1) {
            if (t < 256) {
                int ar = t & 63, akb = t >> 6;
                const int c0 = k0 + akb * 8;
                float4 s0 = *(const float4*)&bnsc[c0];
                float4 s1 = *(const float4*)&bnsc[c0 + 4];
                float4 h0 = *(const float4*)&bnsh[c0];
                float4 h1 = *(const float4*)&bnsh[c0 + 4];
                const float* ga = A32 + (size_t)(m0 + ar) * HD + c0;
                float4 ga0 = *(const float4*)ga;
                float4 ga1 = *(const float4*)(ga + 4);
                float4 oa0 = *(const float4*)&ovn[(size_t)b0 * HD + c0];
                float4 oa1 = *(const float4*)&ovn[(size_t)b0 * HD + c0 + 4];
                f16x8 r0;
                bnpack(ga0, ga1, s0, s1, h0, h1, oa0, oa1, r0);
                *(f16x8*)&As[buf][akb][ar][0] = r0;
            }
        } else {
            if (w < 4)
                gl_lds16(A16 + (size_t)(m0 + lane) * K1 + k0 + w * 8, &As[buf][w][lane][0]);
        }
    };

    // ---- stage 1 ----
    f32x4 acc1[4][2];
#pragma unroll
    for (int mi = 0; mi < 4; ++mi)
#pragma unroll
        for (int ni = 0; ni < 2; ++ni) acc1[mi][ni] = (f32x4){0.f, 0.f, 0.f, 0.f};

    const int nt1 = K1 >> 5;
    stageA(0, 0);
    stageB(0, 0, W1t, K1);
    __syncthreads();
    for (int tt = 0; tt < nt1; ++tt) {
        const int cur = tt & 1;
        if (tt + 1 < nt1) {
            stageA(cur ^ 1, (tt + 1) << 5);
            stageB(cur ^ 1, (tt + 1) << 5, W1t, K1);
        }
        f16x8 af[4], bf[2];
#pragma unroll
        for (int mi = 0; mi < 4; ++mi)
            af[mi] = *(const f16x8*)&As[cur][kb][mi * 16 + fr][0];
#pragma unroll
        for (int ni = 0; ni < 2; ++ni)
            bf[ni] = *(const f16x8*)&Bs[cur][kb][w * 32 + ni * 16 + fr][0];
#pragma unroll
        for (int mi = 0; mi < 4; ++mi)
#pragma unroll
            for (int ni = 0; ni < 2; ++ni)
                acc1[mi][ni] = __builtin_amdgcn_mfma_f32_16x16x32_f16(af[mi], bf[ni], acc1[mi][ni], 0, 0, 0);
        __syncthreads();
    }

    // issue first W2 tile while writing C1 to LDS
    stageB(0, 0, W2t, HD);
#pragma unroll
    for (int mi = 0; mi < 4; ++mi) {
#pragma unroll
        for (int reg = 0; reg < 4; ++reg) {
            int ml = mi * 16 + rr * 4 + reg;
#pragma unroll
            for (int ni = 0; ni < 2; ++ni) {
                int n = w * 32 + ni * 16 + fr;
                float v = gelu_exact(acc1[mi][ni][reg] + b1[n]);
                C1L[n >> 3][ml][n & 7] = (_Float16)v;
            }
        }
    }
    __syncthreads();

    // ---- stage 2 (K2 = 256) ----
    f32x4 acc2[4][2];
#pragma unroll
    for (int mi = 0; mi < 4; ++mi)
#pragma unroll
        for (int ni = 0; ni < 2; ++ni) acc2[mi][ni] = (f32x4){0.f, 0.f, 0.f, 0.f};

    for (int tt = 0; tt < 8; ++tt) {
        const int cur = tt & 1;
        if (tt + 1 < 8) stageB(cur ^ 1, (tt + 1) << 5, W2t, HD);
        f16x8 af[4], bf[2];
#pragma unroll
        for (int mi = 0; mi < 4; ++mi)
            af[mi] = *(const f16x8*)&C1L[tt * 4 + kb][mi * 16 + fr][0];
#pragma unroll
        for (int ni = 0; ni < 2; ++ni)
            bf[ni] = *(const f16x8*)&Bs[cur][kb][w * 32 + ni * 16 + fr][0];
#pragma unroll
        for (int mi = 0; mi < 4; ++mi)
#pragma unroll
            for (int ni = 0; ni < 2; ++ni)
                acc2[mi][ni] = __builtin_amdgcn_mfma_f32_16x16x32_f16(af[mi], bf[ni], acc2[mi][ni], 0, 0, 0);
        __syncthreads();
    }

    // ---- epilogue 2 ----
    float cs[2] = {0.f, 0.f}, cq[2] = {0.f, 0.f};
#pragma unroll
    for (int mi = 0; mi < 4; ++mi) {
#pragma unroll
        for (int reg = 0; reg < 4; ++reg) {
            int m = m0 + mi * 16 + rr * 4 + reg;
            if (m < M) {
#pragma unroll
                for (int ni = 0; ni < 2; ++ni) {
                    int n = w * 32 + ni * 16 + fr;
                    float v = acc2[mi][ni][reg] + b2[n];
                    if (RES2) v += R32[(size_t)m * HD + n];
                    if (RESBN2) v += R32[(size_t)m * HD + n] * bnsc[n] + bnsh[n];
                    if (O32) C32[(size_t)m * HD + n] = v;
                    if (O16) C16[(size_t)m * HD + n] = (_Float16)v;
                    if (STATS2) { cs[ni] += v; cq[ni] += v * v; }
                }
            }
        }
    }
    if constexpr (STATS2) {
#pragma unroll
        for (int ni = 0; ni < 2; ++ni) {
            cs[ni] += __shfl_xor(cs[ni], 16); cs[ni] += __shfl_xor(cs[ni], 32);
            cq[ni] += __shfl_xor(cq[ni], 16); cq[ni] += __shfl_xor(cq[ni], 32);
        }
        if (lane < 16) {
#pragma unroll
            for (int ni = 0; ni < 2; ++ni) {
                int n = w * 32 + ni * 16 + lane;
                atomicAdd(&stat[n], cs[ni]);
                atomicAdd(&stat[HD + n], cq[ni]);
            }
        }
    }
}

// ======== fused VN chain: outvn = ffnn(vn + ffnn(pool)) — one kernel ========
// 16 blocks x 32 group-rows, 256 threads (4 waves). Row-local after pooling, so
// the 4 GEMMs chain in LDS. B-fragments direct from global (L2-hot weights).
// Same rounding points as the old 4-GEMM path (fp16 u, vb, pr).
#define VP 264   // padded row stride (f16) for 256-col bufs
#define VP4 1032 // padded row stride for 1024-col buf
__global__ __launch_bounds__(256) void k_vn4(const _Float16* __restrict__ pool,
                                             const _Float16* __restrict__ uW1t, const float* __restrict__ ub1,
                                             const _Float16* __restrict__ uW2t, const float* __restrict__ ub2,
                                             const _Float16* __restrict__ pW1t, const float* __restrict__ pb1,
                                             const _Float16* __restrict__ pW2t, const float* __restrict__ pb2,
                                             const float* __restrict__ vn,
                                             float* __restrict__ outvn) {
    __shared__ _Float16 bufA[32][VP];    // pool -> pr
    __shared__ _Float16 bufU[32][VP];    // u
    __shared__ _Float16 vbL[32][VP4];    // vb
    const int t = threadIdx.x;
    const int w = t >> 6, lane = t & 63;
    const int kb = lane >> 4, fr = lane & 15, rr = lane >> 4;
    const int g0 = blockIdx.x * 32;

    // load pool rows (32 x 256 f16)
    {
        int row = t >> 3, seg = t & 7;          // 256 threads: 32 rows x 8 segs of 32B
        const f16x8* src = (const f16x8*)(pool + (size_t)(g0 + row) * HD + seg * 16);
        f16x8* dst = (f16x8*)&bufA[row][seg * 16];
        dst[0] = src[0];
        dst[1] = src[1];
    }
    __syncthreads();

    // ---- stage 1: u = gelu(pool@uW1 + ub1)   N=256 K=256 ----
    {
        f32x4 acc[2][4];
#pragma unroll
        for (int mi = 0; mi < 2; ++mi)
#pragma unroll
            for (int ni = 0; ni < 4; ++ni) acc[mi][ni] = (f32x4){0.f, 0.f, 0.f, 0.f};
#pragma unroll
        for (int ks = 0; ks < 8; ++ks) {
            int k0 = ks * 32 + kb * 8;
            f16x8 af[2], bf[4];
#pragma unroll
            for (int mi = 0; mi < 2; ++mi)
                af[mi] = *(const f16x8*)&bufA[mi * 16 + fr][k0];
#pragma unroll
            for (int ni = 0; ni < 4; ++ni)
                bf[ni] = *(const f16x8*)&uW1t[(size_t)(w * 64 + ni * 16 + fr) * HD + k0];
#pragma unroll
            for (int mi = 0; mi < 2; ++mi)
#pragma unroll
                for (int ni = 0; ni < 4; ++ni)
                    acc[mi][ni] = __builtin_amdgcn_mfma_f32_16x16x32_f16(af[mi], bf[ni], acc[mi][ni], 0, 0, 0);
        }
#pragma unroll
        for (int mi = 0; mi < 2; ++mi)
#pragma unroll
            for (int reg = 0; reg < 4; ++reg)
#pragma unroll
                for (int ni = 0; ni < 4; ++ni) {
                    int row = mi * 16 + rr * 4 + reg, col = w * 64 + ni * 16 + fr;
                    bufU[row][col] = (_Float16)gelu_exact(acc[mi][ni][reg] + ub1[col]);
                }
    }
    __syncthreads();

    // ---- stage 2: vb = u@uW2 + ub2 + vn   N=1024 K=256 ----
    {
        f32x4 acc[2][16];
#pragma unroll
        for (int mi = 0; mi < 2; ++mi)
#pragma unroll
            for (int ni = 0; ni < 16; ++ni) acc[mi][ni] = (f32x4){0.f, 0.f, 0.f, 0.f};
#pragma unroll
        for (int ks = 0; ks < 8; ++ks) {
            int k0 = ks * 32 + kb * 8;
            f16x8 af[2];
#pragma unroll
            for (int mi = 0; mi < 2; ++mi)
                af[mi] = *(const f16x8*)&bufU[mi * 16 + fr][k0];
#pragma unroll
            for (int ni = 0; ni < 16; ++ni) {
                f16x8 bf = *(const f16x8*)&uW2t[(size_t)(w * 256 + ni * 16 + fr) * HD + k0];
#pragma unroll
                for (int mi = 0; mi < 2; ++mi)
                    acc[mi][ni] = __builtin_amdgcn_mfma_f32_16x16x32_f16(af[mi], bf, acc[mi][ni], 0, 0, 0);
            }
        }
#pragma unroll
        for (int mi = 0; mi < 2; ++mi)
#pragma unroll
            for (int reg = 0; reg < 4; ++reg)
#pragma unroll
                for (int ni = 0; ni < 16; ++ni) {
                    int row = mi * 16 + rr * 4 + reg, col = w * 256 + ni * 16 + fr;
                    vbL[row][col] = (_Float16)(acc[mi][ni][reg] + ub2[col] + vn[col]);
                }
    }
    __syncthreads();

    // ---- stage 3: pr = gelu(vb@pW1 + pb1)   N=256 K=1024 (writes bufA) ----
    {
        f32x4 acc[2][4];
#pragma unroll
        for (int mi = 0; mi < 2; ++mi)
#pragma unroll
            for (int ni = 0; ni < 4; ++ni) acc[mi][ni] = (f32x4){0.f, 0.f, 0.f, 0.f};
        for (int ks = 0; ks < 32; ++ks) {
            int k0 = ks * 32 + kb * 8;
            f16x8 af[2], bf[4];
#pragma unroll
            for (int mi = 0; mi < 2; ++mi)
                af[mi] = *(const f16x8*)&vbL[mi * 16 + fr][k0];
#pragma unroll
            for (int ni = 0; ni < 4; ++ni)
                bf[ni] = *(const f16x8*)&pW1t[(size_t)(w * 64 + ni * 16 + fr) * H4 + k0];
#pragma unroll
            for (int mi = 0; mi < 2; ++mi)
#pragma unroll
                for (int ni = 0; ni < 4; ++ni)
                    acc[mi][ni] = __builtin_amdgcn_mfma_f32_16x16x32_f16(af[mi], bf[ni], acc[mi][ni], 0, 0, 0);
        }
        __syncthreads();   // everyone done reading bufA? (it was idle) — protects bufA rewrite vs stage-1 stragglers on other waves reading bufU only; cheap
#pragma unroll
        for (int mi = 0; mi < 2; ++mi)
#pragma unroll
            for (int reg = 0; reg < 4; ++reg)
#pragma unroll
                for (int ni = 0; ni < 4; ++ni) {
                    int row = mi * 16 + rr * 4 + reg, col = w * 64 + ni * 16 + fr;
                    bufA[row][col] = (_Float16)gelu_exact(acc[mi][ni][reg] + pb1[col]);
                }
    }
    __syncthreads();

    // ---- stage 4: outvn = pr@pW2 + pb2   N=256 K=256 ----
    {
        f32x4 acc[2][4];
#pragma unroll
        for (int mi = 0; mi < 2; ++mi)
#pragma unroll
            for (int ni = 0; ni < 4; ++ni) acc[mi][ni] = (f32x4){0.f, 0.f, 0.f, 0.f};
#pragma unroll
        for (int ks = 0; ks < 8; ++ks) {
            int k0 = ks * 32 + kb * 8;
            f16x8 af[2], bf[4];
#pragma unroll
            for (int mi = 0; mi < 2; ++mi)
                af[mi] = *(const f16x8*)&bufA[mi * 16 + fr][k0];
#pragma unroll
            for (int ni = 0; ni < 4; ++ni)
                bf[ni] = *(const f16x8*)&pW2t[(size_t)(w * 64 + ni * 16 + fr) * HD + k0];
#pragma unroll
            for (int mi = 0; mi < 2; ++mi)
#pragma unroll
                for (int ni = 0; ni < 4; ++ni)
                    acc[mi][ni] = __builtin_amdgcn_mfma_f32_16x16x32_f16(af[mi], bf[ni], acc[mi][ni], 0, 0, 0);
        }
#pragma unroll
        for (int mi = 0; mi < 2; ++mi)
#pragma unroll
            for (int reg = 0; reg < 4; ++reg)
#pragma unroll
                for (int ni = 0; ni < 4; ++ni) {
                    int row = mi * 16 + rr * 4 + reg, col = w * 64 + ni * 16 + fr;
                    outvn[(size_t)(g0 + row) * HD + col] = acc[mi][ni][reg] + pb2[col];
                }
    }
}

// ---------------- MFMA fp16 GEMM (64x128 tile) — post path only ----------------
template <bool GELU, bool O32, bool O16>
__global__ __launch_bounds__(256) void k_mgemm(const _Float16* __restrict__ A,
                                               const _Float16* __restrict__ Wt,
                                               const float* __restrict__ bias,
                                               float* __restrict__ C32,
                                               _Float16* __restrict__ C16,
                                               int M, int N, int K) {
    __shared__ _Float16 As[2][4][64][8];
    __shared__ _Float16 Bs[2][4][128][8];
    const int t = threadIdx.x;
    const int w = t >> 6, lane = t & 63;
    const int m0 = blockIdx.y * 64, n0 = blockIdx.x * 128;
    const int kb = lane >> 4, fr = lane & 15;

    f32x4 acc[4][2];
#pragma unroll
    for (int mi = 0; mi < 4; ++mi)
#pragma unroll
        for (int ni = 0; ni < 2; ++ni) acc[mi][ni] = (f32x4){0.f, 0.f, 0.f, 0.f};

    const _Float16* gA0 = A + (size_t)(m0 + lane) * K + w * 8;
    const _Float16* gB0 = Wt + (size_t)(n0 + lane) * K + w * 8;
    const _Float16* gB1 = Wt + (size_t)(n0 + 64 + lane) * K + w * 8;

    auto stage = [&](int buf, int k0) {
        gl_lds16(gB0 + k0, &Bs[buf][w][0][0]);
        gl_lds16(gB1 + k0, &Bs[buf][w][64][0]);
        gl_lds16(gA0 + k0, &As[buf][w][0][0]);
    };

    const int nt = K >> 5;
    stage(0, 0);
    __syncthreads();
    for (int tt = 0; tt < nt; ++tt) {
        const int cur = tt & 1;
        if (tt + 1 < nt) stage(cur ^ 1, (tt + 1) << 5);
        f16x8 af[4], bf[2];
#pragma unroll
        for (int mi = 0; mi < 4; ++mi)
            af[mi] = *(const f16x8*)&As[cur][kb][mi * 16 + fr][0];
#pragma unroll
        for (int ni = 0; ni < 2; ++ni)
            bf[ni] = *(const f16x8*)&Bs[cur][kb][w * 32 + ni * 16 + fr][0];
#pragma unroll
        for (int mi = 0; mi < 4; ++mi)
#pragma unroll
            for (int ni = 0; ni < 2; ++ni)
                acc[mi][ni] = __builtin_amdgcn_mfma_f32_16x16x32_f16(af[mi], bf[ni], acc[mi][ni], 0, 0, 0);
        __syncthreads();
    }

    const int rr = lane >> 4;
#pragma unroll
    for (int mi = 0; mi < 4; ++mi) {
#pragma unroll
        for (int reg = 0; reg < 4; ++reg) {
            int m = m0 + mi * 16 + rr * 4 + reg;
            if (m < M) {
#pragma unroll
                for (int ni = 0; ni < 2; ++ni) {
                    int n = n0 + w * 32 + ni * 16 + fr;
                    float v = acc[mi][ni][reg] + bias[n];
                    if (GELU) v = gelu_exact(v);
                    if (O32) C32[(size_t)m * N + n] = v;
                    if (O16) C16[(size_t)m * N + n] = (_Float16)v;
                }
            }
        }
    }
}

static inline void mg_gelu(hipStream_t st, const _Float16* A, const _Float16* Wt,
                           const float* bias, _Float16* C16, int M, int N, int K) {
    dim3 g(N / 128, (M + 63) / 64), b(256);
    k_mgemm<true, false, true><<<g, b, 0, st>>>(A, Wt, bias, nullptr, C16, M, N, K);
}
static inline void mg_f32only(hipStream_t st, const _Float16* A, const _Float16* Wt,
                              const float* bias, float* C32, int M, int N, int K) {
    dim3 g(N / 128, (M + 63) / 64), b(256);
    k_mgemm<false, true, false><<<g, b, 0, st>>>(A, Wt, bias, C32, nullptr, M, N, K);
}

extern "C" void kernel_launch(void* const* d_in, const int* in_sizes, int n_in,
                              void* d_out, int out_size, void* d_ws, size_t ws_size,
                              hipStream_t stream) {
    const float* x       = (const float*)d_in[0];
    const int*   ei      = (const int*)d_in[1];
    const int*   batch   = (const int*)d_in[2];
    const float* pre_W1  = (const float*)d_in[3];
    const float* pre_b1  = (const float*)d_in[4];
    const float* pre_W2  = (const float*)d_in[5];
    const float* pre_b2  = (const float*)d_in[6];
    const float* gin_W1  = (const float*)d_in[7];
    const float* gin_b1  = (const float*)d_in[8];
    const float* gin_W2  = (const float*)d_in[9];
    const float* gin_b2  = (const float*)d_in[10];
    const float* ffn_W1  = (const float*)d_in[11];
    const float* ffn_b1  = (const float*)d_in[12];
    const float* ffn_W2  = (const float*)d_in[13];
    const float* ffn_b2  = (const float*)d_in[14];
    const float* upd_W1  = (const float*)d_in[15];
    const float* upd_b1  = (const float*)d_in[16];
    const float* upd_W2  = (const float*)d_in[17];
    const float* upd_b2  = (const float*)d_in[18];
    const float* prop_W1 = (const float*)d_in[19];
    const float* prop_b1 = (const float*)d_in[20];
    const float* prop_W2 = (const float*)d_in[21];
    const float* prop_b2 = (const float*)d_in[22];
    const float* bn_gamma= (const float*)d_in[23];
    const float* bn_beta = (const float*)d_in[24];
    const float* vn      = (const float*)d_in[25];
    const float* post_W1 = (const float*)d_in[26];
    const float* post_b1 = (const float*)d_in[27];
    const float* post_W2 = (const float*)d_in[28];
    const float* post_b2 = (const float*)d_in[29];
    float* out = (float*)d_out;

    const int* e_src = ei;
    const int* e_dst = ei + NE;

    // ---------- workspace layout ----------
    char* p = (char*)d_ws;
    auto alloc = [&](size_t bytes) -> char* {
        char* r = p;
        p += (bytes + 255) & ~(size_t)255;
        return r;
    };
    float*    h32    = (float*)alloc((size_t)NNP * HD * 4);
    float*    g32    = (float*)alloc((size_t)NNP * HD * 4);
    _Float16* h16    = (_Float16*)alloc((size_t)NNP * HD * 2);
    _Float16* t16a   = (_Float16*)alloc((size_t)NNP * HD * 2);  // agg out; aliases x16 pre-launch
    _Float16* pool16 = (_Float16*)alloc((size_t)NG * HD * 2);
    _Float16* u16    = (_Float16*)alloc((size_t)NG * HD * 2);
    float*    outvn32= (float*)alloc((size_t)NG * HD * 4);
    float*    bnstat = (float*)alloc(2 * HD * 4);
    float*    bnscale= (float*)alloc(HD * 4);
    float*    bnshift= (float*)alloc(HD * 4);
    _Float16* preW1t = (_Float16*)alloc((size_t)HD * DIN * 2);
    _Float16* preW2t = (_Float16*)alloc((size_t)HD * HD * 2);
    _Float16* ginW1t = (_Float16*)alloc((size_t)NL * HD * HD * 2);
    _Float16* ginW2t = (_Float16*)alloc((size_t)NL * HD * HD * 2);
    _Float16* ffnW1t = (_Float16*)alloc((size_t)NL * HD * HD * 2);
    _Float16* ffnW2t = (_Float16*)alloc((size_t)NL * HD * HD * 2);
    _Float16* updW1t = (_Float16*)alloc((size_t)NL * HD * HD * 2);
    _Float16* updW2t = (_Float16*)alloc((size_t)NL * HD * H4 * 2);
    _Float16* propW1t= (_Float16*)alloc((size_t)NL * H4 * HD * 2);
    _Float16* propW2t= (_Float16*)alloc((size_t)NL * HD * HD * 2);
    _Float16* postW1t= (_Float16*)alloc((size_t)HD * HD * 2);
    _Float16* postW2t= (_Float16*)alloc((size_t)DOUT * HD * 2);
    int* gcount = (int*)alloc(NG * 4);
    int* goff   = (int*)alloc((NG + 1) * 4);
    int* deg    = (int*)alloc(NN * 4);
    int* eoff   = (int*)alloc((NN + 1) * 4);
    int* cursor = (int*)alloc(NN * 4);
    int* csr    = (int*)alloc((size_t)NE * 4);
    int* bsum   = (int*)alloc(1024 * 4);
    int* bexcl  = (int*)alloc(1024 * 4);
    _Float16* x16 = t16a;   // alias: consumed by pre-pair before t16a is first written

    // ---------- zero counters + bnstat ----------
    {
        size_t span = (size_t)((char*)(cursor + NN) - (char*)gcount);
        hipMemsetAsync(gcount, 0, span, stream);
        hipMemsetAsync(bnstat, 0, 2 * HD * 4, stream);
    }
    hipLaunchKernelGGL(k_hist, dim3((NN + 255) / 256), dim3(256), 0, stream, batch, gcount, NN);
    hipLaunchKernelGGL(k_hist, dim3((NE + 255) / 256), dim3(256), 0, stream, e_dst, deg, NE);
    hipLaunchKernelGGL(k_scan_small, dim3(1), dim3(1024), 0, stream, gcount, goff, NG);
    {
        int nbN = (NN + 255) / 256;
        hipLaunchKernelGGL(k_scan_part, dim3(nbN), dim3(256), 0, stream, deg, bsum, NN);
        hipLaunchKernelGGL(k_scan_mid, dim3(1), dim3(1024), 0, stream, bsum, bexcl, nbN, eoff, NN);
        hipLaunchKernelGGL(k_scan_out, dim3(nbN), dim3(256), 0, stream, deg, bexcl, eoff, NN);
    }
    hipLaunchKernelGGL(k_fill_csr, dim3((NE + 255) / 256), dim3(256), 0, stream, e_src, e_dst, eoff, cursor, csr, NE);

    // ---------- batched weight transpose (one launch) ----------
    {
        WtJobs j;
        int idx = 0, tiles = 0;
        auto add = [&](const float* s, _Float16* d, int K, int N) {
            j.src[idx] = s; j.dst[idx] = d;
            j.K32[idx] = (short)(K / 32); j.N32[idx] = (short)(N / 32);
            j.pre[idx] = (short)tiles;
            tiles += (K / 32) * (N / 32);
            ++idx;
        };
        add(pre_W1, preW1t, DIN, HD);
        add(pre_W2, preW2t, HD, HD);
        add(post_W1, postW1t, HD, HD);
        add(post_W2, postW2t, HD, DOUT);
        for (int i = 0; i < NL; ++i) {
            add(gin_W1 + (size_t)i * HD * HD, ginW1t + (size_t)i * HD * HD, HD, HD);
            add(gin_W2 + (size_t)i * HD * HD, ginW2t + (size_t)i * HD * HD, HD, HD);
            add(ffn_W1 + (size_t)i * HD * HD, ffnW1t + (size_t)i * HD * HD, HD, HD);
            add(ffn_W2 + (size_t)i * HD * HD, ffnW2t + (size_t)i * HD * HD, HD, HD);
            add(upd_W1 + (size_t)i * HD * HD, updW1t + (size_t)i * HD * HD, HD, HD);
            add(upd_W2 + (size_t)i * HD * H4, updW2t + (size_t)i * HD * H4, HD, H4);
            add(prop_W1 + (size_t)i * H4 * HD, propW1t + (size_t)i * H4 * HD, H4, HD);
            add(prop_W2 + (size_t)i * HD * HD, propW2t + (size_t)i * HD * HD, HD, HD);
        }
        j.pre[idx] = (short)tiles;
        hipLaunchKernelGGL(k_wtb, dim3(tiles), dim3(32, 8), 0, stream, j);
    }

    // x -> fp16
    int n4 = NN * DIN / 4;
    hipLaunchKernelGGL(k_cvt16, dim3((n4 + 255) / 256), dim3(256), 0, stream, x, x16, n4);

    const int nb2b = NNP / 64;

    // ---------- pre-FFNN (fused pair): h32/h16 = gelu(x@W1+b1)@W2+b2 ----------
    hipLaunchKernelGGL((k_b2b<false, false, false, false, true, true>), dim3(nb2b), dim3(512), 0, stream,
                       x16, nullptr, preW1t, pre_b1, preW2t, pre_b2,
                       nullptr, nullptr, nullptr, nullptr, nullptr, nullptr,
                       h32, h16, NN, DIN);

    for (int i = 0; i < NL; ++i) {
        // virtual-node path: pool + fused 4-GEMM chain
        hipLaunchKernelGGL(k_pool16, dim3(NG), dim3(HD), 0, stream, h16, goff, pool16);
        hipLaunchKernelGGL(k_vn4, dim3(NG / 32), dim3(256), 0, stream, pool16,
                           updW1t + (size_t)i * HD * HD, upd_b1 + (size_t)i * HD,
                           updW2t + (size_t)i * HD * H4, upd_b2 + (size_t)i * H4,
                           propW1t + (size_t)i * H4 * HD, prop_b1 + (size_t)i * HD,
                           propW2t + (size_t)i * HD * HD, prop_b2 + (size_t)i * HD,
                           vn, outvn32);

        // GIN: t16a = agg(h16); g32 = gelu(t16a@gW1+b1)@gW2+b2 + h32 (+BN stats)
        hipLaunchKernelGGL(k_agg16, dim3(NN / 4), dim3(256), 0, stream, h16, eoff, csr, t16a);
        hipLaunchKernelGGL((k_b2b<false, true, false, true, true, false>), dim3(nb2b), dim3(512), 0, stream,
                           t16a, nullptr,
                           ginW1t + (size_t)i * HD * HD, gin_b1 + (size_t)i * HD,
                           ginW2t + (size_t)i * HD * HD, gin_b2 + (size_t)i * HD,
                           h32, nullptr, nullptr, nullptr, nullptr, bnstat,
                           g32, nullptr, NN, HD);

        // BN finalize (re-zeroes stat)
        hipLaunchKernelGGL(k_bn_final, dim3(1), dim3(HD), 0, stream, bnstat,
                           bn_gamma + (size_t)i * HD, bn_beta + (size_t)i * HD, bnscale, bnshift);

        // FFN fused pair: h32/h16 = gelu((bn(g32)+ovn)@fW1+b1)@fW2+b2 + bn(g32)
        hipLaunchKernelGGL((k_b2b<true, false, true, false, true, true>), dim3(nb2b), dim3(512), 0, stream,
                           nullptr, g32,
                           ffnW1t + (size_t)i * HD * HD, ffn_b1 + (size_t)i * HD,
                           ffnW2t + (size_t)i * HD * HD, ffn_b2 + (size_t)i * HD,
                           g32, bnscale, bnshift, outvn32, batch, nullptr,
                           h32, h16, NN, HD);
    }

    // ---------- post ----------
    hipLaunchKernelGGL(k_pool16, dim3(NG), dim3(HD), 0, stream, h16, goff, pool16);
    mg_gelu(stream, pool16, postW1t, post_b1, u16, NG, HD, HD);
    mg_f32only(stream, u16, postW2t, post_b2, out, NG, DOUT, HD);
}

// Round 14
// 1688.590 us; speedup vs baseline: 1.0932x; 1.0932x over previous
//
#include <hip/hip_runtime.h>
#include <hip/hip_bf16.h>
#include <math.h>

#define NN 50000
#define NNP 50048          // padded to multiple of 128
#define NE 800000
#define NG 512
#define DIN 128
#define HD 256
#define DOUT 128
#define NL 5
#define H4 1024

typedef _Float16 f16x8 __attribute__((ext_vector_type(8)));
typedef _Float16 f16x4 __attribute__((ext_vector_type(4)));
typedef float f32x4 __attribute__((ext_vector_type(4)));

__device__ __forceinline__ float gelu_exact(float x) {
    return 0.5f * x * (1.0f + erff(x * 0.70710678118654752f));
}

__device__ __forceinline__ void gl_lds16(const _Float16* g, _Float16* l) {
    __builtin_amdgcn_global_load_lds(
        (const __attribute__((address_space(1))) unsigned int*)g,
        (__attribute__((address_space(3))) unsigned int*)l, 16, 0, 0);
}

// ---------------- graph meta ----------------
__global__ void k_hist(const int* __restrict__ idx, int* __restrict__ cnt, int n) {
    int i = blockIdx.x * blockDim.x + threadIdx.x;
    if (i < n) atomicAdd(&cnt[idx[i]], 1);
}

__global__ void k_scan_small(const int* __restrict__ in, int* __restrict__ out, int n) {
    __shared__ int buf[1024];
    int t = threadIdx.x;
    int v = (t < n) ? in[t] : 0;
    buf[t] = v;
    __syncthreads();
    for (int off = 1; off < 1024; off <<= 1) {
        int x = (t >= off) ? buf[t - off] : 0;
        __syncthreads();
        buf[t] += x;
        __syncthreads();
    }
    if (t < n) out[t] = buf[t] - v;
    if (t == 1023) out[n] = buf[1023];
}

__global__ void k_scan_part(const int* __restrict__ in, int* __restrict__ bsum, int n) {
    __shared__ int buf[256];
    int i = blockIdx.x * 256 + threadIdx.x;
    buf[threadIdx.x] = (i < n) ? in[i] : 0;
    __syncthreads();
    for (int off = 128; off > 0; off >>= 1) {
        if (threadIdx.x < off) buf[threadIdx.x] += buf[threadIdx.x + off];
        __syncthreads();
    }
    if (threadIdx.x == 0) bsum[blockIdx.x] = buf[0];
}

__global__ void k_scan_mid(const int* __restrict__ bsum, int* __restrict__ bexcl, int nb,
                           int* __restrict__ out, int n) {
    __shared__ int buf[1024];
    int t = threadIdx.x;
    int v = (t < nb) ? bsum[t] : 0;
    buf[t] = v;
    __syncthreads();
    for (int off = 1; off < 1024; off <<= 1) {
        int x = (t >= off) ? buf[t - off] : 0;
        __syncthreads();
        buf[t] += x;
        __syncthreads();
    }
    if (t < nb) bexcl[t] = buf[t] - v;
    if (t == 1023) out[n] = buf[1023];
}

__global__ void k_scan_out(const int* __restrict__ in, const int* __restrict__ bexcl,
                           int* __restrict__ out, int n) {
    __shared__ int buf[256];
    int i = blockIdx.x * 256 + threadIdx.x;
    int t = threadIdx.x;
    int v = (i < n) ? in[i] : 0;
    buf[t] = v;
    __syncthreads();
    for (int off = 1; off < 256; off <<= 1) {
        int x = (t >= off) ? buf[t - off] : 0;
        __syncthreads();
        buf[t] += x;
        __syncthreads();
    }
    if (i < n) out[i] = bexcl[blockIdx.x] + buf[t] - v;
}

__global__ void k_fill_csr(const int* __restrict__ src, const int* __restrict__ dst,
                           const int* __restrict__ eoff, int* __restrict__ cursor,
                           int* __restrict__ csr, int n) {
    int e = blockIdx.x * blockDim.x + threadIdx.x;
    if (e < n) {
        int d = dst[e];
        int p = atomicAdd(&cursor[d], 1);
        csr[eoff[d] + p] = src[e];
    }
}

// ---------------- converts ----------------
__global__ void k_cvt16(const float* __restrict__ in, _Float16* __restrict__ out, int n4) {
    int i = blockIdx.x * blockDim.x + threadIdx.x;
    if (i < n4) {
        float4 v = *(const float4*)&in[i * 4];
        f16x4 o = { (_Float16)v.x, (_Float16)v.y, (_Float16)v.z, (_Float16)v.w };
        *(f16x4*)&out[i * 4] = o;
    }
}

// batched transpose + convert: one launch for all weight matrices
#define NWTJOBS 44
struct WtJobs {
    const float* src[NWTJOBS];
    _Float16* dst[NWTJOBS];
    short K32[NWTJOBS];
    short N32[NWTJOBS];
    short pre[NWTJOBS + 1];
};
__global__ void k_wtb(WtJobs j) {
    int bid = blockIdx.x;
    int lo = 0;
    while (j.pre[lo + 1] <= bid) ++lo;
    int tl = bid - j.pre[lo];
    int nx = j.N32[lo];
    int n0 = (tl % nx) * 32, k0 = (tl / nx) * 32;
    int K = j.K32[lo] * 32, N = nx * 32;
    const float* W = j.src[lo];
    _Float16* Wt = j.dst[lo];
    __shared__ float tile[32][33];
    for (int i = threadIdx.y; i < 32; i += 8)
        tile[i][threadIdx.x] = W[(size_t)(k0 + i) * N + n0 + threadIdx.x];
    __syncthreads();
    for (int i = threadIdx.y; i < 32; i += 8)
        Wt[(size_t)(n0 + i) * K + k0 + threadIdx.x] = (_Float16)tile[threadIdx.x][i];
}

// ---------------- pooling / aggregation ----------------
__global__ void k_pool16(const _Float16* __restrict__ h16, const int* __restrict__ goff,
                         _Float16* __restrict__ pool) {
    int g = blockIdx.x;
    int c = threadIdx.x;
    int s = goff[g], e = goff[g + 1];
    float acc = 0.f;
    for (int r = s; r < e; ++r) acc += (float)h16[(size_t)r * HD + c];
    int cnt = e - s;
    pool[g * HD + c] = (_Float16)(acc / (float)(cnt > 0 ? cnt : 1));
}

// one wave per node; WAVE-UNIFORM loop bounds; 8 edges/iter
__global__ __launch_bounds__(256) void k_agg16(const _Float16* __restrict__ h16,
                                               const int* __restrict__ eoff,
                                               const int* __restrict__ csr,
                                               _Float16* __restrict__ out) {
    int node = blockIdx.x * 4 + (threadIdx.x >> 6);
    int lane = threadIdx.x & 63;
    int half = lane >> 5, l = lane & 31;
    f16x8 mine = *(const f16x8*)&h16[(size_t)node * HD + l * 8];
    float acc[8];
#pragma unroll
    for (int q = 0; q < 8; ++q) acc[q] = half ? 0.f : (float)mine[q];
    int s = eoff[node], e = eoff[node + 1];
    for (int base = s; base < e; base += 64) {
        int myi = base + lane;
        int vidx = (myi < e) ? csr[myi] : 0;
        int cnt = min(64, e - base);
        int jj = 0;
        for (; jj + 7 < cnt; jj += 8) {
            int s0 = __shfl(vidx, jj + half);
            int s1 = __shfl(vidx, jj + 2 + half);
            int s2 = __shfl(vidx, jj + 4 + half);
            int s3 = __shfl(vidx, jj + 6 + half);
            f16x8 v0 = *(const f16x8*)&h16[(size_t)s0 * HD + l * 8];
            f16x8 v1 = *(const f16x8*)&h16[(size_t)s1 * HD + l * 8];
            f16x8 v2 = *(const f16x8*)&h16[(size_t)s2 * HD + l * 8];
            f16x8 v3 = *(const f16x8*)&h16[(size_t)s3 * HD + l * 8];
#pragma unroll
            for (int q = 0; q < 8; ++q)
                acc[q] += ((float)v0[q] + (float)v1[q]) + ((float)v2[q] + (float)v3[q]);
        }
        for (; jj + 3 < cnt; jj += 4) {
            int s0 = __shfl(vidx, jj + half);
            int s1 = __shfl(vidx, jj + 2 + half);
            f16x8 v0 = *(const f16x8*)&h16[(size_t)s0 * HD + l * 8];
            f16x8 v1 = *(const f16x8*)&h16[(size_t)s1 * HD + l * 8];
#pragma unroll
            for (int q = 0; q < 8; ++q) acc[q] += (float)v0[q] + (float)v1[q];
        }
        for (; jj < cnt; jj += 2) {
            int i0 = jj + half;
            int s0 = __shfl(vidx, i0);
            if (i0 < cnt) {
                f16x8 v0 = *(const f16x8*)&h16[(size_t)s0 * HD + l * 8];
#pragma unroll
                for (int q = 0; q < 8; ++q) acc[q] += (float)v0[q];
            }
        }
    }
#pragma unroll
    for (int q = 0; q < 8; ++q) acc[q] += __shfl_xor(acc[q], 32);
    if (!half) {
        f16x8 o;
#pragma unroll
        for (int q = 0; q < 8; ++q) o[q] = (_Float16)acc[q];
        *(f16x8*)&out[(size_t)node * HD + l * 8] = o;
    }
}

// ---------------- batch norm finalize (also re-zeroes stat for next layer) ----
__global__ void k_bn_final(float* __restrict__ stat,
                           const float* __restrict__ gamma, const float* __restrict__ beta,
                           float* __restrict__ scale, float* __restrict__ shift) {
    int c = threadIdx.x;
    float mu = stat[c] * (1.0f / NN);
    float var = stat[HD + c] * (1.0f / NN) - mu * mu;
    float rs = rsqrtf(var + 1e-5f);
    float sc = rs * gamma[c];
    scale[c] = sc;
    shift[c] = beta[c] - mu * sc;
    stat[c] = 0.f;
    stat[HD + c] = 0.f;
}

// ======== fused back-to-back FFNN (r10-proven all-LDS; fp16 backbone) ========
// C16 = gelu(A@W1+b1)@W2+b2 [+res].  A from fp16 A16, or (ABN1) from fp16 G16
// with bn+vn transform.  RES2: +R16.  RESBN2: +R16*bnsc+bnsh.  STATS2: BN column
// stats computed on the STORED (fp16-rounded) output values.
template <bool ABN1, bool RES2, bool RESBN2, bool STATS2>
__global__ __launch_bounds__(512) void k_b2b(const _Float16* __restrict__ A16,
                                             const _Float16* __restrict__ G16,
                                             const _Float16* __restrict__ W1t,
                                             const float* __restrict__ b1,
                                             const _Float16* __restrict__ W2t,
                                             const float* __restrict__ b2,
                                             const _Float16* __restrict__ R16,
                                             const float* __restrict__ bnsc,
                                             const float* __restrict__ bnsh,
                                             const float* __restrict__ ovn,
                                             const int* __restrict__ batchv,
                                             float* __restrict__ stat,
                                             _Float16* __restrict__ C16,
                                             int M, int K1) {
    __shared__ _Float16 As[2][4][64][8];    // 8 KB
    __shared__ _Float16 Bs[2][4][256][8];   // 32 KB
    __shared__ _Float16 C1L[32][64][8];     // 32 KB
    const int t = threadIdx.x;
    const int w = t >> 6, lane = t & 63;
    const int m0 = blockIdx.x * 64;
    const int kb = lane >> 4, fr = lane & 15, rr = lane >> 4;

    auto stageB = [&](int buf, int k0, const _Float16* Wt, int KB) {
        int s0 = t, s1 = t + 512;
        gl_lds16(Wt + (size_t)(s0 & 255) * KB + k0 + (s0 >> 8) * 8, &Bs[buf][s0 >> 8][s0 & 255][0]);
        gl_lds16(Wt + (size_t)(s1 & 255) * KB + k0 + (s1 >> 8) * 8, &Bs[buf][s1 >> 8][s1 & 255][0]);
    };
    int b0 = 0;
    if constexpr (ABN1) {
        if (t < 256) b0 = batchv[min(m0 + (t & 63), M - 1)];
    }
    auto stageA = [&](int buf, int k0) {
        if constexpr (ABN1) {
            if (t < 256) {
                int ar = t & 63, akb = t >> 6;
                const int c0 = k0 + akb * 8;
                f16x8 g = *(const f16x8*)&G16[(size_t)(m0 + ar) * HD + c0];
                f16x8 r0;
#pragma unroll
                for (int q = 0; q < 8; ++q) {
                    int c = c0 + q;
                    r0[q] = (_Float16)((float)g[q] * bnsc[c] + bnsh[c] + ovn[(size_t)b0 * HD + c]);
                }
                *(f16x8*)&As[buf][akb][ar][0] = r0;
            }
        } else {
            if (w < 4)
                gl_lds16(A16 + (size_t)(m0 + lane) * K1 + k0 + w * 8, &As[buf][w][lane][0]);
        }
    };

    // ---- stage 1 ----
    f32x4 acc1[4][2];
#pragma unroll
    for (int mi = 0; mi < 4; ++mi)
#pragma unroll
        for (int ni = 0; ni < 2; ++ni) acc1[mi][ni] = (f32x4){0.f, 0.f, 0.f, 0.f};

    const int nt1 = K1 >> 5;
    stageA(0, 0);
    stageB(0, 0, W1t, K1);
    __syncthreads();
    for (int tt = 0; tt < nt1; ++tt) {
        const int cur = tt & 1;
        if (tt + 1 < nt1) {
            stageA(cur ^ 1, (tt + 1) << 5);
            stageB(cur ^ 1, (tt + 1) << 5, W1t, K1);
        }
        f16x8 af[4], bf[2];
#pragma unroll
        for (int mi = 0; mi < 4; ++mi)
            af[mi] = *(const f16x8*)&As[cur][kb][mi * 16 + fr][0];
#pragma unroll
        for (int ni = 0; ni < 2; ++ni)
            bf[ni] = *(const f16x8*)&Bs[cur][kb][w * 32 + ni * 16 + fr][0];
#pragma unroll
        for (int mi = 0; mi < 4; ++mi)
#pragma unroll
            for (int ni = 0; ni < 2; ++ni)
                acc1[mi][ni] = __builtin_amdgcn_mfma_f32_16x16x32_f16(af[mi], bf[ni], acc1[mi][ni], 0, 0, 0);
        __syncthreads();
    }

    // issue first W2 tile while writing C1 to LDS
    stageB(0, 0, W2t, HD);
#pragma unroll
    for (int mi = 0; mi < 4; ++mi) {
#pragma unroll
        for (int reg = 0; reg < 4; ++reg) {
            int ml = mi * 16 + rr * 4 + reg;
#pragma unroll
            for (int ni = 0; ni < 2; ++ni) {
                int n = w * 32 + ni * 16 + fr;
                float v = gelu_exact(acc1[mi][ni][reg] + b1[n]);
                C1L[n >> 3][ml][n & 7] = (_Float16)v;
            }
        }
    }
    __syncthreads();

    // ---- stage 2 (K2 = 256) ----
    f32x4 acc2[4][2];
#pragma unroll
    for (int mi = 0; mi < 4; ++mi)
#pragma unroll
        for (int ni = 0; ni < 2; ++ni) acc2[mi][ni] = (f32x4){0.f, 0.f, 0.f, 0.f};

    for (int tt = 0; tt < 8; ++tt) {
        const int cur = tt & 1;
        if (tt + 1 < 8) stageB(cur ^ 1, (tt + 1) << 5, W2t, HD);
        f16x8 af[4], bf[2];
#pragma unroll
        for (int mi = 0; mi < 4; ++mi)
            af[mi] = *(const f16x8*)&C1L[tt * 4 + kb][mi * 16 + fr][0];
#pragma unroll
        for (int ni = 0; ni < 2; ++ni)
            bf[ni] = *(const f16x8*)&Bs[cur][kb][w * 32 + ni * 16 + fr][0];
#pragma unroll
        for (int mi = 0; mi < 4; ++mi)
#pragma unroll
            for (int ni = 0; ni < 2; ++ni)
                acc2[mi][ni] = __builtin_amdgcn_mfma_f32_16x16x32_f16(af[mi], bf[ni], acc2[mi][ni], 0, 0, 0);
        __syncthreads();
    }

    // ---- epilogue 2 ----
    float cs[2] = {0.f, 0.f}, cq[2] = {0.f, 0.f};
#pragma unroll
    for (int mi = 0; mi < 4; ++mi) {
#pragma unroll
        for (int reg = 0; reg < 4; ++reg) {
            int m = m0 + mi * 16 + rr * 4 + reg;
            if (m < M) {
#pragma unroll
                for (int ni = 0; ni < 2; ++ni) {
                    int n = w * 32 + ni * 16 + fr;
                    float v = acc2[mi][ni][reg] + b2[n];
                    if (RES2) v += (float)R16[(size_t)m * HD + n];
                    if (RESBN2) v += (float)R16[(size_t)m * HD + n] * bnsc[n] + bnsh[n];
                    _Float16 vh = (_Float16)v;
                    C16[(size_t)m * HD + n] = vh;
                    if (STATS2) { float vr = (float)vh; cs[ni] += vr; cq[ni] += vr * vr; }
                }
            }
        }
    }
    if constexpr (STATS2) {
#pragma unroll
        for (int ni = 0; ni < 2; ++ni) {
            cs[ni] += __shfl_xor(cs[ni], 16); cs[ni] += __shfl_xor(cs[ni], 32);
            cq[ni] += __shfl_xor(cq[ni], 16); cq[ni] += __shfl_xor(cq[ni], 32);
        }
        if (lane < 16) {
#pragma unroll
            for (int ni = 0; ni < 2; ++ni) {
                int n = w * 32 + ni * 16 + lane;
                atomicAdd(&stat[n], cs[ni]);
                atomicAdd(&stat[HD + n], cq[ni]);
            }
        }
    }
}

// ---------------- MFMA fp16 GEMM (64x128 tile) — VN/post path ----------------
template <bool GELU, bool BIAS2, bool O32, bool O16>
__global__ __launch_bounds__(256) void k_mgemm(const _Float16* __restrict__ A,
                                               const _Float16* __restrict__ Wt,
                                               const float* __restrict__ bias,
                                               const float* __restrict__ bias2,
                                               float* __restrict__ C32,
                                               _Float16* __restrict__ C16,
                                               int M, int N, int K) {
    __shared__ _Float16 As[2][4][64][8];
    __shared__ _Float16 Bs[2][4][128][8];
    const int t = threadIdx.x;
    const int w = t >> 6, lane = t & 63;
    const int m0 = blockIdx.y * 64, n0 = blockIdx.x * 128;
    const int kb = lane >> 4, fr = lane & 15;

    f32x4 acc[4][2];
#pragma unroll
    for (int mi = 0; mi < 4; ++mi)
#pragma unroll
        for (int ni = 0; ni < 2; ++ni) acc[mi][ni] = (f32x4){0.f, 0.f, 0.f, 0.f};

    const _Float16* gA0 = A + (size_t)(m0 + lane) * K + w * 8;
    const _Float16* gB0 = Wt + (size_t)(n0 + lane) * K + w * 8;
    const _Float16* gB1 = Wt + (size_t)(n0 + 64 + lane) * K + w * 8;

    auto stage = [&](int buf, int k0) {
        gl_lds16(gB0 + k0, &Bs[buf][w][0][0]);
        gl_lds16(gB1 + k0, &Bs[buf][w][64][0]);
        gl_lds16(gA0 + k0, &As[buf][w][0][0]);
    };

    const int nt = K >> 5;
    stage(0, 0);
    __syncthreads();
    for (int tt = 0; tt < nt; ++tt) {
        const int cur = tt & 1;
        if (tt + 1 < nt) stage(cur ^ 1, (tt + 1) << 5);
        f16x8 af[4], bf[2];
#pragma unroll
        for (int mi = 0; mi < 4; ++mi)
            af[mi] = *(const f16x8*)&As[cur][kb][mi * 16 + fr][0];
#pragma unroll
        for (int ni = 0; ni < 2; ++ni)
            bf[ni] = *(const f16x8*)&Bs[cur][kb][w * 32 + ni * 16 + fr][0];
#pragma unroll
        for (int mi = 0; mi < 4; ++mi)
#pragma unroll
            for (int ni = 0; ni < 2; ++ni)
                acc[mi][ni] = __builtin_amdgcn_mfma_f32_16x16x32_f16(af[mi], bf[ni], acc[mi][ni], 0, 0, 0);
        __syncthreads();
    }

    const int rr = lane >> 4;
#pragma unroll
    for (int mi = 0; mi < 4; ++mi) {
#pragma unroll
        for (int reg = 0; reg < 4; ++reg) {
            int m = m0 + mi * 16 + rr * 4 + reg;
            if (m < M) {
#pragma unroll
                for (int ni = 0; ni < 2; ++ni) {
                    int n = n0 + w * 32 + ni * 16 + fr;
                    float v = acc[mi][ni][reg] + bias[n];
                    if (BIAS2) v += bias2[n];
                    if (GELU) v = gelu_exact(v);
                    if (O32) C32[(size_t)m * N + n] = v;
                    if (O16) C16[(size_t)m * N + n] = (_Float16)v;
                }
            }
        }
    }
}

static inline void mg_gelu(hipStream_t st, const _Float16* A, const _Float16* Wt,
                           const float* bias, _Float16* C16, int M, int N, int K) {
    dim3 g(N / 128, (M + 63) / 64), b(256);
    k_mgemm<true, false, false, true><<<g, b, 0, st>>>(A, Wt, bias, nullptr, nullptr, C16, M, N, K);
}
static inline void mg_bias2_16(hipStream_t st, const _Float16* A, const _Float16* Wt,
                               const float* bias, const float* bias2, _Float16* C16,
                               int M, int N, int K) {
    dim3 g(N / 128, (M + 63) / 64), b(256);
    k_mgemm<false, true, false, true><<<g, b, 0, st>>>(A, Wt, bias, bias2, nullptr, C16, M, N, K);
}
static inline void mg_f32only(hipStream_t st, const _Float16* A, const _Float16* Wt,
                              const float* bias, float* C32, int M, int N, int K) {
    dim3 g(N / 128, (M + 63) / 64), b(256);
    k_mgemm<false, false, true, false><<<g, b, 0, st>>>(A, Wt, bias, nullptr, C32, nullptr, M, N, K);
}

extern "C" void kernel_launch(void* const* d_in, const int* in_sizes, int n_in,
                              void* d_out, int out_size, void* d_ws, size_t ws_size,
                              hipStream_t stream) {
    const float* x       = (const float*)d_in[0];
    const int*   ei      = (const int*)d_in[1];
    const int*   batch   = (const int*)d_in[2];
    const float* pre_W1  = (const float*)d_in[3];
    const float* pre_b1  = (const float*)d_in[4];
    const float* pre_W2  = (const float*)d_in[5];
    const float* pre_b2  = (const float*)d_in[6];
    const float* gin_W1  = (const float*)d_in[7];
    const float* gin_b1  = (const float*)d_in[8];
    const float* gin_W2  = (const float*)d_in[9];
    const float* gin_b2  = (const float*)d_in[10];
    const float* ffn_W1  = (const float*)d_in[11];
    const float* ffn_b1  = (const float*)d_in[12];
    const float* ffn_W2  = (const float*)d_in[13];
    const float* ffn_b2  = (const float*)d_in[14];
    const float* upd_W1  = (const float*)d_in[15];
    const float* upd_b1  = (const float*)d_in[16];
    const float* upd_W2  = (const float*)d_in[17];
    const float* upd_b2  = (const float*)d_in[18];
    const float* prop_W1 = (const float*)d_in[19];
    const float* prop_b1 = (const float*)d_in[20];
    const float* prop_W2 = (const float*)d_in[21];
    const float* prop_b2 = (const float*)d_in[22];
    const float* bn_gamma= (const float*)d_in[23];
    const float* bn_beta = (const float*)d_in[24];
    const float* vn      = (const float*)d_in[25];
    const float* post_W1 = (const float*)d_in[26];
    const float* post_b1 = (const float*)d_in[27];
    const float* post_W2 = (const float*)d_in[28];
    const float* post_b2 = (const float*)d_in[29];
    float* out = (float*)d_out;

    const int* e_src = ei;
    const int* e_dst = ei + NE;

    // ---------- workspace layout ----------
    char* p = (char*)d_ws;
    auto alloc = [&](size_t bytes) -> char* {
        char* r = p;
        p += (bytes + 255) & ~(size_t)255;
        return r;
    };
    _Float16* h16    = (_Float16*)alloc((size_t)NNP * HD * 2);   // fp16 backbone
    _Float16* g16    = (_Float16*)alloc((size_t)NNP * HD * 2);   // gin output (pre-BN)
    _Float16* t16a   = (_Float16*)alloc((size_t)NNP * HD * 2);   // agg out; aliases x16
    _Float16* pool16 = (_Float16*)alloc((size_t)NG * HD * 2);
    _Float16* u16    = (_Float16*)alloc((size_t)NG * HD * 2);
    _Float16* vb16   = (_Float16*)alloc((size_t)NG * H4 * 2);
    _Float16* p16    = (_Float16*)alloc((size_t)NG * HD * 2);
    float*    outvn32= (float*)alloc((size_t)NG * HD * 4);
    float*    bnstat = (float*)alloc(2 * HD * 4);
    float*    bnscale= (float*)alloc(HD * 4);
    float*    bnshift= (float*)alloc(HD * 4);
    _Float16* preW1t = (_Float16*)alloc((size_t)HD * DIN * 2);
    _Float16* preW2t = (_Float16*)alloc((size_t)HD * HD * 2);
    _Float16* ginW1t = (_Float16*)alloc((size_t)NL * HD * HD * 2);
    _Float16* ginW2t = (_Float16*)alloc((size_t)NL * HD * HD * 2);
    _Float16* ffnW1t = (_Float16*)alloc((size_t)NL * HD * HD * 2);
    _Float16* ffnW2t = (_Float16*)alloc((size_t)NL * HD * HD * 2);
    _Float16* updW1t = (_Float16*)alloc((size_t)NL * HD * HD * 2);
    _Float16* updW2t = (_Float16*)alloc((size_t)NL * HD * H4 * 2);
    _Float16* propW1t= (_Float16*)alloc((size_t)NL * H4 * HD * 2);
    _Float16* propW2t= (_Float16*)alloc((size_t)NL * HD * HD * 2);
    _Float16* postW1t= (_Float16*)alloc((size_t)HD * HD * 2);
    _Float16* postW2t= (_Float16*)alloc((size_t)DOUT * HD * 2);
    int* gcount = (int*)alloc(NG * 4);
    int* goff   = (int*)alloc((NG + 1) * 4);
    int* deg    = (int*)alloc(NN * 4);
    int* eoff   = (int*)alloc((NN + 1) * 4);
    int* cursor = (int*)alloc(NN * 4);
    int* csr    = (int*)alloc((size_t)NE * 4);
    int* bsum   = (int*)alloc(1024 * 4);
    int* bexcl  = (int*)alloc(1024 * 4);
    _Float16* x16 = t16a;   // alias: consumed by pre-pair before t16a is first written

    // ---------- zero counters + bnstat ----------
    {
        size_t span = (size_t)((char*)(cursor + NN) - (char*)gcount);
        hipMemsetAsync(gcount, 0, span, stream);
        hipMemsetAsync(bnstat, 0, 2 * HD * 4, stream);
    }
    hipLaunchKernelGGL(k_hist, dim3((NN + 255) / 256), dim3(256), 0, stream, batch, gcount, NN);
    hipLaunchKernelGGL(k_hist, dim3((NE + 255) / 256), dim3(256), 0, stream, e_dst, deg, NE);
    hipLaunchKernelGGL(k_scan_small, dim3(1), dim3(1024), 0, stream, gcount, goff, NG);
    {
        int nbN = (NN + 255) / 256;
        hipLaunchKernelGGL(k_scan_part, dim3(nbN), dim3(256), 0, stream, deg, bsum, NN);
        hipLaunchKernelGGL(k_scan_mid, dim3(1), dim3(1024), 0, stream, bsum, bexcl, nbN, eoff, NN);
        hipLaunchKernelGGL(k_scan_out, dim3(nbN), dim3(256), 0, stream, deg, bexcl, eoff, NN);
    }
    hipLaunchKernelGGL(k_fill_csr, dim3((NE + 255) / 256), dim3(256), 0, stream, e_src, e_dst, eoff, cursor, csr, NE);

    // ---------- batched weight transpose (one launch) ----------
    {
        WtJobs j;
        int idx = 0, tiles = 0;
        auto add = [&](const float* s, _Float16* d, int K, int N) {
            j.src[idx] = s; j.dst[idx] = d;
            j.K32[idx] = (short)(K / 32); j.N32[idx] = (short)(N / 32);
            j.pre[idx] = (short)tiles;
            tiles += (K / 32) * (N / 32);
            ++idx;
        };
        add(pre_W1, preW1t, DIN, HD);
        add(pre_W2, preW2t, HD, HD);
        add(post_W1, postW1t, HD, HD);
        add(post_W2, postW2t, HD, DOUT);
        for (int i = 0; i < NL; ++i) {
            add(gin_W1 + (size_t)i * HD * HD, ginW1t + (size_t)i * HD * HD, HD, HD);
            add(gin_W2 + (size_t)i * HD * HD, ginW2t + (size_t)i * HD * HD, HD, HD);
            add(ffn_W1 + (size_t)i * HD * HD, ffnW1t + (size_t)i * HD * HD, HD, HD);
            add(ffn_W2 + (size_t)i * HD * HD, ffnW2t + (size_t)i * HD * HD, HD, HD);
            add(upd_W1 + (size_t)i * HD * HD, updW1t + (size_t)i * HD * HD, HD, HD);
            add(upd_W2 + (size_t)i * HD * H4, updW2t + (size_t)i * HD * H4, HD, H4);
            add(prop_W1 + (size_t)i * H4 * HD, propW1t + (size_t)i * H4 * HD, H4, HD);
            add(prop_W2 + (size_t)i * HD * HD, propW2t + (size_t)i * HD * HD, HD, HD);
        }
        j.pre[idx] = (short)tiles;
        hipLaunchKernelGGL(k_wtb, dim3(tiles), dim3(32, 8), 0, stream, j);
    }

    // x -> fp16
    int n4 = NN * DIN / 4;
    hipLaunchKernelGGL(k_cvt16, dim3((n4 + 255) / 256), dim3(256), 0, stream, x, x16, n4);

    const int nb2b = NNP / 64;

    // ---------- pre-FFNN (fused pair): h16 = gelu(x@W1+b1)@W2+b2 ----------
    hipLaunchKernelGGL((k_b2b<false, false, false, false>), dim3(nb2b), dim3(512), 0, stream,
                       x16, nullptr, preW1t, pre_b1, preW2t, pre_b2,
                       nullptr, nullptr, nullptr, nullptr, nullptr, nullptr,
                       h16, NN, DIN);

    for (int i = 0; i < NL; ++i) {
        const _Float16* uW1 = updW1t + (size_t)i * HD * HD;
        const _Float16* uW2 = updW2t + (size_t)i * HD * H4;
        const _Float16* pW1 = propW1t + (size_t)i * H4 * HD;
        const _Float16* pW2 = propW2t + (size_t)i * HD * HD;

        // virtual-node path (M = NG = 512) via MFMA GEMMs (r10-proven)
        hipLaunchKernelGGL(k_pool16, dim3(NG), dim3(HD), 0, stream, h16, goff, pool16);
        mg_gelu(stream, pool16, uW1, upd_b1 + (size_t)i * HD, u16, NG, HD, HD);
        mg_bias2_16(stream, u16, uW2, upd_b2 + (size_t)i * H4, vn, vb16, NG, H4, HD);
        mg_gelu(stream, vb16, pW1, prop_b1 + (size_t)i * HD, p16, NG, HD, H4);
        mg_f32only(stream, p16, pW2, prop_b2 + (size_t)i * HD, outvn32, NG, HD, HD);

        // GIN: t16a = agg(h16); g16 = gelu(t16a@gW1+b1)@gW2+b2 + h16 (+BN stats)
        hipLaunchKernelGGL(k_agg16, dim3(NN / 4), dim3(256), 0, stream, h16, eoff, csr, t16a);
        hipLaunchKernelGGL((k_b2b<false, true, false, true>), dim3(nb2b), dim3(512), 0, stream,
                           t16a, nullptr,
                           ginW1t + (size_t)i * HD * HD, gin_b1 + (size_t)i * HD,
                           ginW2t + (size_t)i * HD * HD, gin_b2 + (size_t)i * HD,
                           h16, nullptr, nullptr, nullptr, nullptr, bnstat,
                           g16, NN, HD);

        // BN finalize (re-zeroes stat)
        hipLaunchKernelGGL(k_bn_final, dim3(1), dim3(HD), 0, stream, bnstat,
                           bn_gamma + (size_t)i * HD, bn_beta + (size_t)i * HD, bnscale, bnshift);

        // FFN fused pair: h16 = gelu((bn(g16)+ovn)@fW1+b1)@fW2+b2 + bn(g16)
        hipLaunchKernelGGL((k_b2b<true, false, true, false>), dim3(nb2b), dim3(512), 0, stream,
                           nullptr, g16,
                           ffnW1t + (size_t)i * HD * HD, ffn_b1 + (size_t)i * HD,
                           ffnW2t + (size_t)i * HD * HD, ffn_b2 + (size_t)i * HD,
                           g16, bnscale, bnshift, outvn32, batch, nullptr,
                           h16, NN, HD);
    }

    // ---------- post ----------
    hipLaunchKernelGGL(k_pool16, dim3(NG), dim3(HD), 0, stream, h16, goff, pool16);
    mg_gelu(stream, pool16, postW1t, post_b1, u16, NG, HD, HD);
    mg_f32only(stream, u16, postW2t, post_b2, out, NG, DOUT, HD);
}

// Round 15
// 1673.934 us; speedup vs baseline: 1.1027x; 1.0088x over previous
//
#include <hip/hip_runtime.h>
#include <hip/hip_bf16.h>
#include <math.h>

#define NN 50000
#define NNP 50048          // padded to multiple of 128
#define NE 800000
#define NG 512
#define DIN 128
#define HD 256
#define DOUT 128
#define NL 5
#define H4 1024

typedef _Float16 f16x8 __attribute__((ext_vector_type(8)));
typedef _Float16 f16x4 __attribute__((ext_vector_type(4)));
typedef float f32x4 __attribute__((ext_vector_type(4)));

__device__ __forceinline__ float gelu_exact(float x) {
    return 0.5f * x * (1.0f + erff(x * 0.70710678118654752f));
}

__device__ __forceinline__ void gl_lds16(const _Float16* g, _Float16* l) {
    __builtin_amdgcn_global_load_lds(
        (const __attribute__((address_space(1))) unsigned int*)g,
        (__attribute__((address_space(3))) unsigned int*)l, 16, 0, 0);
}

// ---------------- graph meta ----------------
__global__ void k_hist(const int* __restrict__ idx, int* __restrict__ cnt, int n) {
    int i = blockIdx.x * blockDim.x + threadIdx.x;
    if (i < n) atomicAdd(&cnt[idx[i]], 1);
}

__global__ void k_scan_small(const int* __restrict__ in, int* __restrict__ out, int n) {
    __shared__ int buf[1024];
    int t = threadIdx.x;
    int v = (t < n) ? in[t] : 0;
    buf[t] = v;
    __syncthreads();
    for (int off = 1; off < 1024; off <<= 1) {
        int x = (t >= off) ? buf[t - off] : 0;
        __syncthreads();
        buf[t] += x;
        __syncthreads();
    }
    if (t < n) out[t] = buf[t] - v;
    if (t == 1023) out[n] = buf[1023];
}

__global__ void k_scan_part(const int* __restrict__ in, int* __restrict__ bsum, int n) {
    __shared__ int buf[256];
    int i = blockIdx.x * 256 + threadIdx.x;
    buf[threadIdx.x] = (i < n) ? in[i] : 0;
    __syncthreads();
    for (int off = 128; off > 0; off >>= 1) {
        if (threadIdx.x < off) buf[threadIdx.x] += buf[threadIdx.x + off];
        __syncthreads();
    }
    if (threadIdx.x == 0) bsum[blockIdx.x] = buf[0];
}

__global__ void k_scan_mid(const int* __restrict__ bsum, int* __restrict__ bexcl, int nb,
                           int* __restrict__ out, int n) {
    __shared__ int buf[1024];
    int t = threadIdx.x;
    int v = (t < nb) ? bsum[t] : 0;
    buf[t] = v;
    __syncthreads();
    for (int off = 1; off < 1024; off <<= 1) {
        int x = (t >= off) ? buf[t - off] : 0;
        __syncthreads();
        buf[t] += x;
        __syncthreads();
    }
    if (t < nb) bexcl[t] = buf[t] - v;
    if (t == 1023) out[n] = buf[1023];
}

__global__ void k_scan_out(const int* __restrict__ in, const int* __restrict__ bexcl,
                           int* __restrict__ out, int n) {
    __shared__ int buf[256];
    int i = blockIdx.x * 256 + threadIdx.x;
    int t = threadIdx.x;
    int v = (i < n) ? in[i] : 0;
    buf[t] = v;
    __syncthreads();
    for (int off = 1; off < 256; off <<= 1) {
        int x = (t >= off) ? buf[t - off] : 0;
        __syncthreads();
        buf[t] += x;
        __syncthreads();
    }
    if (i < n) out[i] = bexcl[blockIdx.x] + buf[t] - v;
}

__global__ void k_fill_csr(const int* __restrict__ src, const int* __restrict__ dst,
                           const int* __restrict__ eoff, int* __restrict__ cursor,
                           int* __restrict__ csr, int n) {
    int e = blockIdx.x * blockDim.x + threadIdx.x;
    if (e < n) {
        int d = dst[e];
        int p = atomicAdd(&cursor[d], 1);
        csr[eoff[d] + p] = src[e];
    }
}

// ---------------- converts ----------------
__global__ void k_cvt16(const float* __restrict__ in, _Float16* __restrict__ out, int n4) {
    int i = blockIdx.x * blockDim.x + threadIdx.x;
    if (i < n4) {
        float4 v = *(const float4*)&in[i * 4];
        f16x4 o = { (_Float16)v.x, (_Float16)v.y, (_Float16)v.z, (_Float16)v.w };
        *(f16x4*)&out[i * 4] = o;
    }
}

// batched transpose + convert: one launch for all weight matrices
#define NWTJOBS 44
struct WtJobs {
    const float* src[NWTJOBS];
    _Float16* dst[NWTJOBS];
    short K32[NWTJOBS];
    short N32[NWTJOBS];
    short pre[NWTJOBS + 1];
};
__global__ void k_wtb(WtJobs j) {
    int bid = blockIdx.x;
    int lo = 0;
    while (j.pre[lo + 1] <= bid) ++lo;
    int tl = bid - j.pre[lo];
    int nx = j.N32[lo];
    int n0 = (tl % nx) * 32, k0 = (tl / nx) * 32;
    int K = j.K32[lo] * 32, N = nx * 32;
    const float* W = j.src[lo];
    _Float16* Wt = j.dst[lo];
    __shared__ float tile[32][33];
    for (int i = threadIdx.y; i < 32; i += 8)
        tile[i][threadIdx.x] = W[(size_t)(k0 + i) * N + n0 + threadIdx.x];
    __syncthreads();
    for (int i = threadIdx.y; i < 32; i += 8)
        Wt[(size_t)(n0 + i) * K + k0 + threadIdx.x] = (_Float16)tile[threadIdx.x][i];
}

// ---------------- pooling / aggregation ----------------
__global__ void k_pool16(const _Float16* __restrict__ h16, const int* __restrict__ goff,
                         _Float16* __restrict__ pool) {
    int g = blockIdx.x;
    int c = threadIdx.x;
    int s = goff[g], e = goff[g + 1];
    float acc = 0.f;
    for (int r = s; r < e; ++r) acc += (float)h16[(size_t)r * HD + c];
    int cnt = e - s;
    pool[g * HD + c] = (_Float16)(acc / (float)(cnt > 0 ? cnt : 1));
}

// one wave per node; WAVE-UNIFORM loop bounds; 8 edges/iter
__global__ __launch_bounds__(256) void k_agg16(const _Float16* __restrict__ h16,
                                               const int* __restrict__ eoff,
                                               const int* __restrict__ csr,
                                               _Float16* __restrict__ out) {
    int node = blockIdx.x * 4 + (threadIdx.x >> 6);
    int lane = threadIdx.x & 63;
    int half = lane >> 5, l = lane & 31;
    f16x8 mine = *(const f16x8*)&h16[(size_t)node * HD + l * 8];
    float acc[8];
#pragma unroll
    for (int q = 0; q < 8; ++q) acc[q] = half ? 0.f : (float)mine[q];
    int s = eoff[node], e = eoff[node + 1];
    for (int base = s; base < e; base += 64) {
        int myi = base + lane;
        int vidx = (myi < e) ? csr[myi] : 0;
        int cnt = min(64, e - base);
        int jj = 0;
        for (; jj + 7 < cnt; jj += 8) {
            int s0 = __shfl(vidx, jj + half);
            int s1 = __shfl(vidx, jj + 2 + half);
            int s2 = __shfl(vidx, jj + 4 + half);
            int s3 = __shfl(vidx, jj + 6 + half);
            f16x8 v0 = *(const f16x8*)&h16[(size_t)s0 * HD + l * 8];
            f16x8 v1 = *(const f16x8*)&h16[(size_t)s1 * HD + l * 8];
            f16x8 v2 = *(const f16x8*)&h16[(size_t)s2 * HD + l * 8];
            f16x8 v3 = *(const f16x8*)&h16[(size_t)s3 * HD + l * 8];
#pragma unroll
            for (int q = 0; q < 8; ++q)
                acc[q] += ((float)v0[q] + (float)v1[q]) + ((float)v2[q] + (float)v3[q]);
        }
        for (; jj + 3 < cnt; jj += 4) {
            int s0 = __shfl(vidx, jj + half);
            int s1 = __shfl(vidx, jj + 2 + half);
            f16x8 v0 = *(const f16x8*)&h16[(size_t)s0 * HD + l * 8];
            f16x8 v1 = *(const f16x8*)&h16[(size_t)s1 * HD + l * 8];
#pragma unroll
            for (int q = 0; q < 8; ++q) acc[q] += (float)v0[q] + (float)v1[q];
        }
        for (; jj < cnt; jj += 2) {
            int i0 = jj + half;
            int s0 = __shfl(vidx, i0);
            if (i0 < cnt) {
                f16x8 v0 = *(const f16x8*)&h16[(size_t)s0 * HD + l * 8];
#pragma unroll
                for (int q = 0; q < 8; ++q) acc[q] += (float)v0[q];
            }
        }
    }
#pragma unroll
    for (int q = 0; q < 8; ++q) acc[q] += __shfl_xor(acc[q], 32);
    if (!half) {
        f16x8 o;
#pragma unroll
        for (int q = 0; q < 8; ++q) o[q] = (_Float16)acc[q];
        *(f16x8*)&out[(size_t)node * HD + l * 8] = o;
    }
}

// ---------------- batch norm finalize (also re-zeroes stat for next layer) ----
__global__ void k_bn_final(float* __restrict__ stat,
                           const float* __restrict__ gamma, const float* __restrict__ beta,
                           float* __restrict__ scale, float* __restrict__ shift) {
    int c = threadIdx.x;
    float mu = stat[c] * (1.0f / NN);
    float var = stat[HD + c] * (1.0f / NN) - mu * mu;
    float rs = rsqrtf(var + 1e-5f);
    float sc = rs * gamma[c];
    scale[c] = sc;
    shift[c] = beta[c] - mu * sc;
    stat[c] = 0.f;
    stat[HD + c] = 0.f;
}

// ======== fused back-to-back FFNN (fp16 backbone, A-tile resident in LDS) ====
// C16 = gelu(A@W1+b1)@W2+b2 [+res].  The 64-row A tile (<=32 KB) is loaded ONCE
// into the AC buffer in the prologue (bulk drain); stage-1 k-step barriers then
// wait only on L2-hot weight staging.  AC is overwritten with C1 for stage 2.
template <bool ABN1, bool RES2, bool RESBN2, bool STATS2>
__global__ __launch_bounds__(512) void k_b2b(const _Float16* __restrict__ A16,
                                             const _Float16* __restrict__ G16,
                                             const _Float16* __restrict__ W1t,
                                             const float* __restrict__ b1,
                                             const _Float16* __restrict__ W2t,
                                             const float* __restrict__ b2,
                                             const _Float16* __restrict__ R16,
                                             const float* __restrict__ bnsc,
                                             const float* __restrict__ bnsh,
                                             const float* __restrict__ ovn,
                                             const int* __restrict__ batchv,
                                             float* __restrict__ stat,
                                             _Float16* __restrict__ C16,
                                             int M, int K1) {
    __shared__ _Float16 AC[32][64][8];      // 32 KB: A-tile (stage 1) then C1 (stage 2)
    __shared__ _Float16 Bs[2][4][256][8];   // 32 KB weight staging (dbuf)
    const int t = threadIdx.x;
    const int w = t >> 6, lane = t & 63;
    const int m0 = blockIdx.x * 64;
    const int kb = lane >> 4, fr = lane & 15, rr = lane >> 4;

    auto stageB = [&](int buf, int k0, const _Float16* Wt, int KB) {
        int s0 = t, s1 = t + 512;
        gl_lds16(Wt + (size_t)(s0 & 255) * KB + k0 + (s0 >> 8) * 8, &Bs[buf][s0 >> 8][s0 & 255][0]);
        gl_lds16(Wt + (size_t)(s1 & 255) * KB + k0 + (s1 >> 8) * 8, &Bs[buf][s1 >> 8][s1 & 255][0]);
    };

    // ---- prologue: load ENTIRE A tile (64 x K1 f16) into AC ----
    const int nchunk = K1 * 8;   // (64 rows * K1 / 8) chunks of 16 B
    if constexpr (ABN1) {
        for (int c = t; c < nchunk; c += 512) {
            int kblk = c >> 6, row = c & 63;
            int b0 = batchv[min(m0 + row, M - 1)];
            const int c0 = kblk * 8;
            f16x8 g = *(const f16x8*)&G16[(size_t)(m0 + row) * HD + c0];
            f16x8 r0;
#pragma unroll
            for (int q = 0; q < 8; ++q)
                r0[q] = (_Float16)((float)g[q] * bnsc[c0 + q] + bnsh[c0 + q] +
                                   ovn[(size_t)b0 * HD + c0 + q]);
            *(f16x8*)&AC[kblk][row][0] = r0;
        }
    } else {
        for (int c = t; c < nchunk; c += 512) {
            int kblk = c >> 6, row = c & 63;
            gl_lds16(A16 + (size_t)(m0 + row) * K1 + kblk * 8, &AC[kblk][row][0]);
        }
    }
    stageB(0, 0, W1t, K1);
    __syncthreads();

    // ---- stage 1 ----
    f32x4 acc1[4][2];
#pragma unroll
    for (int mi = 0; mi < 4; ++mi)
#pragma unroll
        for (int ni = 0; ni < 2; ++ni) acc1[mi][ni] = (f32x4){0.f, 0.f, 0.f, 0.f};

    const int nt1 = K1 >> 5;
    for (int tt = 0; tt < nt1; ++tt) {
        const int cur = tt & 1;
        if (tt + 1 < nt1) stageB(cur ^ 1, (tt + 1) << 5, W1t, K1);
        f16x8 af[4], bf[2];
#pragma unroll
        for (int mi = 0; mi < 4; ++mi)
            af[mi] = *(const f16x8*)&AC[(tt << 2) + kb][mi * 16 + fr][0];
#pragma unroll
        for (int ni = 0; ni < 2; ++ni)
            bf[ni] = *(const f16x8*)&Bs[cur][kb][w * 32 + ni * 16 + fr][0];
#pragma unroll
        for (int mi = 0; mi < 4; ++mi)
#pragma unroll
            for (int ni = 0; ni < 2; ++ni)
                acc1[mi][ni] = __builtin_amdgcn_mfma_f32_16x16x32_f16(af[mi], bf[ni], acc1[mi][ni], 0, 0, 0);
        __syncthreads();
    }

    // ---- C1 -> AC (gelu + b1); issue first W2 tile; handoff barrier ----
    stageB(0, 0, W2t, HD);
#pragma unroll
    for (int mi = 0; mi < 4; ++mi) {
#pragma unroll
        for (int reg = 0; reg < 4; ++reg) {
            int ml = mi * 16 + rr * 4 + reg;
#pragma unroll
            for (int ni = 0; ni < 2; ++ni) {
                int n = w * 32 + ni * 16 + fr;
                float v = gelu_exact(acc1[mi][ni][reg] + b1[n]);
                AC[n >> 3][ml][n & 7] = (_Float16)v;
            }
        }
    }
    __syncthreads();

    // ---- stage 2 (K2 = 256) ----
    f32x4 acc2[4][2];
#pragma unroll
    for (int mi = 0; mi < 4; ++mi)
#pragma unroll
        for (int ni = 0; ni < 2; ++ni) acc2[mi][ni] = (f32x4){0.f, 0.f, 0.f, 0.f};

    for (int tt = 0; tt < 8; ++tt) {
        const int cur = tt & 1;
        if (tt + 1 < 8) stageB(cur ^ 1, (tt + 1) << 5, W2t, HD);
        f16x8 af[4], bf[2];
#pragma unroll
        for (int mi = 0; mi < 4; ++mi)
            af[mi] = *(const f16x8*)&AC[tt * 4 + kb][mi * 16 + fr][0];
#pragma unroll
        for (int ni = 0; ni < 2; ++ni)
            bf[ni] = *(const f16x8*)&Bs[cur][kb][w * 32 + ni * 16 + fr][0];
#pragma unroll
        for (int mi = 0; mi < 4; ++mi)
#pragma unroll
            for (int ni = 0; ni < 2; ++ni)
                acc2[mi][ni] = __builtin_amdgcn_mfma_f32_16x16x32_f16(af[mi], bf[ni], acc2[mi][ni], 0, 0, 0);
        __syncthreads();
    }

    // ---- epilogue 2 ----
    float cs[2] = {0.f, 0.f}, cq[2] = {0.f, 0.f};
#pragma unroll
    for (int mi = 0; mi < 4; ++mi) {
#pragma unroll
        for (int reg = 0; reg < 4; ++reg) {
            int m = m0 + mi * 16 + rr * 4 + reg;
            if (m < M) {
#pragma unroll
                for (int ni = 0; ni < 2; ++ni) {
                    int n = w * 32 + ni * 16 + fr;
                    float v = acc2[mi][ni][reg] + b2[n];
                    if (RES2) v += (float)R16[(size_t)m * HD + n];
                    if (RESBN2) v += (float)R16[(size_t)m * HD + n] * bnsc[n] + bnsh[n];
                    _Float16 vh = (_Float16)v;
                    C16[(size_t)m * HD + n] = vh;
                    if (STATS2) { float vr = (float)vh; cs[ni] += vr; cq[ni] += vr * vr; }
                }
            }
        }
    }
    if constexpr (STATS2) {
#pragma unroll
        for (int ni = 0; ni < 2; ++ni) {
            cs[ni] += __shfl_xor(cs[ni], 16); cs[ni] += __shfl_xor(cs[ni], 32);
            cq[ni] += __shfl_xor(cq[ni], 16); cq[ni] += __shfl_xor(cq[ni], 32);
        }
        if (lane < 16) {
#pragma unroll
            for (int ni = 0; ni < 2; ++ni) {
                int n = w * 32 + ni * 16 + lane;
                atomicAdd(&stat[n], cs[ni]);
                atomicAdd(&stat[HD + n], cq[ni]);
            }
        }
    }
}

// ---------------- MFMA fp16 GEMM (64x128 tile) — VN/post path ----------------
template <bool GELU, bool BIAS2, bool O32, bool O16>
__global__ __launch_bounds__(256) void k_mgemm(const _Float16* __restrict__ A,
                                               const _Float16* __restrict__ Wt,
                                               const float* __restrict__ bias,
                                               const float* __restrict__ bias2,
                                               float* __restrict__ C32,
                                               _Float16* __restrict__ C16,
                                               int M, int N, int K) {
    __shared__ _Float16 As[2][4][64][8];
    __shared__ _Float16 Bs[2][4][128][8];
    const int t = threadIdx.x;
    const int w = t >> 6, lane = t & 63;
    const int m0 = blockIdx.y * 64, n0 = blockIdx.x * 128;
    const int kb = lane >> 4, fr = lane & 15;

    f32x4 acc[4][2];
#pragma unroll
    for (int mi = 0; mi < 4; ++mi)
#pragma unroll
        for (int ni = 0; ni < 2; ++ni) acc[mi][ni] = (f32x4){0.f, 0.f, 0.f, 0.f};

    const _Float16* gA0 = A + (size_t)(m0 + lane) * K + w * 8;
    const _Float16* gB0 = Wt + (size_t)(n0 + lane) * K + w * 8;
    const _Float16* gB1 = Wt + (size_t)(n0 + 64 + lane) * K + w * 8;

    auto stage = [&](int buf, int k0) {
        gl_lds16(gB0 + k0, &Bs[buf][w][0][0]);
        gl_lds16(gB1 + k0, &Bs[buf][w][64][0]);
        gl_lds16(gA0 + k0, &As[buf][w][0][0]);
    };

    const int nt = K >> 5;
    stage(0, 0);
    __syncthreads();
    for (int tt = 0; tt < nt; ++tt) {
        const int cur = tt & 1;
        if (tt + 1 < nt) stage(cur ^ 1, (tt + 1) << 5);
        f16x8 af[4], bf[2];
#pragma unroll
        for (int mi = 0; mi < 4; ++mi)
            af[mi] = *(const f16x8*)&As[cur][kb][mi * 16 + fr][0];
#pragma unroll
        for (int ni = 0; ni < 2; ++ni)
            bf[ni] = *(const f16x8*)&Bs[cur][kb][w * 32 + ni * 16 + fr][0];
#pragma unroll
        for (int mi = 0; mi < 4; ++mi)
#pragma unroll
            for (int ni = 0; ni < 2; ++ni)
                acc[mi][ni] = __builtin_amdgcn_mfma_f32_16x16x32_f16(af[mi], bf[ni], acc[mi][ni], 0, 0, 0);
        __syncthreads();
    }

    const int rr = lane >> 4;
#pragma unroll
    for (int mi = 0; mi < 4; ++mi) {
#pragma unroll
        for (int reg = 0; reg < 4; ++reg) {
            int m = m0 + mi * 16 + rr * 4 + reg;
            if (m < M) {
#pragma unroll
                for (int ni = 0; ni < 2; ++ni) {
                    int n = n0 + w * 32 + ni * 16 + fr;
                    float v = acc[mi][ni][reg] + bias[n];
                    if (BIAS2) v += bias2[n];
                    if (GELU) v = gelu_exact(v);
                    if (O32) C32[(size_t)m * N + n] = v;
                    if (O16) C16[(size_t)m * N + n] = (_Float16)v;
                }
            }
        }
    }
}

static inline void mg_gelu(hipStream_t st, const _Float16* A, const _Float16* Wt,
                           const float* bias, _Float16* C16, int M, int N, int K) {
    dim3 g(N / 128, (M + 63) / 64), b(256);
    k_mgemm<true, false, false, true><<<g, b, 0, st>>>(A, Wt, bias, nullptr, nullptr, C16, M, N, K);
}
static inline void mg_bias2_16(hipStream_t st, const _Float16* A, const _Float16* Wt,
                               const float* bias, const float* bias2, _Float16* C16,
                               int M, int N, int K) {
    dim3 g(N / 128, (M + 63) / 64), b(256);
    k_mgemm<false, true, false, true><<<g, b, 0, st>>>(A, Wt, bias, bias2, nullptr, C16, M, N, K);
}
static inline void mg_f32only(hipStream_t st, const _Float16* A, const _Float16* Wt,
                              const float* bias, float* C32, int M, int N, int K) {
    dim3 g(N / 128, (M + 63) / 64), b(256);
    k_mgemm<false, false, true, false><<<g, b, 0, st>>>(A, Wt, bias, nullptr, C32, nullptr, M, N, K);
}

extern "C" void kernel_launch(void* const* d_in, const int* in_sizes, int n_in,
                              void* d_out, int out_size, void* d_ws, size_t ws_size,
                              hipStream_t stream) {
    const float* x       = (const float*)d_in[0];
    const int*   ei      = (const int*)d_in[1];
    const int*   batch   = (const int*)d_in[2];
    const float* pre_W1  = (const float*)d_in[3];
    const float* pre_b1  = (const float*)d_in[4];
    const float* pre_W2  = (const float*)d_in[5];
    const float* pre_b2  = (const float*)d_in[6];
    const float* gin_W1  = (const float*)d_in[7];
    const float* gin_b1  = (const float*)d_in[8];
    const float* gin_W2  = (const float*)d_in[9];
    const float* gin_b2  = (const float*)d_in[10];
    const float* ffn_W1  = (const float*)d_in[11];
    const float* ffn_b1  = (const float*)d_in[12];
    const float* ffn_W2  = (const float*)d_in[13];
    const float* ffn_b2  = (const float*)d_in[14];
    const float* upd_W1  = (const float*)d_in[15];
    const float* upd_b1  = (const float*)d_in[16];
    const float* upd_W2  = (const float*)d_in[17];
    const float* upd_b2  = (const float*)d_in[18];
    const float* prop_W1 = (const float*)d_in[19];
    const float* prop_b1 = (const float*)d_in[20];
    const float* prop_W2 = (const float*)d_in[21];
    const float* prop_b2 = (const float*)d_in[22];
    const float* bn_gamma= (const float*)d_in[23];
    const float* bn_beta = (const float*)d_in[24];
    const float* vn      = (const float*)d_in[25];
    const float* post_W1 = (const float*)d_in[26];
    const float* post_b1 = (const float*)d_in[27];
    const float* post_W2 = (const float*)d_in[28];
    const float* post_b2 = (const float*)d_in[29];
    float* out = (float*)d_out;

    const int* e_src = ei;
    const int* e_dst = ei + NE;

    // ---------- workspace layout ----------
    char* p = (char*)d_ws;
    auto alloc = [&](size_t bytes) -> char* {
        char* r = p;
        p += (bytes + 255) & ~(size_t)255;
        return r;
    };
    _Float16* h16    = (_Float16*)alloc((size_t)NNP * HD * 2);   // fp16 backbone
    _Float16* g16    = (_Float16*)alloc((size_t)NNP * HD * 2);   // gin output (pre-BN)
    _Float16* t16a   = (_Float16*)alloc((size_t)NNP * HD * 2);   // agg out; aliases x16
    _Float16* pool16 = (_Float16*)alloc((size_t)NG * HD * 2);
    _Float16* u16    = (_Float16*)alloc((size_t)NG * HD * 2);
    _Float16* vb16   = (_Float16*)alloc((size_t)NG * H4 * 2);
    _Float16* p16    = (_Float16*)alloc((size_t)NG * HD * 2);
    float*    outvn32= (float*)alloc((size_t)NG * HD * 4);
    float*    bnstat = (float*)alloc(2 * HD * 4);
    float*    bnscale= (float*)alloc(HD * 4);
    float*    bnshift= (float*)alloc(HD * 4);
    _Float16* preW1t = (_Float16*)alloc((size_t)HD * DIN * 2);
    _Float16* preW2t = (_Float16*)alloc((size_t)HD * HD * 2);
    _Float16* ginW1t = (_Float16*)alloc((size_t)NL * HD * HD * 2);
    _Float16* ginW2t = (_Float16*)alloc((size_t)NL * HD * HD * 2);
    _Float16* ffnW1t = (_Float16*)alloc((size_t)NL * HD * HD * 2);
    _Float16* ffnW2t = (_Float16*)alloc((size_t)NL * HD * HD * 2);
    _Float16* updW1t = (_Float16*)alloc((size_t)NL * HD * HD * 2);
    _Float16* updW2t = (_Float16*)alloc((size_t)NL * HD * H4 * 2);
    _Float16* propW1t= (_Float16*)alloc((size_t)NL * H4 * HD * 2);
    _Float16* propW2t= (_Float16*)alloc((size_t)NL * HD * HD * 2);
    _Float16* postW1t= (_Float16*)alloc((size_t)HD * HD * 2);
    _Float16* postW2t= (_Float16*)alloc((size_t)DOUT * HD * 2);
    int* gcount = (int*)alloc(NG * 4);
    int* goff   = (int*)alloc((NG + 1) * 4);
    int* deg    = (int*)alloc(NN * 4);
    int* eoff   = (int*)alloc((NN + 1) * 4);
    int* cursor = (int*)alloc(NN * 4);
    int* csr    = (int*)alloc((size_t)NE * 4);
    int* bsum   = (int*)alloc(1024 * 4);
    int* bexcl  = (int*)alloc(1024 * 4);
    _Float16* x16 = t16a;   // alias: consumed by pre-pair before t16a is first written

    // ---------- zero counters + bnstat ----------
    {
        size_t span = (size_t)((char*)(cursor + NN) - (char*)gcount);
        hipMemsetAsync(gcount, 0, span, stream);
        hipMemsetAsync(bnstat, 0, 2 * HD * 4, stream);
    }
    hipLaunchKernelGGL(k_hist, dim3((NN + 255) / 256), dim3(256), 0, stream, batch, gcount, NN);
    hipLaunchKernelGGL(k_hist, dim3((NE + 255) / 256), dim3(256), 0, stream, e_dst, deg, NE);
    hipLaunchKernelGGL(k_scan_small, dim3(1), dim3(1024), 0, stream, gcount, goff, NG);
    {
        int nbN = (NN + 255) / 256;
        hipLaunchKernelGGL(k_scan_part, dim3(nbN), dim3(256), 0, stream, deg, bsum, NN);
        hipLaunchKernelGGL(k_scan_mid, dim3(1), dim3(1024), 0, stream, bsum, bexcl, nbN, eoff, NN);
        hipLaunchKernelGGL(k_scan_out, dim3(nbN), dim3(256), 0, stream, deg, bexcl, eoff, NN);
    }
    hipLaunchKernelGGL(k_fill_csr, dim3((NE + 255) / 256), dim3(256), 0, stream, e_src, e_dst, eoff, cursor, csr, NE);

    // ---------- batched weight transpose (one launch) ----------
    {
        WtJobs j;
        int idx = 0, tiles = 0;
        auto add = [&](const float* s, _Float16* d, int K, int N) {
            j.src[idx] = s; j.dst[idx] = d;
            j.K32[idx] = (short)(K / 32); j.N32[idx] = (short)(N / 32);
            j.pre[idx] = (short)tiles;
            tiles += (K / 32) * (N / 32);
            ++idx;
        };
        add(pre_W1, preW1t, DIN, HD);
        add(pre_W2, preW2t, HD, HD);
        add(post_W1, postW1t, HD, HD);
        add(post_W2, postW2t, HD, DOUT);
        for (int i = 0; i < NL; ++i) {
            add(gin_W1 + (size_t)i * HD * HD, ginW1t + (size_t)i * HD * HD, HD, HD);
            add(gin_W2 + (size_t)i * HD * HD, ginW2t + (size_t)i * HD * HD, HD, HD);
            add(ffn_W1 + (size_t)i * HD * HD, ffnW1t + (size_t)i * HD * HD, HD, HD);
            add(ffn_W2 + (size_t)i * HD * HD, ffnW2t + (size_t)i * HD * HD, HD, HD);
            add(upd_W1 + (size_t)i * HD * HD, updW1t + (size_t)i * HD * HD, HD, HD);
            add(upd_W2 + (size_t)i * HD * H4, updW2t + (size_t)i * HD * H4, HD, H4);
            add(prop_W1 + (size_t)i * H4 * HD, propW1t + (size_t)i * H4 * HD, H4, HD);
            add(prop_W2 + (size_t)i * HD * HD, propW2t + (size_t)i * HD * HD, HD, HD);
        }
        j.pre[idx] = (short)tiles;
        hipLaunchKernelGGL(k_wtb, dim3(tiles), dim3(32, 8), 0, stream, j);
    }

    // x -> fp16
    int n4 = NN * DIN / 4;
    hipLaunchKernelGGL(k_cvt16, dim3((n4 + 255) / 256), dim3(256), 0, stream, x, x16, n4);

    const int nb2b = NNP / 64;

    // ---------- pre-FFNN (fused pair): h16 = gelu(x@W1+b1)@W2+b2 ----------
    hipLaunchKernelGGL((k_b2b<false, false, false, false>), dim3(nb2b), dim3(512), 0, stream,
                       x16, nullptr, preW1t, pre_b1, preW2t, pre_b2,
                       nullptr, nullptr, nullptr, nullptr, nullptr, nullptr,
                       h16, NN, DIN);

    for (int i = 0; i < NL; ++i) {
        const _Float16* uW1 = updW1t + (size_t)i * HD * HD;
        const _Float16* uW2 = updW2t + (size_t)i * HD * H4;
        const _Float16* pW1 = propW1t + (size_t)i * H4 * HD;
        const _Float16* pW2 = propW2t + (size_t)i * HD * HD;

        // virtual-node path (M = NG = 512) via MFMA GEMMs (r10-proven)
        hipLaunchKernelGGL(k_pool16, dim3(NG), dim3(HD), 0, stream, h16, goff, pool16);
        mg_gelu(stream, pool16, uW1, upd_b1 + (size_t)i * HD, u16, NG, HD, HD);
        mg_bias2_16(stream, u16, uW2, upd_b2 + (size_t)i * H4, vn, vb16, NG, H4, HD);
        mg_gelu(stream, vb16, pW1, prop_b1 + (size_t)i * HD, p16, NG, HD, H4);
        mg_f32only(stream, p16, pW2, prop_b2 + (size_t)i * HD, outvn32, NG, HD, HD);

        // GIN: t16a = agg(h16); g16 = gelu(t16a@gW1+b1)@gW2+b2 + h16 (+BN stats)
        hipLaunchKernelGGL(k_agg16, dim3(NN / 4), dim3(256), 0, stream, h16, eoff, csr, t16a);
        hipLaunchKernelGGL((k_b2b<false, true, false, true>), dim3(nb2b), dim3(512), 0, stream,
                           t16a, nullptr,
                           ginW1t + (size_t)i * HD * HD, gin_b1 + (size_t)i * HD,
                           ginW2t + (size_t)i * HD * HD, gin_b2 + (size_t)i * HD,
                           h16, nullptr, nullptr, nullptr, nullptr, bnstat,
                           g16, NN, HD);

        // BN finalize (re-zeroes stat)
        hipLaunchKernelGGL(k_bn_final, dim3(1), dim3(HD), 0, stream, bnstat,
                           bn_gamma + (size_t)i * HD, bn_beta + (size_t)i * HD, bnscale, bnshift);

        // FFN fused pair: h16 = gelu((bn(g16)+ovn)@fW1+b1)@fW2+b2 + bn(g16)
        hipLaunchKernelGGL((k_b2b<true, false, true, false>), dim3(nb2b), dim3(512), 0, stream,
                           nullptr, g16,
                           ffnW1t + (size_t)i * HD * HD, ffn_b1 + (size_t)i * HD,
                           ffnW2t + (size_t)i * HD * HD, ffn_b2 + (size_t)i * HD,
                           g16, bnscale, bnshift, outvn32, batch, nullptr,
                           h16, NN, HD);
    }

    // ---------- post ----------
    hipLaunchKernelGGL(k_pool16, dim3(NG), dim3(HD), 0, stream, h16, goff, pool16);
    mg_gelu(stream, pool16, postW1t, post_b1, u16, NG, HD, HD);
    mg_f32only(stream, u16, postW2t, post_b2, out, NG, DOUT, HD);
}

// Round 16
// 1647.890 us; speedup vs baseline: 1.1202x; 1.0158x over previous
//
#include <hip/hip_runtime.h>
#include <hip/hip_bf16.h>
#include <math.h>

#define NN 50000
#define NNP 50048          // padded to multiple of 128
#define NE 800000
#define NG 512
#define DIN 128
#define HD 256
#define DOUT 128
#define NL 5
#define H4 1024

typedef _Float16 f16x8 __attribute__((ext_vector_type(8)));
typedef _Float16 f16x4 __attribute__((ext_vector_type(4)));
typedef float f32x4 __attribute__((ext_vector_type(4)));

__device__ __forceinline__ float gelu_exact(float x) {
    return 0.5f * x * (1.0f + erff(x * 0.70710678118654752f));
}

__device__ __forceinline__ void gl_lds16(const _Float16* g, _Float16* l) {
    __builtin_amdgcn_global_load_lds(
        (const __attribute__((address_space(1))) unsigned int*)g,
        (__attribute__((address_space(3))) unsigned int*)l, 16, 0, 0);
}

// ---------------- graph meta ----------------
__global__ void k_hist(const int* __restrict__ idx, int* __restrict__ cnt, int n) {
    int i = blockIdx.x * blockDim.x + threadIdx.x;
    if (i < n) atomicAdd(&cnt[idx[i]], 1);
}

__global__ void k_scan_small(const int* __restrict__ in, int* __restrict__ out, int n) {
    __shared__ int buf[1024];
    int t = threadIdx.x;
    int v = (t < n) ? in[t] : 0;
    buf[t] = v;
    __syncthreads();
    for (int off = 1; off < 1024; off <<= 1) {
        int x = (t >= off) ? buf[t - off] : 0;
        __syncthreads();
        buf[t] += x;
        __syncthreads();
    }
    if (t < n) out[t] = buf[t] - v;
    if (t == 1023) out[n] = buf[1023];
}

__global__ void k_scan_part(const int* __restrict__ in, int* __restrict__ bsum, int n) {
    __shared__ int buf[256];
    int i = blockIdx.x * 256 + threadIdx.x;
    buf[threadIdx.x] = (i < n) ? in[i] : 0;
    __syncthreads();
    for (int off = 128; off > 0; off >>= 1) {
        if (threadIdx.x < off) buf[threadIdx.x] += buf[threadIdx.x + off];
        __syncthreads();
    }
    if (threadIdx.x == 0) bsum[blockIdx.x] = buf[0];
}

__global__ void k_scan_mid(const int* __restrict__ bsum, int* __restrict__ bexcl, int nb,
                           int* __restrict__ out, int n) {
    __shared__ int buf[1024];
    int t = threadIdx.x;
    int v = (t < nb) ? bsum[t] : 0;
    buf[t] = v;
    __syncthreads();
    for (int off = 1; off < 1024; off <<= 1) {
        int x = (t >= off) ? buf[t - off] : 0;
        __syncthreads();
        buf[t] += x;
        __syncthreads();
    }
    if (t < nb) bexcl[t] = buf[t] - v;
    if (t == 1023) out[n] = buf[1023];
}

__global__ void k_scan_out(const int* __restrict__ in, const int* __restrict__ bexcl,
                           int* __restrict__ out, int n) {
    __shared__ int buf[256];
    int i = blockIdx.x * 256 + threadIdx.x;
    int t = threadIdx.x;
    int v = (i < n) ? in[i] : 0;
    buf[t] = v;
    __syncthreads();
    for (int off = 1; off < 256; off <<= 1) {
        int x = (t >= off) ? buf[t - off] : 0;
        __syncthreads();
        buf[t] += x;
        __syncthreads();
    }
    if (i < n) out[i] = bexcl[blockIdx.x] + buf[t] - v;
}

__global__ void k_fill_csr(const int* __restrict__ src, const int* __restrict__ dst,
                           const int* __restrict__ eoff, int* __restrict__ cursor,
                           int* __restrict__ csr, int n) {
    int e = blockIdx.x * blockDim.x + threadIdx.x;
    if (e < n) {
        int d = dst[e];
        int p = atomicAdd(&cursor[d], 1);
        csr[eoff[d] + p] = src[e];
    }
}

// ---------------- converts ----------------
__global__ void k_cvt16(const float* __restrict__ in, _Float16* __restrict__ out, int n4) {
    int i = blockIdx.x * blockDim.x + threadIdx.x;
    if (i < n4) {
        float4 v = *(const float4*)&in[i * 4];
        f16x4 o = { (_Float16)v.x, (_Float16)v.y, (_Float16)v.z, (_Float16)v.w };
        *(f16x4*)&out[i * 4] = o;
    }
}

// batched transpose + convert: one launch for all weight matrices
#define NWTJOBS 44
struct WtJobs {
    const float* src[NWTJOBS];
    _Float16* dst[NWTJOBS];
    short K32[NWTJOBS];
    short N32[NWTJOBS];
    short pre[NWTJOBS + 1];
};
__global__ void k_wtb(WtJobs j) {
    int bid = blockIdx.x;
    int lo = 0;
    while (j.pre[lo + 1] <= bid) ++lo;
    int tl = bid - j.pre[lo];
    int nx = j.N32[lo];
    int n0 = (tl % nx) * 32, k0 = (tl / nx) * 32;
    int K = j.K32[lo] * 32, N = nx * 32;
    const float* W = j.src[lo];
    _Float16* Wt = j.dst[lo];
    __shared__ float tile[32][33];
    for (int i = threadIdx.y; i < 32; i += 8)
        tile[i][threadIdx.x] = W[(size_t)(k0 + i) * N + n0 + threadIdx.x];
    __syncthreads();
    for (int i = threadIdx.y; i < 32; i += 8)
        Wt[(size_t)(n0 + i) * K + k0 + threadIdx.x] = (_Float16)tile[threadIdx.x][i];
}

// ---------------- pooling / aggregation ----------------
__global__ void k_pool16(const _Float16* __restrict__ h16, const int* __restrict__ goff,
                         _Float16* __restrict__ pool) {
    int g = blockIdx.x;
    int c = threadIdx.x;
    int s = goff[g], e = goff[g + 1];
    float acc = 0.f;
    for (int r = s; r < e; ++r) acc += (float)h16[(size_t)r * HD + c];
    int cnt = e - s;
    pool[g * HD + c] = (_Float16)(acc / (float)(cnt > 0 ? cnt : 1));
}

// one wave per node; WAVE-UNIFORM loop bounds; 8 edges/iter
__global__ __launch_bounds__(256) void k_agg16(const _Float16* __restrict__ h16,
                                               const int* __restrict__ eoff,
                                               const int* __restrict__ csr,
                                               _Float16* __restrict__ out) {
    int node = blockIdx.x * 4 + (threadIdx.x >> 6);
    int lane = threadIdx.x & 63;
    int half = lane >> 5, l = lane & 31;
    f16x8 mine = *(const f16x8*)&h16[(size_t)node * HD + l * 8];
    float acc[8];
#pragma unroll
    for (int q = 0; q < 8; ++q) acc[q] = half ? 0.f : (float)mine[q];
    int s = eoff[node], e = eoff[node + 1];
    for (int base = s; base < e; base += 64) {
        int myi = base + lane;
        int vidx = (myi < e) ? csr[myi] : 0;
        int cnt = min(64, e - base);
        int jj = 0;
        for (; jj + 7 < cnt; jj += 8) {
            int s0 = __shfl(vidx, jj + half);
            int s1 = __shfl(vidx, jj + 2 + half);
            int s2 = __shfl(vidx, jj + 4 + half);
            int s3 = __shfl(vidx, jj + 6 + half);
            f16x8 v0 = *(const f16x8*)&h16[(size_t)s0 * HD + l * 8];
            f16x8 v1 = *(const f16x8*)&h16[(size_t)s1 * HD + l * 8];
            f16x8 v2 = *(const f16x8*)&h16[(size_t)s2 * HD + l * 8];
            f16x8 v3 = *(const f16x8*)&h16[(size_t)s3 * HD + l * 8];
#pragma unroll
            for (int q = 0; q < 8; ++q)
                acc[q] += ((float)v0[q] + (float)v1[q]) + ((float)v2[q] + (float)v3[q]);
        }
        for (; jj + 3 < cnt; jj += 4) {
            int s0 = __shfl(vidx, jj + half);
            int s1 = __shfl(vidx, jj + 2 + half);
            f16x8 v0 = *(const f16x8*)&h16[(size_t)s0 * HD + l * 8];
            f16x8 v1 = *(const f16x8*)&h16[(size_t)s1 * HD + l * 8];
#pragma unroll
            for (int q = 0; q < 8; ++q) acc[q] += (float)v0[q] + (float)v1[q];
        }
        for (; jj < cnt; jj += 2) {
            int i0 = jj + half;
            int s0 = __shfl(vidx, i0);
            if (i0 < cnt) {
                f16x8 v0 = *(const f16x8*)&h16[(size_t)s0 * HD + l * 8];
#pragma unroll
                for (int q = 0; q < 8; ++q) acc[q] += (float)v0[q];
            }
        }
    }
#pragma unroll
    for (int q = 0; q < 8; ++q) acc[q] += __shfl_xor(acc[q], 32);
    if (!half) {
        f16x8 o;
#pragma unroll
        for (int q = 0; q < 8; ++q) o[q] = (_Float16)acc[q];
        *(f16x8*)&out[(size_t)node * HD + l * 8] = o;
    }
}

// ---------------- batch norm finalize (also re-zeroes stat for next layer) ----
__global__ void k_bn_final(float* __restrict__ stat,
                           const float* __restrict__ gamma, const float* __restrict__ beta,
                           float* __restrict__ scale, float* __restrict__ shift) {
    int c = threadIdx.x;
    float mu = stat[c] * (1.0f / NN);
    float var = stat[HD + c] * (1.0f / NN) - mu * mu;
    float rs = rsqrtf(var + 1e-5f);
    float sc = rs * gamma[c];
    scale[c] = sc;
    shift[c] = beta[c] - mu * sc;
    stat[c] = 0.f;
    stat[HD + c] = 0.f;
}

// ======== fused back-to-back FFNN: counted-vmcnt pipeline (T4) ========
// C16 = gelu(A@W1+b1)@W2+b2 [+res].  A-tile resident in AC (32 KB); B staged
// through a 3-deep ring (48 KB) with loads issued 2 steps ahead.  Barriers are
// raw s_barrier with asm s_waitcnt vmcnt(2) -- one B load-group always stays
// in flight across the barrier (never drain to 0 in the main loop).
template <bool ABN1, bool RES2, bool RESBN2, bool STATS2, int K1>
__global__ __launch_bounds__(512) void k_b2b(const _Float16* __restrict__ A16,
                                             const _Float16* __restrict__ G16,
                                             const _Float16* __restrict__ W1t,
                                             const float* __restrict__ b1,
                                             const _Float16* __restrict__ W2t,
                                             const float* __restrict__ b2,
                                             const _Float16* __restrict__ R16,
                                             const float* __restrict__ bnsc,
                                             const float* __restrict__ bnsh,
                                             const float* __restrict__ ovn,
                                             const int* __restrict__ batchv,
                                             float* __restrict__ stat,
                                             _Float16* __restrict__ C16,
                                             int M) {
    __shared__ _Float16 AC[32][64][8];      // 32 KB: A-tile (stage 1) then C1 (stage 2)
    __shared__ _Float16 Bs[3][4][256][8];   // 48 KB weight ring
    constexpr int NT1 = K1 >> 5;
    constexpr int NSTEP = NT1 + 8;
    const int t = threadIdx.x;
    const int w = t >> 6, lane = t & 63;
    const int m0 = blockIdx.x * 64;
    const int kb = lane >> 4, fr = lane & 15, rr = lane >> 4;

    auto stageB = [&](int s) {
        const _Float16* Wt = (s < NT1) ? W1t : W2t;
        const int KB = (s < NT1) ? K1 : HD;
        const int k0 = ((s < NT1) ? s : (s - NT1)) << 5;
        const int buf = s % 3;
        int s0 = t, s1 = t + 512;
        gl_lds16(Wt + (size_t)(s0 & 255) * KB + k0 + (s0 >> 8) * 8, &Bs[buf][s0 >> 8][s0 & 255][0]);
        gl_lds16(Wt + (size_t)(s1 & 255) * KB + k0 + (s1 >> 8) * 8, &Bs[buf][s1 >> 8][s1 & 255][0]);
    };

    // preload b1 (issued before stage loads -> consuming it never drains prefetch)
    float b1r[2];
#pragma unroll
    for (int ni = 0; ni < 2; ++ni) b1r[ni] = b1[w * 32 + ni * 16 + fr];

    // ---- prologue: A tile -> AC ----
    if constexpr (ABN1) {
        for (int c = t; c < K1 * 8; c += 512) {
            int kblk = c >> 6, row = c & 63;
            int b0 = batchv[min(m0 + row, M - 1)];
            const int c0 = kblk * 8;
            f16x8 g = *(const f16x8*)&G16[(size_t)(m0 + row) * HD + c0];
            f16x8 r0;
#pragma unroll
            for (int q = 0; q < 8; ++q)
                r0[q] = (_Float16)((float)g[q] * bnsc[c0 + q] + bnsh[c0 + q] +
                                   ovn[(size_t)b0 * HD + c0 + q]);
            *(f16x8*)&AC[kblk][row][0] = r0;
        }
    } else {
        for (int c = t; c < K1 * 8; c += 512) {
            int kblk = c >> 6, row = c & 63;
            gl_lds16(A16 + (size_t)(m0 + row) * K1 + kblk * 8, &AC[kblk][row][0]);
        }
    }
    stageB(0);
    stageB(1);
    asm volatile("s_waitcnt vmcnt(2) lgkmcnt(0)" ::: "memory");
    __builtin_amdgcn_s_barrier();

    // ---- stage 1 ----
    f32x4 acc1[4][2];
#pragma unroll
    for (int mi = 0; mi < 4; ++mi)
#pragma unroll
        for (int ni = 0; ni < 2; ++ni) acc1[mi][ni] = (f32x4){0.f, 0.f, 0.f, 0.f};

#pragma unroll
    for (int s = 0; s < NT1; ++s) {
        if (s) {
            asm volatile("s_waitcnt vmcnt(2)" ::: "memory");
            __builtin_amdgcn_s_barrier();
        }
        f16x8 af[4], bf[2];
#pragma unroll
        for (int mi = 0; mi < 4; ++mi)
            af[mi] = *(const f16x8*)&AC[(s << 2) + kb][mi * 16 + fr][0];
#pragma unroll
        for (int ni = 0; ni < 2; ++ni)
            bf[ni] = *(const f16x8*)&Bs[s % 3][kb][w * 32 + ni * 16 + fr][0];
        stageB(s + 2);
#pragma unroll
        for (int mi = 0; mi < 4; ++mi)
#pragma unroll
            for (int ni = 0; ni < 2; ++ni)
                acc1[mi][ni] = __builtin_amdgcn_mfma_f32_16x16x32_f16(af[mi], bf[ni], acc1[mi][ni], 0, 0, 0);
    }

    // ---- handoff: C1 -> AC ----
    asm volatile("s_waitcnt vmcnt(2)" ::: "memory");
    __builtin_amdgcn_s_barrier();
#pragma unroll
    for (int mi = 0; mi < 4; ++mi) {
#pragma unroll
        for (int reg = 0; reg < 4; ++reg) {
            int ml = mi * 16 + rr * 4 + reg;
#pragma unroll
            for (int ni = 0; ni < 2; ++ni) {
                int n = w * 32 + ni * 16 + fr;
                float v = gelu_exact(acc1[mi][ni][reg] + b1r[ni]);
                AC[n >> 3][ml][n & 7] = (_Float16)v;
            }
        }
    }
    asm volatile("s_waitcnt lgkmcnt(0)" ::: "memory");
    __builtin_amdgcn_s_barrier();

    // ---- stage 2 (K2 = 256) ----
    f32x4 acc2[4][2];
#pragma unroll
    for (int mi = 0; mi < 4; ++mi)
#pragma unroll
        for (int ni = 0; ni < 2; ++ni) acc2[mi][ni] = (f32x4){0.f, 0.f, 0.f, 0.f};

#pragma unroll
    for (int s2 = 0; s2 < 8; ++s2) {
        const int s = NT1 + s2;
        if (s2) {
            if (s2 == 7) asm volatile("s_waitcnt vmcnt(0)" ::: "memory");
            else asm volatile("s_waitcnt vmcnt(2)" ::: "memory");
            __builtin_amdgcn_s_barrier();
        }
        f16x8 af[4], bf[2];
#pragma unroll
        for (int mi = 0; mi < 4; ++mi)
            af[mi] = *(const f16x8*)&AC[s2 * 4 + kb][mi * 16 + fr][0];
#pragma unroll
        for (int ni = 0; ni < 2; ++ni)
            bf[ni] = *(const f16x8*)&Bs[s % 3][kb][w * 32 + ni * 16 + fr][0];
        if (s + 2 < NSTEP) stageB(s + 2);
#pragma unroll
        for (int mi = 0; mi < 4; ++mi)
#pragma unroll
            for (int ni = 0; ni < 2; ++ni)
                acc2[mi][ni] = __builtin_amdgcn_mfma_f32_16x16x32_f16(af[mi], bf[ni], acc2[mi][ni], 0, 0, 0);
    }

    // ---- epilogue 2 ----
    float cs[2] = {0.f, 0.f}, cq[2] = {0.f, 0.f};
#pragma unroll
    for (int mi = 0; mi < 4; ++mi) {
#pragma unroll
        for (int reg = 0; reg < 4; ++reg) {
            int m = m0 + mi * 16 + rr * 4 + reg;
            if (m < M) {
#pragma unroll
                for (int ni = 0; ni < 2; ++ni) {
                    int n = w * 32 + ni * 16 + fr;
                    float v = acc2[mi][ni][reg] + b2[n];
                    if (RES2) v += (float)R16[(size_t)m * HD + n];
                    if (RESBN2) v += (float)R16[(size_t)m * HD + n] * bnsc[n] + bnsh[n];
                    _Float16 vh = (_Float16)v;
                    C16[(size_t)m * HD + n] = vh;
                    if (STATS2) { float vr = (float)vh; cs[ni] += vr; cq[ni] += vr * vr; }
                }
            }
        }
    }
    if constexpr (STATS2) {
#pragma unroll
        for (int ni = 0; ni < 2; ++ni) {
            cs[ni] += __shfl_xor(cs[ni], 16); cs[ni] += __shfl_xor(cs[ni], 32);
            cq[ni] += __shfl_xor(cq[ni], 16); cq[ni] += __shfl_xor(cq[ni], 32);
        }
        if (lane < 16) {
#pragma unroll
            for (int ni = 0; ni < 2; ++ni) {
                int n = w * 32 + ni * 16 + lane;
                atomicAdd(&stat[n], cs[ni]);
                atomicAdd(&stat[HD + n], cq[ni]);
            }
        }
    }
}

// ---------------- MFMA fp16 GEMM (64x128 tile) — VN/post path ----------------
template <bool GELU, bool BIAS2, bool O32, bool O16>
__global__ __launch_bounds__(256) void k_mgemm(const _Float16* __restrict__ A,
                                               const _Float16* __restrict__ Wt,
                                               const float* __restrict__ bias,
                                               const float* __restrict__ bias2,
                                               float* __restrict__ C32,
                                               _Float16* __restrict__ C16,
                                               int M, int N, int K) {
    __shared__ _Float16 As[2][4][64][8];
    __shared__ _Float16 Bs[2][4][128][8];
    const int t = threadIdx.x;
    const int w = t >> 6, lane = t & 63;
    const int m0 = blockIdx.y * 64, n0 = blockIdx.x * 128;
    const int kb = lane >> 4, fr = lane & 15;

    f32x4 acc[4][2];
#pragma unroll
    for (int mi = 0; mi < 4; ++mi)
#pragma unroll
        for (int ni = 0; ni < 2; ++ni) acc[mi][ni] = (f32x4){0.f, 0.f, 0.f, 0.f};

    const _Float16* gA0 = A + (size_t)(m0 + lane) * K + w * 8;
    const _Float16* gB0 = Wt + (size_t)(n0 + lane) * K + w * 8;
    const _Float16* gB1 = Wt + (size_t)(n0 + 64 + lane) * K + w * 8;

    auto stage = [&](int buf, int k0) {
        gl_lds16(gB0 + k0, &Bs[buf][w][0][0]);
        gl_lds16(gB1 + k0, &Bs[buf][w][64][0]);
        gl_lds16(gA0 + k0, &As[buf][w][0][0]);
    };

    const int nt = K >> 5;
    stage(0, 0);
    __syncthreads();
    for (int tt = 0; tt < nt; ++tt) {
        const int cur = tt & 1;
        if (tt + 1 < nt) stage(cur ^ 1, (tt + 1) << 5);
        f16x8 af[4], bf[2];
#pragma unroll
        for (int mi = 0; mi < 4; ++mi)
            af[mi] = *(const f16x8*)&As[cur][kb][mi * 16 + fr][0];
#pragma unroll
        for (int ni = 0; ni < 2; ++ni)
            bf[ni] = *(const f16x8*)&Bs[cur][kb][w * 32 + ni * 16 + fr][0];
#pragma unroll
        for (int mi = 0; mi < 4; ++mi)
#pragma unroll
            for (int ni = 0; ni < 2; ++ni)
                acc[mi][ni] = __builtin_amdgcn_mfma_f32_16x16x32_f16(af[mi], bf[ni], acc[mi][ni], 0, 0, 0);
        __syncthreads();
    }

    const int rr = lane >> 4;
#pragma unroll
    for (int mi = 0; mi < 4; ++mi) {
#pragma unroll
        for (int reg = 0; reg < 4; ++reg) {
            int m = m0 + mi * 16 + rr * 4 + reg;
            if (m < M) {
#pragma unroll
                for (int ni = 0; ni < 2; ++ni) {
                    int n = n0 + w * 32 + ni * 16 + fr;
                    float v = acc[mi][ni][reg] + bias[n];
                    if (BIAS2) v += bias2[n];
                    if (GELU) v = gelu_exact(v);
                    if (O32) C32[(size_t)m * N + n] = v;
                    if (O16) C16[(size_t)m * N + n] = (_Float16)v;
                }
            }
        }
    }
}

static inline void mg_gelu(hipStream_t st, const _Float16* A, const _Float16* Wt,
                           const float* bias, _Float16* C16, int M, int N, int K) {
    dim3 g(N / 128, (M + 63) / 64), b(256);
    k_mgemm<true, false, false, true><<<g, b, 0, st>>>(A, Wt, bias, nullptr, nullptr, C16, M, N, K);
}
static inline void mg_bias2_16(hipStream_t st, const _Float16* A, const _Float16* Wt,
                               const float* bias, const float* bias2, _Float16* C16,
                               int M, int N, int K) {
    dim3 g(N / 128, (M + 63) / 64), b(256);
    k_mgemm<false, true, false, true><<<g, b, 0, st>>>(A, Wt, bias, bias2, nullptr, C16, M, N, K);
}
static inline void mg_f32only(hipStream_t st, const _Float16* A, const _Float16* Wt,
                              const float* bias, float* C32, int M, int N, int K) {
    dim3 g(N / 128, (M + 63) / 64), b(256);
    k_mgemm<false, false, true, false><<<g, b, 0, st>>>(A, Wt, bias, nullptr, C32, nullptr, M, N, K);
}

extern "C" void kernel_launch(void* const* d_in, const int* in_sizes, int n_in,
                              void* d_out, int out_size, void* d_ws, size_t ws_size,
                              hipStream_t stream) {
    const float* x       = (const float*)d_in[0];
    const int*   ei      = (const int*)d_in[1];
    const int*   batch   = (const int*)d_in[2];
    const float* pre_W1  = (const float*)d_in[3];
    const float* pre_b1  = (const float*)d_in[4];
    const float* pre_W2  = (const float*)d_in[5];
    const float* pre_b2  = (const float*)d_in[6];
    const float* gin_W1  = (const float*)d_in[7];
    const float* gin_b1  = (const float*)d_in[8];
    const float* gin_W2  = (const float*)d_in[9];
    const float* gin_b2  = (const float*)d_in[10];
    const float* ffn_W1  = (const float*)d_in[11];
    const float* ffn_b1  = (const float*)d_in[12];
    const float* ffn_W2  = (const float*)d_in[13];
    const float* ffn_b2  = (const float*)d_in[14];
    const float* upd_W1  = (const float*)d_in[15];
    const float* upd_b1  = (const float*)d_in[16];
    const float* upd_W2  = (const float*)d_in[17];
    const float* upd_b2  = (const float*)d_in[18];
    const float* prop_W1 = (const float*)d_in[19];
    const float* prop_b1 = (const float*)d_in[20];
    const float* prop_W2 = (const float*)d_in[21];
    const float* prop_b2 = (const float*)d_in[22];
    const float* bn_gamma= (const float*)d_in[23];
    const float* bn_beta = (const float*)d_in[24];
    const float* vn      = (const float*)d_in[25];
    const float* post_W1 = (const float*)d_in[26];
    const float* post_b1 = (const float*)d_in[27];
    const float* post_W2 = (const float*)d_in[28];
    const float* post_b2 = (const float*)d_in[29];
    float* out = (float*)d_out;

    const int* e_src = ei;
    const int* e_dst = ei + NE;

    // ---------- workspace layout ----------
    char* p = (char*)d_ws;
    auto alloc = [&](size_t bytes) -> char* {
        char* r = p;
        p += (bytes + 255) & ~(size_t)255;
        return r;
    };
    _Float16* h16    = (_Float16*)alloc((size_t)NNP * HD * 2);   // fp16 backbone
    _Float16* g16    = (_Float16*)alloc((size_t)NNP * HD * 2);   // gin output (pre-BN)
    _Float16* t16a   = (_Float16*)alloc((size_t)NNP * HD * 2);   // agg out; aliases x16
    _Float16* pool16 = (_Float16*)alloc((size_t)NG * HD * 2);
    _Float16* u16    = (_Float16*)alloc((size_t)NG * HD * 2);
    _Float16* vb16   = (_Float16*)alloc((size_t)NG * H4 * 2);
    _Float16* p16    = (_Float16*)alloc((size_t)NG * HD * 2);
    float*    outvn32= (float*)alloc((size_t)NG * HD * 4);
    float*    bnstat = (float*)alloc(2 * HD * 4);
    float*    bnscale= (float*)alloc(HD * 4);
    float*    bnshift= (float*)alloc(HD * 4);
    _Float16* preW1t = (_Float16*)alloc((size_t)HD * DIN * 2);
    _Float16* preW2t = (_Float16*)alloc((size_t)HD * HD * 2);
    _Float16* ginW1t = (_Float16*)alloc((size_t)NL * HD * HD * 2);
    _Float16* ginW2t = (_Float16*)alloc((size_t)NL * HD * HD * 2);
    _Float16* ffnW1t = (_Float16*)alloc((size_t)NL * HD * HD * 2);
    _Float16* ffnW2t = (_Float16*)alloc((size_t)NL * HD * HD * 2);
    _Float16* updW1t = (_Float16*)alloc((size_t)NL * HD * HD * 2);
    _Float16* updW2t = (_Float16*)alloc((size_t)NL * HD * H4 * 2);
    _Float16* propW1t= (_Float16*)alloc((size_t)NL * H4 * HD * 2);
    _Float16* propW2t= (_Float16*)alloc((size_t)NL * HD * HD * 2);
    _Float16* postW1t= (_Float16*)alloc((size_t)HD * HD * 2);
    _Float16* postW2t= (_Float16*)alloc((size_t)DOUT * HD * 2);
    int* gcount = (int*)alloc(NG * 4);
    int* goff   = (int*)alloc((NG + 1) * 4);
    int* deg    = (int*)alloc(NN * 4);
    int* eoff   = (int*)alloc((NN + 1) * 4);
    int* cursor = (int*)alloc(NN * 4);
    int* csr    = (int*)alloc((size_t)NE * 4);
    int* bsum   = (int*)alloc(1024 * 4);
    int* bexcl  = (int*)alloc(1024 * 4);
    _Float16* x16 = t16a;   // alias: consumed by pre-pair before t16a is first written

    // ---------- zero counters + bnstat ----------
    {
        size_t span = (size_t)((char*)(cursor + NN) - (char*)gcount);
        hipMemsetAsync(gcount, 0, span, stream);
        hipMemsetAsync(bnstat, 0, 2 * HD * 4, stream);
    }
    hipLaunchKernelGGL(k_hist, dim3((NN + 255) / 256), dim3(256), 0, stream, batch, gcount, NN);
    hipLaunchKernelGGL(k_hist, dim3((NE + 255) / 256), dim3(256), 0, stream, e_dst, deg, NE);
    hipLaunchKernelGGL(k_scan_small, dim3(1), dim3(1024), 0, stream, gcount, goff, NG);
    {
        int nbN = (NN + 255) / 256;
        hipLaunchKernelGGL(k_scan_part, dim3(nbN), dim3(256), 0, stream, deg, bsum, NN);
        hipLaunchKernelGGL(k_scan_mid, dim3(1), dim3(1024), 0, stream, bsum, bexcl, nbN, eoff, NN);
        hipLaunchKernelGGL(k_scan_out, dim3(nbN), dim3(256), 0, stream, deg, bexcl, eoff, NN);
    }
    hipLaunchKernelGGL(k_fill_csr, dim3((NE + 255) / 256), dim3(256), 0, stream, e_src, e_dst, eoff, cursor, csr, NE);

    // ---------- batched weight transpose (one launch) ----------
    {
        WtJobs j;
        int idx = 0, tiles = 0;
        auto add = [&](const float* s, _Float16* d, int K, int N) {
            j.src[idx] = s; j.dst[idx] = d;
            j.K32[idx] = (short)(K / 32); j.N32[idx] = (short)(N / 32);
            j.pre[idx] = (short)tiles;
            tiles += (K / 32) * (N / 32);
            ++idx;
        };
        add(pre_W1, preW1t, DIN, HD);
        add(pre_W2, preW2t, HD, HD);
        add(post_W1, postW1t, HD, HD);
        add(post_W2, postW2t, HD, DOUT);
        for (int i = 0; i < NL; ++i) {
            add(gin_W1 + (size_t)i * HD * HD, ginW1t + (size_t)i * HD * HD, HD, HD);
            add(gin_W2 + (size_t)i * HD * HD, ginW2t + (size_t)i * HD * HD, HD, HD);
            add(ffn_W1 + (size_t)i * HD * HD, ffnW1t + (size_t)i * HD * HD, HD, HD);
            add(ffn_W2 + (size_t)i * HD * HD, ffnW2t + (size_t)i * HD * HD, HD, HD);
            add(upd_W1 + (size_t)i * HD * HD, updW1t + (size_t)i * HD * HD, HD, HD);
            add(upd_W2 + (size_t)i * HD * H4, updW2t + (size_t)i * HD * H4, HD, H4);
            add(prop_W1 + (size_t)i * H4 * HD, propW1t + (size_t)i * H4 * HD, H4, HD);
            add(prop_W2 + (size_t)i * HD * HD, propW2t + (size_t)i * HD * HD, HD, HD);
        }
        j.pre[idx] = (short)tiles;
        hipLaunchKernelGGL(k_wtb, dim3(tiles), dim3(32, 8), 0, stream, j);
    }

    // x -> fp16
    int n4 = NN * DIN / 4;
    hipLaunchKernelGGL(k_cvt16, dim3((n4 + 255) / 256), dim3(256), 0, stream, x, x16, n4);

    const int nb2b = NNP / 64;

    // ---------- pre-FFNN (fused pair): h16 = gelu(x@W1+b1)@W2+b2 ----------
    hipLaunchKernelGGL((k_b2b<false, false, false, false, DIN>), dim3(nb2b), dim3(512), 0, stream,
                       x16, nullptr, preW1t, pre_b1, preW2t, pre_b2,
                       nullptr, nullptr, nullptr, nullptr, nullptr, nullptr,
                       h16, NN);

    for (int i = 0; i < NL; ++i) {
        const _Float16* uW1 = updW1t + (size_t)i * HD * HD;
        const _Float16* uW2 = updW2t + (size_t)i * HD * H4;
        const _Float16* pW1 = propW1t + (size_t)i * H4 * HD;
        const _Float16* pW2 = propW2t + (size_t)i * HD * HD;

        // virtual-node path (M = NG = 512) via MFMA GEMMs
        hipLaunchKernelGGL(k_pool16, dim3(NG), dim3(HD), 0, stream, h16, goff, pool16);
        mg_gelu(stream, pool16, uW1, upd_b1 + (size_t)i * HD, u16, NG, HD, HD);
        mg_bias2_16(stream, u16, uW2, upd_b2 + (size_t)i * H4, vn, vb16, NG, H4, HD);
        mg_gelu(stream, vb16, pW1, prop_b1 + (size_t)i * HD, p16, NG, HD, H4);
        mg_f32only(stream, p16, pW2, prop_b2 + (size_t)i * HD, outvn32, NG, HD, HD);

        // GIN: t16a = agg(h16); g16 = gelu(t16a@gW1+b1)@gW2+b2 + h16 (+BN stats)
        hipLaunchKernelGGL(k_agg16, dim3(NN / 4), dim3(256), 0, stream, h16, eoff, csr, t16a);
        hipLaunchKernelGGL((k_b2b<false, true, false, true, HD>), dim3(nb2b), dim3(512), 0, stream,
                           t16a, nullptr,
                           ginW1t + (size_t)i * HD * HD, gin_b1 + (size_t)i * HD,
                           ginW2t + (size_t)i * HD * HD, gin_b2 + (size_t)i * HD,
                           h16, nullptr, nullptr, nullptr, nullptr, bnstat,
                           g16, NN);

        // BN finalize (re-zeroes stat)
        hipLaunchKernelGGL(k_bn_final, dim3(1), dim3(HD), 0, stream, bnstat,
                           bn_gamma + (size_t)i * HD, bn_beta + (size_t)i * HD, bnscale, bnshift);

        // FFN fused pair: h16 = gelu((bn(g16)+ovn)@fW1+b1)@fW2+b2 + bn(g16)
        hipLaunchKernelGGL((k_b2b<true, false, true, false, HD>), dim3(nb2b), dim3(512), 0, stream,
                           nullptr, g16,
                           ffnW1t + (size_t)i * HD * HD, ffn_b1 + (size_t)i * HD,
                           ffnW2t + (size_t)i * HD * HD, ffn_b2 + (size_t)i * HD,
                           g16, bnscale, bnshift, outvn32, batch, nullptr,
                           h16, NN);
    }

    // ---------- post ----------
    hipLaunchKernelGGL(k_pool16, dim3(NG), dim3(HD), 0, stream, h16, goff, pool16);
    mg_gelu(stream, pool16, postW1t, post_b1, u16, NG, HD, HD);
    mg_f32only(stream, u16, postW2t, post_b2, out, NG, DOUT, HD);
}

// Round 17
// 1639.377 us; speedup vs baseline: 1.1260x; 1.0052x over previous
//
#include <hip/hip_runtime.h>
#include <hip/hip_bf16.h>
#include <math.h>

#define NN 50000
#define NNP 50048          // padded to multiple of 128
#define NE 800000
#define NG 512
#define DIN 128
#define HD 256
#define DOUT 128
#define NL 5
#define H4 1024

typedef _Float16 f16x8 __attribute__((ext_vector_type(8)));
typedef _Float16 f16x4 __attribute__((ext_vector_type(4)));
typedef float f32x4 __attribute__((ext_vector_type(4)));

__device__ __forceinline__ float gelu_exact(float x) {
    return 0.5f * x * (1.0f + erff(x * 0.70710678118654752f));
}

__device__ __forceinline__ void gl_lds16(const _Float16* g, _Float16* l) {
    __builtin_amdgcn_global_load_lds(
        (const __attribute__((address_space(1))) unsigned int*)g,
        (__attribute__((address_space(3))) unsigned int*)l, 16, 0, 0);
}

// ---------------- graph meta ----------------
__global__ void k_hist(const int* __restrict__ idx, int* __restrict__ cnt, int n) {
    int i = blockIdx.x * blockDim.x + threadIdx.x;
    if (i < n) atomicAdd(&cnt[idx[i]], 1);
}

__global__ void k_scan_small(const int* __restrict__ in, int* __restrict__ out, int n) {
    __shared__ int buf[1024];
    int t = threadIdx.x;
    int v = (t < n) ? in[t] : 0;
    buf[t] = v;
    __syncthreads();
    for (int off = 1; off < 1024; off <<= 1) {
        int x = (t >= off) ? buf[t - off] : 0;
        __syncthreads();
        buf[t] += x;
        __syncthreads();
    }
    if (t < n) out[t] = buf[t] - v;
    if (t == 1023) out[n] = buf[1023];
}

__global__ void k_scan_part(const int* __restrict__ in, int* __restrict__ bsum, int n) {
    __shared__ int buf[256];
    int i = blockIdx.x * 256 + threadIdx.x;
    buf[threadIdx.x] = (i < n) ? in[i] : 0;
    __syncthreads();
    for (int off = 128; off > 0; off >>= 1) {
        if (threadIdx.x < off) buf[threadIdx.x] += buf[threadIdx.x + off];
        __syncthreads();
    }
    if (threadIdx.x == 0) bsum[blockIdx.x] = buf[0];
}

__global__ void k_scan_mid(const int* __restrict__ bsum, int* __restrict__ bexcl, int nb,
                           int* __restrict__ out, int n) {
    __shared__ int buf[1024];
    int t = threadIdx.x;
    int v = (t < nb) ? bsum[t] : 0;
    buf[t] = v;
    __syncthreads();
    for (int off = 1; off < 1024; off <<= 1) {
        int x = (t >= off) ? buf[t - off] : 0;
        __syncthreads();
        buf[t] += x;
        __syncthreads();
    }
    if (t < nb) bexcl[t] = buf[t] - v;
    if (t == 1023) out[n] = buf[1023];
}

__global__ void k_scan_out(const int* __restrict__ in, const int* __restrict__ bexcl,
                           int* __restrict__ out, int n) {
    __shared__ int buf[256];
    int i = blockIdx.x * 256 + threadIdx.x;
    int t = threadIdx.x;
    int v = (i < n) ? in[i] : 0;
    buf[t] = v;
    __syncthreads();
    for (int off = 1; off < 256; off <<= 1) {
        int x = (t >= off) ? buf[t - off] : 0;
        __syncthreads();
        buf[t] += x;
        __syncthreads();
    }
    if (i < n) out[i] = bexcl[blockIdx.x] + buf[t] - v;
}

__global__ void k_fill_csr(const int* __restrict__ src, const int* __restrict__ dst,
                           const int* __restrict__ eoff, int* __restrict__ cursor,
                           int* __restrict__ csr, int n) {
    int e = blockIdx.x * blockDim.x + threadIdx.x;
    if (e < n) {
        int d = dst[e];
        int p = atomicAdd(&cursor[d], 1);
        csr[eoff[d] + p] = src[e];
    }
}

// ---------------- converts ----------------
__global__ void k_cvt16(const float* __restrict__ in, _Float16* __restrict__ out, int n4) {
    int i = blockIdx.x * blockDim.x + threadIdx.x;
    if (i < n4) {
        float4 v = *(const float4*)&in[i * 4];
        f16x4 o = { (_Float16)v.x, (_Float16)v.y, (_Float16)v.z, (_Float16)v.w };
        *(f16x4*)&out[i * 4] = o;
    }
}

// batched transpose + convert: one launch for all weight matrices
#define NWTJOBS 44
struct WtJobs {
    const float* src[NWTJOBS];
    _Float16* dst[NWTJOBS];
    short K32[NWTJOBS];
    short N32[NWTJOBS];
    short pre[NWTJOBS + 1];
};
__global__ void k_wtb(WtJobs j) {
    int bid = blockIdx.x;
    int lo = 0;
    while (j.pre[lo + 1] <= bid) ++lo;
    int tl = bid - j.pre[lo];
    int nx = j.N32[lo];
    int n0 = (tl % nx) * 32, k0 = (tl / nx) * 32;
    int K = j.K32[lo] * 32, N = nx * 32;
    const float* W = j.src[lo];
    _Float16* Wt = j.dst[lo];
    __shared__ float tile[32][33];
    for (int i = threadIdx.y; i < 32; i += 8)
        tile[i][threadIdx.x] = W[(size_t)(k0 + i) * N + n0 + threadIdx.x];
    __syncthreads();
    for (int i = threadIdx.y; i < 32; i += 8)
        Wt[(size_t)(n0 + i) * K + k0 + threadIdx.x] = (_Float16)tile[threadIdx.x][i];
}

// ---------------- pooling / aggregation ----------------
__global__ void k_pool16(const _Float16* __restrict__ h16, const int* __restrict__ goff,
                         _Float16* __restrict__ pool) {
    int g = blockIdx.x;
    int c = threadIdx.x;
    int s = goff[g], e = goff[g + 1];
    float acc = 0.f;
    for (int r = s; r < e; ++r) acc += (float)h16[(size_t)r * HD + c];
    int cnt = e - s;
    pool[g * HD + c] = (_Float16)(acc / (float)(cnt > 0 ? cnt : 1));
}

// one wave per node; WAVE-UNIFORM loop bounds; 8 edges/iter
__global__ __launch_bounds__(256) void k_agg16(const _Float16* __restrict__ h16,
                                               const int* __restrict__ eoff,
                                               const int* __restrict__ csr,
                                               _Float16* __restrict__ out) {
    int node = blockIdx.x * 4 + (threadIdx.x >> 6);
    int lane = threadIdx.x & 63;
    int half = lane >> 5, l = lane & 31;
    f16x8 mine = *(const f16x8*)&h16[(size_t)node * HD + l * 8];
    float acc[8];
#pragma unroll
    for (int q = 0; q < 8; ++q) acc[q] = half ? 0.f : (float)mine[q];
    int s = eoff[node], e = eoff[node + 1];
    for (int base = s; base < e; base += 64) {
        int myi = base + lane;
        int vidx = (myi < e) ? csr[myi] : 0;
        int cnt = min(64, e - base);
        int jj = 0;
        for (; jj + 7 < cnt; jj += 8) {
            int s0 = __shfl(vidx, jj + half);
            int s1 = __shfl(vidx, jj + 2 + half);
            int s2 = __shfl(vidx, jj + 4 + half);
            int s3 = __shfl(vidx, jj + 6 + half);
            f16x8 v0 = *(const f16x8*)&h16[(size_t)s0 * HD + l * 8];
            f16x8 v1 = *(const f16x8*)&h16[(size_t)s1 * HD + l * 8];
            f16x8 v2 = *(const f16x8*)&h16[(size_t)s2 * HD + l * 8];
            f16x8 v3 = *(const f16x8*)&h16[(size_t)s3 * HD + l * 8];
#pragma unroll
            for (int q = 0; q < 8; ++q)
                acc[q] += ((float)v0[q] + (float)v1[q]) + ((float)v2[q] + (float)v3[q]);
        }
        for (; jj + 3 < cnt; jj += 4) {
            int s0 = __shfl(vidx, jj + half);
            int s1 = __shfl(vidx, jj + 2 + half);
            f16x8 v0 = *(const f16x8*)&h16[(size_t)s0 * HD + l * 8];
            f16x8 v1 = *(const f16x8*)&h16[(size_t)s1 * HD + l * 8];
#pragma unroll
            for (int q = 0; q < 8; ++q) acc[q] += (float)v0[q] + (float)v1[q];
        }
        for (; jj < cnt; jj += 2) {
            int i0 = jj + half;
            int s0 = __shfl(vidx, i0);
            if (i0 < cnt) {
                f16x8 v0 = *(const f16x8*)&h16[(size_t)s0 * HD + l * 8];
#pragma unroll
                for (int q = 0; q < 8; ++q) acc[q] += (float)v0[q];
            }
        }
    }
#pragma unroll
    for (int q = 0; q < 8; ++q) acc[q] += __shfl_xor(acc[q], 32);
    if (!half) {
        f16x8 o;
#pragma unroll
        for (int q = 0; q < 8; ++q) o[q] = (_Float16)acc[q];
        *(f16x8*)&out[(size_t)node * HD + l * 8] = o;
    }
}

// ---------------- batch norm finalize (also re-zeroes stat for next layer) ----
__global__ void k_bn_final(float* __restrict__ stat,
                           const float* __restrict__ gamma, const float* __restrict__ beta,
                           float* __restrict__ scale, float* __restrict__ shift) {
    int c = threadIdx.x;
    float mu = stat[c] * (1.0f / NN);
    float var = stat[HD + c] * (1.0f / NN) - mu * mu;
    float rs = rsqrtf(var + 1e-5f);
    float sc = rs * gamma[c];
    scale[c] = sc;
    shift[c] = beta[c] - mu * sc;
    stat[c] = 0.f;
    stat[HD + c] = 0.f;
}

// ======== fused back-to-back FFNN: register-B, barrier-free main loops ========
// C16 = gelu(A@W1+b1)@W2+b2 [+res].  A-tile resident in AC (32 KB, the ONLY
// LDS).  B-fragments load direct to a 3-deep register ring, 2 steps ahead, in
// fully-unrolled loops (compiler emits counted vmcnt per use).  Stage 1 has no
// barriers (AC read-only after prologue); two barriers at the C1 handoff.
// 32 KB LDS -> 4 blocks/CU (32 waves) for TLP through the memory phases.
template <bool ABN1, bool RES2, bool RESBN2, bool STATS2, int K1>
__global__ __launch_bounds__(512) void k_b2b(const _Float16* __restrict__ A16,
                                             const _Float16* __restrict__ G16,
                                             const _Float16* __restrict__ W1t,
                                             const float* __restrict__ b1,
                                             const _Float16* __restrict__ W2t,
                                             const float* __restrict__ b2,
                                             const _Float16* __restrict__ R16,
                                             const float* __restrict__ bnsc,
                                             const float* __restrict__ bnsh,
                                             const float* __restrict__ ovn,
                                             const int* __restrict__ batchv,
                                             float* __restrict__ stat,
                                             _Float16* __restrict__ C16,
                                             int M) {
    __shared__ _Float16 AC[32][64][8];      // 32 KB: A-tile (stage 1) then C1 (stage 2)
    constexpr int NT1 = K1 >> 5;
    const int t = threadIdx.x;
    const int w = t >> 6, lane = t & 63;
    const int m0 = blockIdx.x * 64;
    const int kb = lane >> 4, fr = lane & 15, rr = lane >> 4;

    // ---- prologue: A tile -> AC ----
    if constexpr (ABN1) {
        for (int c = t; c < K1 * 8; c += 512) {
            int kblk = c >> 6, row = c & 63;
            int b0 = batchv[min(m0 + row, M - 1)];
            const int c0 = kblk * 8;
            f16x8 g = *(const f16x8*)&G16[(size_t)(m0 + row) * HD + c0];
            f16x8 r0;
#pragma unroll
            for (int q = 0; q < 8; ++q)
                r0[q] = (_Float16)((float)g[q] * bnsc[c0 + q] + bnsh[c0 + q] +
                                   ovn[(size_t)b0 * HD + c0 + q]);
            *(f16x8*)&AC[kblk][row][0] = r0;
        }
    } else {
        for (int c = t; c < K1 * 8; c += 512) {
            int kblk = c >> 6, row = c & 63;
            gl_lds16(A16 + (size_t)(m0 + row) * K1 + kblk * 8, &AC[kblk][row][0]);
        }
    }
    __syncthreads();

    // ---- stage 1: barrier-free, register-B ring (depth 3, 2 ahead) ----
    f32x4 acc1[4][2];
#pragma unroll
    for (int mi = 0; mi < 4; ++mi)
#pragma unroll
        for (int ni = 0; ni < 2; ++ni) acc1[mi][ni] = (f32x4){0.f, 0.f, 0.f, 0.f};

    {
        f16x8 bf[3][2];
        auto loadB = [&](int s, f16x8* dst) {
#pragma unroll
            for (int ni = 0; ni < 2; ++ni)
                dst[ni] = *(const f16x8*)&W1t[(size_t)(w * 32 + ni * 16 + fr) * K1 + (s << 5) + kb * 8];
        };
        loadB(0, bf[0]);
        if (NT1 > 1) loadB(1, bf[1]);
#pragma unroll
        for (int s = 0; s < NT1; ++s) {
            if (s + 2 < NT1) loadB(s + 2, bf[(s + 2) % 3]);
            f16x8 af[4];
#pragma unroll
            for (int mi = 0; mi < 4; ++mi)
                af[mi] = *(const f16x8*)&AC[(s << 2) + kb][mi * 16 + fr][0];
#pragma unroll
            for (int mi = 0; mi < 4; ++mi)
#pragma unroll
                for (int ni = 0; ni < 2; ++ni)
                    acc1[mi][ni] = __builtin_amdgcn_mfma_f32_16x16x32_f16(af[mi], bf[s % 3][ni], acc1[mi][ni], 0, 0, 0);
        }
    }

    // ---- handoff: C1 -> AC (two barriers around the overwrite) ----
    __syncthreads();   // all stage-1 AC reads complete
#pragma unroll
    for (int mi = 0; mi < 4; ++mi) {
#pragma unroll
        for (int reg = 0; reg < 4; ++reg) {
            int ml = mi * 16 + rr * 4 + reg;
#pragma unroll
            for (int ni = 0; ni < 2; ++ni) {
                int n = w * 32 + ni * 16 + fr;
                float v = gelu_exact(acc1[mi][ni][reg] + b1[n]);
                AC[n >> 3][ml][n & 7] = (_Float16)v;
            }
        }
    }
    __syncthreads();   // C1 visible to all waves

    // ---- stage 2 (K2 = 256): barrier-free, register-B ring ----
    f32x4 acc2[4][2];
#pragma unroll
    for (int mi = 0; mi < 4; ++mi)
#pragma unroll
        for (int ni = 0; ni < 2; ++ni) acc2[mi][ni] = (f32x4){0.f, 0.f, 0.f, 0.f};

    {
        f16x8 bf[3][2];
        auto loadB = [&](int s, f16x8* dst) {
#pragma unroll
            for (int ni = 0; ni < 2; ++ni)
                dst[ni] = *(const f16x8*)&W2t[(size_t)(w * 32 + ni * 16 + fr) * HD + (s << 5) + kb * 8];
        };
        loadB(0, bf[0]);
        loadB(1, bf[1]);
#pragma unroll
        for (int s = 0; s < 8; ++s) {
            if (s + 2 < 8) loadB(s + 2, bf[(s + 2) % 3]);
            f16x8 af[4];
#pragma unroll
            for (int mi = 0; mi < 4; ++mi)
                af[mi] = *(const f16x8*)&AC[s * 4 + kb][mi * 16 + fr][0];
#pragma unroll
            for (int mi = 0; mi < 4; ++mi)
#pragma unroll
                for (int ni = 0; ni < 2; ++ni)
                    acc2[mi][ni] = __builtin_amdgcn_mfma_f32_16x16x32_f16(af[mi], bf[s % 3][ni], acc2[mi][ni], 0, 0, 0);
        }
    }

    // ---- epilogue 2 ----
    float cs[2] = {0.f, 0.f}, cq[2] = {0.f, 0.f};
#pragma unroll
    for (int mi = 0; mi < 4; ++mi) {
#pragma unroll
        for (int reg = 0; reg < 4; ++reg) {
            int m = m0 + mi * 16 + rr * 4 + reg;
            if (m < M) {
#pragma unroll
                for (int ni = 0; ni < 2; ++ni) {
                    int n = w * 32 + ni * 16 + fr;
                    float v = acc2[mi][ni][reg] + b2[n];
                    if (RES2) v += (float)R16[(size_t)m * HD + n];
                    if (RESBN2) v += (float)R16[(size_t)m * HD + n] * bnsc[n] + bnsh[n];
                    _Float16 vh = (_Float16)v;
                    C16[(size_t)m * HD + n] = vh;
                    if (STATS2) { float vr = (float)vh; cs[ni] += vr; cq[ni] += vr * vr; }
                }
            }
        }
    }
    if constexpr (STATS2) {
#pragma unroll
        for (int ni = 0; ni < 2; ++ni) {
            cs[ni] += __shfl_xor(cs[ni], 16); cs[ni] += __shfl_xor(cs[ni], 32);
            cq[ni] += __shfl_xor(cq[ni], 16); cq[ni] += __shfl_xor(cq[ni], 32);
        }
        if (lane < 16) {
#pragma unroll
            for (int ni = 0; ni < 2; ++ni) {
                int n = w * 32 + ni * 16 + lane;
                atomicAdd(&stat[n], cs[ni]);
                atomicAdd(&stat[HD + n], cq[ni]);
            }
        }
    }
}

// ---------------- MFMA fp16 GEMM (64x128 tile) — VN/post path ----------------
template <bool GELU, bool BIAS2, bool O32, bool O16>
__global__ __launch_bounds__(256) void k_mgemm(const _Float16* __restrict__ A,
                                               const _Float16* __restrict__ Wt,
                                               const float* __restrict__ bias,
                                               const float* __restrict__ bias2,
                                               float* __restrict__ C32,
                                               _Float16* __restrict__ C16,
                                               int M, int N, int K) {
    __shared__ _Float16 As[2][4][64][8];
    __shared__ _Float16 Bs[2][4][128][8];
    const int t = threadIdx.x;
    const int w = t >> 6, lane = t & 63;
    const int m0 = blockIdx.y * 64, n0 = blockIdx.x * 128;
    const int kb = lane >> 4, fr = lane & 15;

    f32x4 acc[4][2];
#pragma unroll
    for (int mi = 0; mi < 4; ++mi)
#pragma unroll
        for (int ni = 0; ni < 2; ++ni) acc[mi][ni] = (f32x4){0.f, 0.f, 0.f, 0.f};

    const _Float16* gA0 = A + (size_t)(m0 + lane) * K + w * 8;
    const _Float16* gB0 = Wt + (size_t)(n0 + lane) * K + w * 8;
    const _Float16* gB1 = Wt + (size_t)(n0 + 64 + lane) * K + w * 8;

    auto stage = [&](int buf, int k0) {
        gl_lds16(gB0 + k0, &Bs[buf][w][0][0]);
        gl_lds16(gB1 + k0, &Bs[buf][w][64][0]);
        gl_lds16(gA0 + k0, &As[buf][w][0][0]);
    };

    const int nt = K >> 5;
    stage(0, 0);
    __syncthreads();
    for (int tt = 0; tt < nt; ++tt) {
        const int cur = tt & 1;
        if (tt + 1 < nt) stage(cur ^ 1, (tt + 1) << 5);
        f16x8 af[4], bf[2];
#pragma unroll
        for (int mi = 0; mi < 4; ++mi)
            af[mi] = *(const f16x8*)&As[cur][kb][mi * 16 + fr][0];
#pragma unroll
        for (int ni = 0; ni < 2; ++ni)
            bf[ni] = *(const f16x8*)&Bs[cur][kb][w * 32 + ni * 16 + fr][0];
#pragma unroll
        for (int mi = 0; mi < 4; ++mi)
#pragma unroll
            for (int ni = 0; ni < 2; ++ni)
                acc[mi][ni] = __builtin_amdgcn_mfma_f32_16x16x32_f16(af[mi], bf[ni], acc[mi][ni], 0, 0, 0);
        __syncthreads();
    }

    const int rr = lane >> 4;
#pragma unroll
    for (int mi = 0; mi < 4; ++mi) {
#pragma unroll
        for (int reg = 0; reg < 4; ++reg) {
            int m = m0 + mi * 16 + rr * 4 + reg;
            if (m < M) {
#pragma unroll
                for (int ni = 0; ni < 2; ++ni) {
                    int n = n0 + w * 32 + ni * 16 + fr;
                    float v = acc[mi][ni][reg] + bias[n];
                    if (BIAS2) v += bias2[n];
                    if (GELU) v = gelu_exact(v);
                    if (O32) C32[(size_t)m * N + n] = v;
                    if (O16) C16[(size_t)m * N + n] = (_Float16)v;
                }
            }
        }
    }
}

static inline void mg_gelu(hipStream_t st, const _Float16* A, const _Float16* Wt,
                           const float* bias, _Float16* C16, int M, int N, int K) {
    dim3 g(N / 128, (M + 63) / 64), b(256);
    k_mgemm<true, false, false, true><<<g, b, 0, st>>>(A, Wt, bias, nullptr, nullptr, C16, M, N, K);
}
static inline void mg_bias2_16(hipStream_t st, const _Float16* A, const _Float16* Wt,
                               const float* bias, const float* bias2, _Float16* C16,
                               int M, int N, int K) {
    dim3 g(N / 128, (M + 63) / 64), b(256);
    k_mgemm<false, true, false, true><<<g, b, 0, st>>>(A, Wt, bias, bias2, nullptr, C16, M, N, K);
}
static inline void mg_f32only(hipStream_t st, const _Float16* A, const _Float16* Wt,
                              const float* bias, float* C32, int M, int N, int K) {
    dim3 g(N / 128, (M + 63) / 64), b(256);
    k_mgemm<false, false, true, false><<<g, b, 0, st>>>(A, Wt, bias, nullptr, C32, nullptr, M, N, K);
}

extern "C" void kernel_launch(void* const* d_in, const int* in_sizes, int n_in,
                              void* d_out, int out_size, void* d_ws, size_t ws_size,
                              hipStream_t stream) {
    const float* x       = (const float*)d_in[0];
    const int*   ei      = (const int*)d_in[1];
    const int*   batch   = (const int*)d_in[2];
    const float* pre_W1  = (const float*)d_in[3];
    const float* pre_b1  = (const float*)d_in[4];
    const float* pre_W2  = (const float*)d_in[5];
    const float* pre_b2  = (const float*)d_in[6];
    const float* gin_W1  = (const float*)d_in[7];
    const float* gin_b1  = (const float*)d_in[8];
    const float* gin_W2  = (const float*)d_in[9];
    const float* gin_b2  = (const float*)d_in[10];
    const float* ffn_W1  = (const float*)d_in[11];
    const float* ffn_b1  = (const float*)d_in[12];
    const float* ffn_W2  = (const float*)d_in[13];
    const float* ffn_b2  = (const float*)d_in[14];
    const float* upd_W1  = (const float*)d_in[15];
    const float* upd_b1  = (const float*)d_in[16];
    const float* upd_W2  = (const float*)d_in[17];
    const float* upd_b2  = (const float*)d_in[18];
    const float* prop_W1 = (const float*)d_in[19];
    const float* prop_b1 = (const float*)d_in[20];
    const float* prop_W2 = (const float*)d_in[21];
    const float* prop_b2 = (const float*)d_in[22];
    const float* bn_gamma= (const float*)d_in[23];
    const float* bn_beta = (const float*)d_in[24];
    const float* vn      = (const float*)d_in[25];
    const float* post_W1 = (const float*)d_in[26];
    const float* post_b1 = (const float*)d_in[27];
    const float* post_W2 = (const float*)d_in[28];
    const float* post_b2 = (const float*)d_in[29];
    float* out = (float*)d_out;

    const int* e_src = ei;
    const int* e_dst = ei + NE;

    // ---------- workspace layout ----------
    char* p = (char*)d_ws;
    auto alloc = [&](size_t bytes) -> char* {
        char* r = p;
        p += (bytes + 255) & ~(size_t)255;
        return r;
    };
    _Float16* h16    = (_Float16*)alloc((size_t)NNP * HD * 2);   // fp16 backbone
    _Float16* g16    = (_Float16*)alloc((size_t)NNP * HD * 2);   // gin output (pre-BN)
    _Float16* t16a   = (_Float16*)alloc((size_t)NNP * HD * 2);   // agg out; aliases x16
    _Float16* pool16 = (_Float16*)alloc((size_t)NG * HD * 2);
    _Float16* u16    = (_Float16*)alloc((size_t)NG * HD * 2);
    _Float16* vb16   = (_Float16*)alloc((size_t)NG * H4 * 2);
    _Float16* p16    = (_Float16*)alloc((size_t)NG * HD * 2);
    float*    outvn32= (float*)alloc((size_t)NG * HD * 4);
    float*    bnstat = (float*)alloc(2 * HD * 4);
    float*    bnscale= (float*)alloc(HD * 4);
    float*    bnshift= (float*)alloc(HD * 4);
    _Float16* preW1t = (_Float16*)alloc((size_t)HD * DIN * 2);
    _Float16* preW2t = (_Float16*)alloc((size_t)HD * HD * 2);
    _Float16* ginW1t = (_Float16*)alloc((size_t)NL * HD * HD * 2);
    _Float16* ginW2t = (_Float16*)alloc((size_t)NL * HD * HD * 2);
    _Float16* ffnW1t = (_Float16*)alloc((size_t)NL * HD * HD * 2);
    _Float16* ffnW2t = (_Float16*)alloc((size_t)NL * HD * HD * 2);
    _Float16* updW1t = (_Float16*)alloc((size_t)NL * HD * HD * 2);
    _Float16* updW2t = (_Float16*)alloc((size_t)NL * HD * H4 * 2);
    _Float16* propW1t= (_Float16*)alloc((size_t)NL * H4 * HD * 2);
    _Float16* propW2t= (_Float16*)alloc((size_t)NL * HD * HD * 2);
    _Float16* postW1t= (_Float16*)alloc((size_t)HD * HD * 2);
    _Float16* postW2t= (_Float16*)alloc((size_t)DOUT * HD * 2);
    int* gcount = (int*)alloc(NG * 4);
    int* goff   = (int*)alloc((NG + 1) * 4);
    int* deg    = (int*)alloc(NN * 4);
    int* eoff   = (int*)alloc((NN + 1) * 4);
    int* cursor = (int*)alloc(NN * 4);
    int* csr    = (int*)alloc((size_t)NE * 4);
    int* bsum   = (int*)alloc(1024 * 4);
    int* bexcl  = (int*)alloc(1024 * 4);
    _Float16* x16 = t16a;   // alias: consumed by pre-pair before t16a is first written

    // ---------- zero counters + bnstat ----------
    {
        size_t span = (size_t)((char*)(cursor + NN) - (char*)gcount);
        hipMemsetAsync(gcount, 0, span, stream);
        hipMemsetAsync(bnstat, 0, 2 * HD * 4, stream);
    }
    hipLaunchKernelGGL(k_hist, dim3((NN + 255) / 256), dim3(256), 0, stream, batch, gcount, NN);
    hipLaunchKernelGGL(k_hist, dim3((NE + 255) / 256), dim3(256), 0, stream, e_dst, deg, NE);
    hipLaunchKernelGGL(k_scan_small, dim3(1), dim3(1024), 0, stream, gcount, goff, NG);
    {
        int nbN = (NN + 255) / 256;
        hipLaunchKernelGGL(k_scan_part, dim3(nbN), dim3(256), 0, stream, deg, bsum, NN);
        hipLaunchKernelGGL(k_scan_mid, dim3(1), dim3(1024), 0, stream, bsum, bexcl, nbN, eoff, NN);
        hipLaunchKernelGGL(k_scan_out, dim3(nbN), dim3(256), 0, stream, deg, bexcl, eoff, NN);
    }
    hipLaunchKernelGGL(k_fill_csr, dim3((NE + 255) / 256), dim3(256), 0, stream, e_src, e_dst, eoff, cursor, csr, NE);

    // ---------- batched weight transpose (one launch) ----------
    {
        WtJobs j;
        int idx = 0, tiles = 0;
        auto add = [&](const float* s, _Float16* d, int K, int N) {
            j.src[idx] = s; j.dst[idx] = d;
            j.K32[idx] = (short)(K / 32); j.N32[idx] = (short)(N / 32);
            j.pre[idx] = (short)tiles;
            tiles += (K / 32) * (N / 32);
            ++idx;
        };
        add(pre_W1, preW1t, DIN, HD);
        add(pre_W2, preW2t, HD, HD);
        add(post_W1, postW1t, HD, HD);
        add(post_W2, postW2t, HD, DOUT);
        for (int i = 0; i < NL; ++i) {
            add(gin_W1 + (size_t)i * HD * HD, ginW1t + (size_t)i * HD * HD, HD, HD);
            add(gin_W2 + (size_t)i * HD * HD, ginW2t + (size_t)i * HD * HD, HD, HD);
            add(ffn_W1 + (size_t)i * HD * HD, ffnW1t + (size_t)i * HD * HD, HD, HD);
            add(ffn_W2 + (size_t)i * HD * HD, ffnW2t + (size_t)i * HD * HD, HD, HD);
            add(upd_W1 + (size_t)i * HD * HD, updW1t + (size_t)i * HD * HD, HD, HD);
            add(upd_W2 + (size_t)i * HD * H4, updW2t + (size_t)i * HD * H4, HD, H4);
            add(prop_W1 + (size_t)i * H4 * HD, propW1t + (size_t)i * H4 * HD, H4, HD);
            add(prop_W2 + (size_t)i * HD * HD, propW2t + (size_t)i * HD * HD, HD, HD);
        }
        j.pre[idx] = (short)tiles;
        hipLaunchKernelGGL(k_wtb, dim3(tiles), dim3(32, 8), 0, stream, j);
    }

    // x -> fp16
    int n4 = NN * DIN / 4;
    hipLaunchKernelGGL(k_cvt16, dim3((n4 + 255) / 256), dim3(256), 0, stream, x, x16, n4);

    const int nb2b = NNP / 64;

    // ---------- pre-FFNN (fused pair): h16 = gelu(x@W1+b1)@W2+b2 ----------
    hipLaunchKernelGGL((k_b2b<false, false, false, false, DIN>), dim3(nb2b), dim3(512), 0, stream,
                       x16, nullptr, preW1t, pre_b1, preW2t, pre_b2,
                       nullptr, nullptr, nullptr, nullptr, nullptr, nullptr,
                       h16, NN);

    for (int i = 0; i < NL; ++i) {
        const _Float16* uW1 = updW1t + (size_t)i * HD * HD;
        const _Float16* uW2 = updW2t + (size_t)i * HD * H4;
        const _Float16* pW1 = propW1t + (size_t)i * H4 * HD;
        const _Float16* pW2 = propW2t + (size_t)i * HD * HD;

        // virtual-node path (M = NG = 512) via MFMA GEMMs
        hipLaunchKernelGGL(k_pool16, dim3(NG), dim3(HD), 0, stream, h16, goff, pool16);
        mg_gelu(stream, pool16, uW1, upd_b1 + (size_t)i * HD, u16, NG, HD, HD);
        mg_bias2_16(stream, u16, uW2, upd_b2 + (size_t)i * H4, vn, vb16, NG, H4, HD);
        mg_gelu(stream, vb16, pW1, prop_b1 + (size_t)i * HD, p16, NG, HD, H4);
        mg_f32only(stream, p16, pW2, prop_b2 + (size_t)i * HD, outvn32, NG, HD, HD);

        // GIN: t16a = agg(h16); g16 = gelu(t16a@gW1+b1)@gW2+b2 + h16 (+BN stats)
        hipLaunchKernelGGL(k_agg16, dim3(NN / 4), dim3(256), 0, stream, h16, eoff, csr, t16a);
        hipLaunchKernelGGL((k_b2b<false, true, false, true, HD>), dim3(nb2b), dim3(512), 0, stream,
                           t16a, nullptr,
                           ginW1t + (size_t)i * HD * HD, gin_b1 + (size_t)i * HD,
                           ginW2t + (size_t)i * HD * HD, gin_b2 + (size_t)i * HD,
                           h16, nullptr, nullptr, nullptr, nullptr, bnstat,
                           g16, NN);

        // BN finalize (re-zeroes stat)
        hipLaunchKernelGGL(k_bn_final, dim3(1), dim3(HD), 0, stream, bnstat,
                           bn_gamma + (size_t)i * HD, bn_beta + (size_t)i * HD, bnscale, bnshift);

        // FFN fused pair: h16 = gelu((bn(g16)+ovn)@fW1+b1)@fW2+b2 + bn(g16)
        hipLaunchKernelGGL((k_b2b<true, false, true, false, HD>), dim3(nb2b), dim3(512), 0, stream,
                           nullptr, g16,
                           ffnW1t + (size_t)i * HD * HD, ffn_b1 + (size_t)i * HD,
                           ffnW2t + (size_t)i * HD * HD, ffn_b2 + (size_t)i * HD,
                           g16, bnscale, bnshift, outvn32, batch, nullptr,
                           h16, NN);
    }

    // ---------- post ----------
    hipLaunchKernelGGL(k_pool16, dim3(NG), dim3(HD), 0, stream, h16, goff, pool16);
    mg_gelu(stream, pool16, postW1t, post_b1, u16, NG, HD, HD);
    mg_f32only(stream, u16, postW2t, post_b2, out, NG, DOUT, HD);
}

// Round 18
// 1396.689 us; speedup vs baseline: 1.3216x; 1.1738x over previous
//
#include <hip/hip_runtime.h>
#include <hip/hip_bf16.h>
#include <math.h>

#define NN 50000
#define NNP 50048          // padded to multiple of 128
#define NE 800000
#define NG 512
#define DIN 128
#define HD 256
#define DOUT 128
#define NL 5
#define H4 1024
#define NSL 8              // BN stat slices (atomic de-contention)

typedef _Float16 f16x8 __attribute__((ext_vector_type(8)));
typedef _Float16 f16x4 __attribute__((ext_vector_type(4)));
typedef float f32x4 __attribute__((ext_vector_type(4)));

// exact-GELU via A&S 7.1.26 erf approximation (|eps| <= 1.5e-7)
__device__ __forceinline__ float gelu_exact(float x) {
    float ax = fabsf(x) * 0.70710678118654752f;
    float t = __builtin_amdgcn_rcpf(1.0f + 0.3275911f * ax);
    float poly = t * (0.254829592f + t * (-0.284496736f + t * (1.421413741f +
                 t * (-1.453152027f + t * 1.061405429f))));
    float erfv = 1.0f - poly * __expf(-ax * ax);
    erfv = copysignf(erfv, x);
    return 0.5f * x * (1.0f + erfv);
}

__device__ __forceinline__ void gl_lds16(const _Float16* g, _Float16* l) {
    __builtin_amdgcn_global_load_lds(
        (const __attribute__((address_space(1))) unsigned int*)g,
        (__attribute__((address_space(3))) unsigned int*)l, 16, 0, 0);
}

// ---------------- graph meta ----------------
__global__ void k_hist(const int* __restrict__ idx, int* __restrict__ cnt, int n) {
    int i = blockIdx.x * blockDim.x + threadIdx.x;
    if (i < n) atomicAdd(&cnt[idx[i]], 1);
}

__global__ void k_scan_small(const int* __restrict__ in, int* __restrict__ out, int n) {
    __shared__ int buf[1024];
    int t = threadIdx.x;
    int v = (t < n) ? in[t] : 0;
    buf[t] = v;
    __syncthreads();
    for (int off = 1; off < 1024; off <<= 1) {
        int x = (t >= off) ? buf[t - off] : 0;
        __syncthreads();
        buf[t] += x;
        __syncthreads();
    }
    if (t < n) out[t] = buf[t] - v;
    if (t == 1023) out[n] = buf[1023];
}

__global__ void k_scan_part(const int* __restrict__ in, int* __restrict__ bsum, int n) {
    __shared__ int buf[256];
    int i = blockIdx.x * 256 + threadIdx.x;
    buf[threadIdx.x] = (i < n) ? in[i] : 0;
    __syncthreads();
    for (int off = 128; off > 0; off >>= 1) {
        if (threadIdx.x < off) buf[threadIdx.x] += buf[threadIdx.x + off];
        __syncthreads();
    }
    if (threadIdx.x == 0) bsum[blockIdx.x] = buf[0];
}

__global__ void k_scan_mid(const int* __restrict__ bsum, int* __restrict__ bexcl, int nb,
                           int* __restrict__ out, int n) {
    __shared__ int buf[1024];
    int t = threadIdx.x;
    int v = (t < nb) ? bsum[t] : 0;
    buf[t] = v;
    __syncthreads();
    for (int off = 1; off < 1024; off <<= 1) {
        int x = (t >= off) ? buf[t - off] : 0;
        __syncthreads();
        buf[t] += x;
        __syncthreads();
    }
    if (t < nb) bexcl[t] = buf[t] - v;
    if (t == 1023) out[n] = buf[1023];
}

__global__ void k_scan_out(const int* __restrict__ in, const int* __restrict__ bexcl,
                           int* __restrict__ out, int n) {
    __shared__ int buf[256];
    int i = blockIdx.x * 256 + threadIdx.x;
    int t = threadIdx.x;
    int v = (i < n) ? in[i] : 0;
    buf[t] = v;
    __syncthreads();
    for (int off = 1; off < 256; off <<= 1) {
        int x = (t >= off) ? buf[t - off] : 0;
        __syncthreads();
        buf[t] += x;
        __syncthreads();
    }
    if (i < n) out[i] = bexcl[blockIdx.x] + buf[t] - v;
}

__global__ void k_fill_csr(const int* __restrict__ src, const int* __restrict__ dst,
                           const int* __restrict__ eoff, int* __restrict__ cursor,
                           int* __restrict__ csr, int n) {
    int e = blockIdx.x * blockDim.x + threadIdx.x;
    if (e < n) {
        int d = dst[e];
        int p = atomicAdd(&cursor[d], 1);
        csr[eoff[d] + p] = src[e];
    }
}

// ---------------- converts ----------------
__global__ void k_cvt16(const float* __restrict__ in, _Float16* __restrict__ out, int n4) {
    int i = blockIdx.x * blockDim.x + threadIdx.x;
    if (i < n4) {
        float4 v = *(const float4*)&in[i * 4];
        f16x4 o = { (_Float16)v.x, (_Float16)v.y, (_Float16)v.z, (_Float16)v.w };
        *(f16x4*)&out[i * 4] = o;
    }
}

// batched transpose + convert: one launch for all weight matrices
#define NWTJOBS 44
struct WtJobs {
    const float* src[NWTJOBS];
    _Float16* dst[NWTJOBS];
    short K32[NWTJOBS];
    short N32[NWTJOBS];
    short pre[NWTJOBS + 1];
};
__global__ void k_wtb(WtJobs j) {
    int bid = blockIdx.x;
    int lo = 0;
    while (j.pre[lo + 1] <= bid) ++lo;
    int tl = bid - j.pre[lo];
    int nx = j.N32[lo];
    int n0 = (tl % nx) * 32, k0 = (tl / nx) * 32;
    int K = j.K32[lo] * 32, N = nx * 32;
    const float* W = j.src[lo];
    _Float16* Wt = j.dst[lo];
    __shared__ float tile[32][33];
    for (int i = threadIdx.y; i < 32; i += 8)
        tile[i][threadIdx.x] = W[(size_t)(k0 + i) * N + n0 + threadIdx.x];
    __syncthreads();
    for (int i = threadIdx.y; i < 32; i += 8)
        Wt[(size_t)(n0 + i) * K + k0 + threadIdx.x] = (_Float16)tile[threadIdx.x][i];
}

// ---------------- pooling / aggregation ----------------
__global__ void k_pool16(const _Float16* __restrict__ h16, const int* __restrict__ goff,
                         _Float16* __restrict__ pool) {
    int g = blockIdx.x;
    int c = threadIdx.x;
    int s = goff[g], e = goff[g + 1];
    float a0 = 0.f, a1 = 0.f, a2 = 0.f, a3 = 0.f;
    int r = s;
    for (; r + 3 < e; r += 4) {
        a0 += (float)h16[(size_t)r * HD + c];
        a1 += (float)h16[(size_t)(r + 1) * HD + c];
        a2 += (float)h16[(size_t)(r + 2) * HD + c];
        a3 += (float)h16[(size_t)(r + 3) * HD + c];
    }
    for (; r < e; ++r) a0 += (float)h16[(size_t)r * HD + c];
    float acc = (a0 + a1) + (a2 + a3);
    int cnt = e - s;
    pool[g * HD + c] = (_Float16)(acc / (float)(cnt > 0 ? cnt : 1));
}

// one wave per node; WAVE-UNIFORM loop bounds; 8 edges/iter
__global__ __launch_bounds__(256) void k_agg16(const _Float16* __restrict__ h16,
                                               const int* __restrict__ eoff,
                                               const int* __restrict__ csr,
                                               _Float16* __restrict__ out) {
    int node = blockIdx.x * 4 + (threadIdx.x >> 6);
    int lane = threadIdx.x & 63;
    int half = lane >> 5, l = lane & 31;
    f16x8 mine = *(const f16x8*)&h16[(size_t)node * HD + l * 8];
    float acc[8];
#pragma unroll
    for (int q = 0; q < 8; ++q) acc[q] = half ? 0.f : (float)mine[q];
    int s = eoff[node], e = eoff[node + 1];
    for (int base = s; base < e; base += 64) {
        int myi = base + lane;
        int vidx = (myi < e) ? csr[myi] : 0;
        int cnt = min(64, e - base);
        int jj = 0;
        for (; jj + 7 < cnt; jj += 8) {
            int s0 = __shfl(vidx, jj + half);
            int s1 = __shfl(vidx, jj + 2 + half);
            int s2 = __shfl(vidx, jj + 4 + half);
            int s3 = __shfl(vidx, jj + 6 + half);
            f16x8 v0 = *(const f16x8*)&h16[(size_t)s0 * HD + l * 8];
            f16x8 v1 = *(const f16x8*)&h16[(size_t)s1 * HD + l * 8];
            f16x8 v2 = *(const f16x8*)&h16[(size_t)s2 * HD + l * 8];
            f16x8 v3 = *(const f16x8*)&h16[(size_t)s3 * HD + l * 8];
#pragma unroll
            for (int q = 0; q < 8; ++q)
                acc[q] += ((float)v0[q] + (float)v1[q]) + ((float)v2[q] + (float)v3[q]);
        }
        for (; jj + 3 < cnt; jj += 4) {
            int s0 = __shfl(vidx, jj + half);
            int s1 = __shfl(vidx, jj + 2 + half);
            f16x8 v0 = *(const f16x8*)&h16[(size_t)s0 * HD + l * 8];
            f16x8 v1 = *(const f16x8*)&h16[(size_t)s1 * HD + l * 8];
#pragma unroll
            for (int q = 0; q < 8; ++q) acc[q] += (float)v0[q] + (float)v1[q];
        }
        for (; jj < cnt; jj += 2) {
            int i0 = jj + half;
            int s0 = __shfl(vidx, i0);
            if (i0 < cnt) {
                f16x8 v0 = *(const f16x8*)&h16[(size_t)s0 * HD + l * 8];
#pragma unroll
                for (int q = 0; q < 8; ++q) acc[q] += (float)v0[q];
            }
        }
    }
#pragma unroll
    for (int q = 0; q < 8; ++q) acc[q] += __shfl_xor(acc[q], 32);
    if (!half) {
        f16x8 o;
#pragma unroll
        for (int q = 0; q < 8; ++q) o[q] = (_Float16)acc[q];
        *(f16x8*)&out[(size_t)node * HD + l * 8] = o;
    }
}

// ---------------- batch norm finalize: sum NSL slices, re-zero all ----------
__global__ void k_bn_final(float* __restrict__ stat,
                           const float* __restrict__ gamma, const float* __restrict__ beta,
                           float* __restrict__ scale, float* __restrict__ shift) {
    int c = threadIdx.x;
    float s = 0.f, q = 0.f;
#pragma unroll
    for (int k = 0; k < NSL; ++k) {
        s += stat[k * 2 * HD + c];
        q += stat[k * 2 * HD + HD + c];
        stat[k * 2 * HD + c] = 0.f;
        stat[k * 2 * HD + HD + c] = 0.f;
    }
    float mu = s * (1.0f / NN);
    float var = q * (1.0f / NN) - mu * mu;
    float rs = rsqrtf(var + 1e-5f);
    float sc = rs * gamma[c];
    scale[c] = sc;
    shift[c] = beta[c] - mu * sc;
}

// ======== fused back-to-back FFNN: register-B, barrier-free main loops ========
template <bool ABN1, bool RES2, bool RESBN2, bool STATS2, int K1>
__global__ __launch_bounds__(512) void k_b2b(const _Float16* __restrict__ A16,
                                             const _Float16* __restrict__ G16,
                                             const _Float16* __restrict__ W1t,
                                             const float* __restrict__ b1,
                                             const _Float16* __restrict__ W2t,
                                             const float* __restrict__ b2,
                                             const _Float16* __restrict__ R16,
                                             const float* __restrict__ bnsc,
                                             const float* __restrict__ bnsh,
                                             const float* __restrict__ ovn,
                                             const int* __restrict__ batchv,
                                             float* __restrict__ stat,
                                             _Float16* __restrict__ C16,
                                             int M) {
    __shared__ _Float16 AC[32][64][8];      // 32 KB: A-tile (stage 1) then C1 (stage 2)
    constexpr int NT1 = K1 >> 5;
    const int t = threadIdx.x;
    const int w = t >> 6, lane = t & 63;
    const int m0 = blockIdx.x * 64;
    const int kb = lane >> 4, fr = lane & 15, rr = lane >> 4;

    // ---- prologue: A tile -> AC ----
    if constexpr (ABN1) {
        for (int c = t; c < K1 * 8; c += 512) {
            int kblk = c >> 6, row = c & 63;
            int b0 = batchv[min(m0 + row, M - 1)];
            const int c0 = kblk * 8;
            f16x8 g = *(const f16x8*)&G16[(size_t)(m0 + row) * HD + c0];
            f16x8 r0;
#pragma unroll
            for (int q = 0; q < 8; ++q)
                r0[q] = (_Float16)((float)g[q] * bnsc[c0 + q] + bnsh[c0 + q] +
                                   ovn[(size_t)b0 * HD + c0 + q]);
            *(f16x8*)&AC[kblk][row][0] = r0;
        }
    } else {
        for (int c = t; c < K1 * 8; c += 512) {
            int kblk = c >> 6, row = c & 63;
            gl_lds16(A16 + (size_t)(m0 + row) * K1 + kblk * 8, &AC[kblk][row][0]);
        }
    }
    __syncthreads();

    // ---- stage 1: barrier-free, register-B ring (depth 3, 2 ahead) ----
    f32x4 acc1[4][2];
#pragma unroll
    for (int mi = 0; mi < 4; ++mi)
#pragma unroll
        for (int ni = 0; ni < 2; ++ni) acc1[mi][ni] = (f32x4){0.f, 0.f, 0.f, 0.f};

    {
        f16x8 bf[3][2];
        auto loadB = [&](int s, f16x8* dst) {
#pragma unroll
            for (int ni = 0; ni < 2; ++ni)
                dst[ni] = *(const f16x8*)&W1t[(size_t)(w * 32 + ni * 16 + fr) * K1 + (s << 5) + kb * 8];
        };
        loadB(0, bf[0]);
        if (NT1 > 1) loadB(1, bf[1]);
#pragma unroll
        for (int s = 0; s < NT1; ++s) {
            if (s + 2 < NT1) loadB(s + 2, bf[(s + 2) % 3]);
            f16x8 af[4];
#pragma unroll
            for (int mi = 0; mi < 4; ++mi)
                af[mi] = *(const f16x8*)&AC[(s << 2) + kb][mi * 16 + fr][0];
#pragma unroll
            for (int mi = 0; mi < 4; ++mi)
#pragma unroll
                for (int ni = 0; ni < 2; ++ni)
                    acc1[mi][ni] = __builtin_amdgcn_mfma_f32_16x16x32_f16(af[mi], bf[s % 3][ni], acc1[mi][ni], 0, 0, 0);
        }
    }

    // ---- handoff: C1 -> AC (two barriers around the overwrite) ----
    __syncthreads();
#pragma unroll
    for (int mi = 0; mi < 4; ++mi) {
#pragma unroll
        for (int reg = 0; reg < 4; ++reg) {
            int ml = mi * 16 + rr * 4 + reg;
#pragma unroll
            for (int ni = 0; ni < 2; ++ni) {
                int n = w * 32 + ni * 16 + fr;
                float v = gelu_exact(acc1[mi][ni][reg] + b1[n]);
                AC[n >> 3][ml][n & 7] = (_Float16)v;
            }
        }
    }
    __syncthreads();

    // ---- stage 2 (K2 = 256): barrier-free, register-B ring ----
    f32x4 acc2[4][2];
#pragma unroll
    for (int mi = 0; mi < 4; ++mi)
#pragma unroll
        for (int ni = 0; ni < 2; ++ni) acc2[mi][ni] = (f32x4){0.f, 0.f, 0.f, 0.f};

    {
        f16x8 bf[3][2];
        auto loadB = [&](int s, f16x8* dst) {
#pragma unroll
            for (int ni = 0; ni < 2; ++ni)
                dst[ni] = *(const f16x8*)&W2t[(size_t)(w * 32 + ni * 16 + fr) * HD + (s << 5) + kb * 8];
        };
        loadB(0, bf[0]);
        loadB(1, bf[1]);
#pragma unroll
        for (int s = 0; s < 8; ++s) {
            if (s + 2 < 8) loadB(s + 2, bf[(s + 2) % 3]);
            f16x8 af[4];
#pragma unroll
            for (int mi = 0; mi < 4; ++mi)
                af[mi] = *(const f16x8*)&AC[s * 4 + kb][mi * 16 + fr][0];
#pragma unroll
            for (int mi = 0; mi < 4; ++mi)
#pragma unroll
                for (int ni = 0; ni < 2; ++ni)
                    acc2[mi][ni] = __builtin_amdgcn_mfma_f32_16x16x32_f16(af[mi], bf[s % 3][ni], acc2[mi][ni], 0, 0, 0);
        }
    }

    // ---- epilogue 2 ----
    float cs[2] = {0.f, 0.f}, cq[2] = {0.f, 0.f};
#pragma unroll
    for (int mi = 0; mi < 4; ++mi) {
#pragma unroll
        for (int reg = 0; reg < 4; ++reg) {
            int m = m0 + mi * 16 + rr * 4 + reg;
            if (m < M) {
#pragma unroll
                for (int ni = 0; ni < 2; ++ni) {
                    int n = w * 32 + ni * 16 + fr;
                    float v = acc2[mi][ni][reg] + b2[n];
                    if (RES2) v += (float)R16[(size_t)m * HD + n];
                    if (RESBN2) v += (float)R16[(size_t)m * HD + n] * bnsc[n] + bnsh[n];
                    _Float16 vh = (_Float16)v;
                    C16[(size_t)m * HD + n] = vh;
                    if (STATS2) { float vr = (float)vh; cs[ni] += vr; cq[ni] += vr * vr; }
                }
            }
        }
    }
    if constexpr (STATS2) {
        float* slice = stat + (size_t)(blockIdx.x & (NSL - 1)) * 2 * HD;
#pragma unroll
        for (int ni = 0; ni < 2; ++ni) {
            cs[ni] += __shfl_xor(cs[ni], 16); cs[ni] += __shfl_xor(cs[ni], 32);
            cq[ni] += __shfl_xor(cq[ni], 16); cq[ni] += __shfl_xor(cq[ni], 32);
        }
        if (lane < 16) {
#pragma unroll
            for (int ni = 0; ni < 2; ++ni) {
                int n = w * 32 + ni * 16 + lane;
                atomicAdd(&slice[n], cs[ni]);
                atomicAdd(&slice[HD + n], cq[ni]);
            }
        }
    }
}

// ---------------- MFMA fp16 GEMM (64x128 tile) — VN/post path ----------------
template <bool GELU, bool BIAS2, bool O32, bool O16>
__global__ __launch_bounds__(256) void k_mgemm(const _Float16* __restrict__ A,
                                               const _Float16* __restrict__ Wt,
                                               const float* __restrict__ bias,
                                               const float* __restrict__ bias2,
                                               float* __restrict__ C32,
                                               _Float16* __restrict__ C16,
                                               int M, int N, int K) {
    __shared__ _Float16 As[2][4][64][8];
    __shared__ _Float16 Bs[2][4][128][8];
    const int t = threadIdx.x;
    const int w = t >> 6, lane = t & 63;
    const int m0 = blockIdx.y * 64, n0 = blockIdx.x * 128;
    const int kb = lane >> 4, fr = lane & 15;

    f32x4 acc[4][2];
#pragma unroll
    for (int mi = 0; mi < 4; ++mi)
#pragma unroll
        for (int ni = 0; ni < 2; ++ni) acc[mi][ni] = (f32x4){0.f, 0.f, 0.f, 0.f};

    const _Float16* gA0 = A + (size_t)(m0 + lane) * K + w * 8;
    const _Float16* gB0 = Wt + (size_t)(n0 + lane) * K + w * 8;
    const _Float16* gB1 = Wt + (size_t)(n0 + 64 + lane) * K + w * 8;

    auto stage = [&](int buf, int k0) {
        gl_lds16(gB0 + k0, &Bs[buf][w][0][0]);
        gl_lds16(gB1 + k0, &Bs[buf][w][64][0]);
        gl_lds16(gA0 + k0, &As[buf][w][0][0]);
    };

    const int nt = K >> 5;
    stage(0, 0);
    __syncthreads();
    for (int tt = 0; tt < nt; ++tt) {
        const int cur = tt & 1;
        if (tt + 1 < nt) stage(cur ^ 1, (tt + 1) << 5);
        f16x8 af[4], bf[2];
#pragma unroll
        for (int mi = 0; mi < 4; ++mi)
            af[mi] = *(const f16x8*)&As[cur][kb][mi * 16 + fr][0];
#pragma unroll
        for (int ni = 0; ni < 2; ++ni)
            bf[ni] = *(const f16x8*)&Bs[cur][kb][w * 32 + ni * 16 + fr][0];
#pragma unroll
        for (int mi = 0; mi < 4; ++mi)
#pragma unroll
            for (int ni = 0; ni < 2; ++ni)
                acc[mi][ni] = __builtin_amdgcn_mfma_f32_16x16x32_f16(af[mi], bf[ni], acc[mi][ni], 0, 0, 0);
        __syncthreads();
    }

    const int rr = lane >> 4;
#pragma unroll
    for (int mi = 0; mi < 4; ++mi) {
#pragma unroll
        for (int reg = 0; reg < 4; ++reg) {
            int m = m0 + mi * 16 + rr * 4 + reg;
            if (m < M) {
#pragma unroll
                for (int ni = 0; ni < 2; ++ni) {
                    int n = n0 + w * 32 + ni * 16 + fr;
                    float v = acc[mi][ni][reg] + bias[n];
                    if (BIAS2) v += bias2[n];
                    if (GELU) v = gelu_exact(v);
                    if (O32) C32[(size_t)m * N + n] = v;
                    if (O16) C16[(size_t)m * N + n] = (_Float16)v;
                }
            }
        }
    }
}

static inline void mg_gelu(hipStream_t st, const _Float16* A, const _Float16* Wt,
                           const float* bias, _Float16* C16, int M, int N, int K) {
    dim3 g(N / 128, (M + 63) / 64), b(256);
    k_mgemm<true, false, false, true><<<g, b, 0, st>>>(A, Wt, bias, nullptr, nullptr, C16, M, N, K);
}
static inline void mg_bias2_16(hipStream_t st, const _Float16* A, const _Float16* Wt,
                               const float* bias, const float* bias2, _Float16* C16,
                               int M, int N, int K) {
    dim3 g(N / 128, (M + 63) / 64), b(256);
    k_mgemm<false, true, false, true><<<g, b, 0, st>>>(A, Wt, bias, bias2, nullptr, C16, M, N, K);
}
static inline void mg_f32only(hipStream_t st, const _Float16* A, const _Float16* Wt,
                              const float* bias, float* C32, int M, int N, int K) {
    dim3 g(N / 128, (M + 63) / 64), b(256);
    k_mgemm<false, false, true, false><<<g, b, 0, st>>>(A, Wt, bias, nullptr, C32, nullptr, M, N, K);
}

extern "C" void kernel_launch(void* const* d_in, const int* in_sizes, int n_in,
                              void* d_out, int out_size, void* d_ws, size_t ws_size,
                              hipStream_t stream) {
    const float* x       = (const float*)d_in[0];
    const int*   ei      = (const int*)d_in[1];
    const int*   batch   = (const int*)d_in[2];
    const float* pre_W1  = (const float*)d_in[3];
    const float* pre_b1  = (const float*)d_in[4];
    const float* pre_W2  = (const float*)d_in[5];
    const float* pre_b2  = (const float*)d_in[6];
    const float* gin_W1  = (const float*)d_in[7];
    const float* gin_b1  = (const float*)d_in[8];
    const float* gin_W2  = (const float*)d_in[9];
    const float* gin_b2  = (const float*)d_in[10];
    const float* ffn_W1  = (const float*)d_in[11];
    const float* ffn_b1  = (const float*)d_in[12];
    const float* ffn_W2  = (const float*)d_in[13];
    const float* ffn_b2  = (const float*)d_in[14];
    const float* upd_W1  = (const float*)d_in[15];
    const float* upd_b1  = (const float*)d_in[16];
    const float* upd_W2  = (const float*)d_in[17];
    const float* upd_b2  = (const float*)d_in[18];
    const float* prop_W1 = (const float*)d_in[19];
    const float* prop_b1 = (const float*)d_in[20];
    const float* prop_W2 = (const float*)d_in[21];
    const float* prop_b2 = (const float*)d_in[22];
    const float* bn_gamma= (const float*)d_in[23];
    const float* bn_beta = (const float*)d_in[24];
    const float* vn      = (const float*)d_in[25];
    const float* post_W1 = (const float*)d_in[26];
    const float* post_b1 = (const float*)d_in[27];
    const float* post_W2 = (const float*)d_in[28];
    const float* post_b2 = (const float*)d_in[29];
    float* out = (float*)d_out;

    const int* e_src = ei;
    const int* e_dst = ei + NE;

    // ---------- workspace layout ----------
    char* p = (char*)d_ws;
    auto alloc = [&](size_t bytes) -> char* {
        char* r = p;
        p += (bytes + 255) & ~(size_t)255;
        return r;
    };
    _Float16* h16    = (_Float16*)alloc((size_t)NNP * HD * 2);   // fp16 backbone
    _Float16* g16    = (_Float16*)alloc((size_t)NNP * HD * 2);   // gin output (pre-BN)
    _Float16* t16a   = (_Float16*)alloc((size_t)NNP * HD * 2);   // agg out; aliases x16
    _Float16* pool16 = (_Float16*)alloc((size_t)NG * HD * 2);
    _Float16* u16    = (_Float16*)alloc((size_t)NG * HD * 2);
    _Float16* vb16   = (_Float16*)alloc((size_t)NG * H4 * 2);
    _Float16* p16    = (_Float16*)alloc((size_t)NG * HD * 2);
    float*    outvn32= (float*)alloc((size_t)NG * HD * 4);
    float*    bnstat = (float*)alloc((size_t)NSL * 2 * HD * 4);
    float*    bnscale= (float*)alloc(HD * 4);
    float*    bnshift= (float*)alloc(HD * 4);
    _Float16* preW1t = (_Float16*)alloc((size_t)HD * DIN * 2);
    _Float16* preW2t = (_Float16*)alloc((size_t)HD * HD * 2);
    _Float16* ginW1t = (_Float16*)alloc((size_t)NL * HD * HD * 2);
    _Float16* ginW2t = (_Float16*)alloc((size_t)NL * HD * HD * 2);
    _Float16* ffnW1t = (_Float16*)alloc((size_t)NL * HD * HD * 2);
    _Float16* ffnW2t = (_Float16*)alloc((size_t)NL * HD * HD * 2);
    _Float16* updW1t = (_Float16*)alloc((size_t)NL * HD * HD * 2);
    _Float16* updW2t = (_Float16*)alloc((size_t)NL * HD * H4 * 2);
    _Float16* propW1t= (_Float16*)alloc((size_t)NL * H4 * HD * 2);
    _Float16* propW2t= (_Float16*)alloc((size_t)NL * HD * HD * 2);
    _Float16* postW1t= (_Float16*)alloc((size_t)HD * HD * 2);
    _Float16* postW2t= (_Float16*)alloc((size_t)DOUT * HD * 2);
    int* gcount = (int*)alloc(NG * 4);
    int* goff   = (int*)alloc((NG + 1) * 4);
    int* deg    = (int*)alloc(NN * 4);
    int* eoff   = (int*)alloc((NN + 1) * 4);
    int* cursor = (int*)alloc(NN * 4);
    int* csr    = (int*)alloc((size_t)NE * 4);
    int* bsum   = (int*)alloc(1024 * 4);
    int* bexcl  = (int*)alloc(1024 * 4);
    _Float16* x16 = t16a;   // alias: consumed by pre-pair before t16a is first written

    // ---------- zero counters + bnstat ----------
    {
        size_t span = (size_t)((char*)(cursor + NN) - (char*)gcount);
        hipMemsetAsync(gcount, 0, span, stream);
        hipMemsetAsync(bnstat, 0, (size_t)NSL * 2 * HD * 4, stream);
    }
    hipLaunchKernelGGL(k_hist, dim3((NN + 255) / 256), dim3(256), 0, stream, batch, gcount, NN);
    hipLaunchKernelGGL(k_hist, dim3((NE + 255) / 256), dim3(256), 0, stream, e_dst, deg, NE);
    hipLaunchKernelGGL(k_scan_small, dim3(1), dim3(1024), 0, stream, gcount, goff, NG);
    {
        int nbN = (NN + 255) / 256;
        hipLaunchKernelGGL(k_scan_part, dim3(nbN), dim3(256), 0, stream, deg, bsum, NN);
        hipLaunchKernelGGL(k_scan_mid, dim3(1), dim3(1024), 0, stream, bsum, bexcl, nbN, eoff, NN);
        hipLaunchKernelGGL(k_scan_out, dim3(nbN), dim3(256), 0, stream, deg, bexcl, eoff, NN);
    }
    hipLaunchKernelGGL(k_fill_csr, dim3((NE + 255) / 256), dim3(256), 0, stream, e_src, e_dst, eoff, cursor, csr, NE);

    // ---------- batched weight transpose (one launch) ----------
    {
        WtJobs j;
        int idx = 0, tiles = 0;
        auto add = [&](const float* s, _Float16* d, int K, int N) {
            j.src[idx] = s; j.dst[idx] = d;
            j.K32[idx] = (short)(K / 32); j.N32[idx] = (short)(N / 32);
            j.pre[idx] = (short)tiles;
            tiles += (K / 32) * (N / 32);
            ++idx;
        };
        add(pre_W1, preW1t, DIN, HD);
        add(pre_W2, preW2t, HD, HD);
        add(post_W1, postW1t, HD, HD);
        add(post_W2, postW2t, HD, DOUT);
        for (int i = 0; i < NL; ++i) {
            add(gin_W1 + (size_t)i * HD * HD, ginW1t + (size_t)i * HD * HD, HD, HD);
            add(gin_W2 + (size_t)i * HD * HD, ginW2t + (size_t)i * HD * HD, HD, HD);
            add(ffn_W1 + (size_t)i * HD * HD, ffnW1t + (size_t)i * HD * HD, HD, HD);
            add(ffn_W2 + (size_t)i * HD * HD, ffnW2t + (size_t)i * HD * HD, HD, HD);
            add(upd_W1 + (size_t)i * HD * HD, updW1t + (size_t)i * HD * HD, HD, HD);
            add(upd_W2 + (size_t)i * HD * H4, updW2t + (size_t)i * HD * H4, HD, H4);
            add(prop_W1 + (size_t)i * H4 * HD, propW1t + (size_t)i * H4 * HD, H4, HD);
            add(prop_W2 + (size_t)i * HD * HD, propW2t + (size_t)i * HD * HD, HD, HD);
        }
        j.pre[idx] = (short)tiles;
        hipLaunchKernelGGL(k_wtb, dim3(tiles), dim3(32, 8), 0, stream, j);
    }

    // x -> fp16
    int n4 = NN * DIN / 4;
    hipLaunchKernelGGL(k_cvt16, dim3((n4 + 255) / 256), dim3(256), 0, stream, x, x16, n4);

    const int nb2b = NNP / 64;

    // ---------- pre-FFNN (fused pair): h16 = gelu(x@W1+b1)@W2+b2 ----------
    hipLaunchKernelGGL((k_b2b<false, false, false, false, DIN>), dim3(nb2b), dim3(512), 0, stream,
                       x16, nullptr, preW1t, pre_b1, preW2t, pre_b2,
                       nullptr, nullptr, nullptr, nullptr, nullptr, nullptr,
                       h16, NN);

    for (int i = 0; i < NL; ++i) {
        const _Float16* uW1 = updW1t + (size_t)i * HD * HD;
        const _Float16* uW2 = updW2t + (size_t)i * HD * H4;
        const _Float16* pW1 = propW1t + (size_t)i * H4 * HD;
        const _Float16* pW2 = propW2t + (size_t)i * HD * HD;

        // virtual-node path (M = NG = 512) via MFMA GEMMs
        hipLaunchKernelGGL(k_pool16, dim3(NG), dim3(HD), 0, stream, h16, goff, pool16);
        mg_gelu(stream, pool16, uW1, upd_b1 + (size_t)i * HD, u16, NG, HD, HD);
        mg_bias2_16(stream, u16, uW2, upd_b2 + (size_t)i * H4, vn, vb16, NG, H4, HD);
        mg_gelu(stream, vb16, pW1, prop_b1 + (size_t)i * HD, p16, NG, HD, H4);
        mg_f32only(stream, p16, pW2, prop_b2 + (size_t)i * HD, outvn32, NG, HD, HD);

        // GIN: t16a = agg(h16); g16 = gelu(t16a@gW1+b1)@gW2+b2 + h16 (+BN stats)
        hipLaunchKernelGGL(k_agg16, dim3(NN / 4), dim3(256), 0, stream, h16, eoff, csr, t16a);
        hipLaunchKernelGGL((k_b2b<false, true, false, true, HD>), dim3(nb2b), dim3(512), 0, stream,
                           t16a, nullptr,
                           ginW1t + (size_t)i * HD * HD, gin_b1 + (size_t)i * HD,
                           ginW2t + (size_t)i * HD * HD, gin_b2 + (size_t)i * HD,
                           h16, nullptr, nullptr, nullptr, nullptr, bnstat,
                           g16, NN);

        // BN finalize (sums slices, re-zeroes)
        hipLaunchKernelGGL(k_bn_final, dim3(1), dim3(HD), 0, stream, bnstat,
                           bn_gamma + (size_t)i * HD, bn_beta + (size_t)i * HD, bnscale, bnshift);

        // FFN fused pair: h16 = gelu((bn(g16)+ovn)@fW1+b1)@fW2+b2 + bn(g16)
        hipLaunchKernelGGL((k_b2b<true, false, true, false, HD>), dim3(nb2b), dim3(512), 0, stream,
                           nullptr, g16,
                           ffnW1t + (size_t)i * HD * HD, ffn_b1 + (size_t)i * HD,
                           ffnW2t + (size_t)i * HD * HD, ffn_b2 + (size_t)i * HD,
                           g16, bnscale, bnshift, outvn32, batch, nullptr,
                           h16, NN);
    }

    // ---------- post ----------
    hipLaunchKernelGGL(k_pool16, dim3(NG), dim3(HD), 0, stream, h16, goff, pool16);
    mg_gelu(stream, pool16, postW1t, post_b1, u16, NG, HD, HD);
    mg_f32only(stream, u16, postW2t, post_b2, out, NG, DOUT, HD);
}